// Round 1
// baseline (3893.361 us; speedup 1.0000x reference)
//
#include <hip/hip_runtime.h>
#include <math.h>

#define NN 20000
#define NE 320000
#define EG 340000   // NE + NN self loops
#define NB 4096

// ---------------------------------------------------------------- kernels

// C[M,Nc] = A[M,K] @ W[K,Nc] (+ bias[Nc]).  lgw = log2 of lane-width (6 or 5).
__global__ void k_gemm_bias(const float* __restrict__ A, const float* __restrict__ W,
                            const float* __restrict__ bias, float* __restrict__ C,
                            int M, int K, int Nc, int lgw) {
  int wmask = (1 << lgw) - 1;
  int n = blockIdx.x * (1 << lgw) + (threadIdx.x & wmask);
  int m = blockIdx.y * (256 >> lgw) + (threadIdx.x >> lgw);
  if (m >= M || n >= Nc) return;
  const float* a = A + (size_t)m * K;
  float acc = bias ? bias[n] : 0.0f;
#pragma unroll 4
  for (int k = 0; k < K; ++k) acc = fmaf(a[k], W[(size_t)k * Nc + n], acc);
  C[(size_t)m * Nc + n] = acc;
}

// out[m, n] = bias[n]   (Nc is power of two; mask = Nc-1)
__global__ void k_init_rows(float* __restrict__ out, const float* __restrict__ bias,
                            int total, int mask) {
  int t = blockIdx.x * blockDim.x + threadIdx.x;
  if (t >= total) return;
  out[t] = bias[t & mask];
}

// x = where(x>=0, x, a[col]*x)  in place (col = t & mask)
__global__ void k_prelu(float* __restrict__ x, const float* __restrict__ a,
                        int total, int mask) {
  int t = blockIdx.x * blockDim.x + threadIdx.x;
  if (t >= total) return;
  float v = x[t];
  x[t] = (v >= 0.0f) ? v : a[t & mask] * v;
}

// als[i], ald[i] = <h[i,:], a_src[h,:]>, <h[i,:], a_dst[h,:]> for i = node*heads+h
__global__ void k_gat_al(const float* __restrict__ h, const float* __restrict__ asrc,
                         const float* __restrict__ adst, float* __restrict__ als,
                         float* __restrict__ ald, int total, int heads, int c) {
  int i = blockIdx.x * blockDim.x + threadIdx.x;
  if (i >= total) return;
  int hd = i % heads;
  const float* hp = h + (size_t)i * c;
  const float* as = asrc + hd * c;
  const float* ad = adst + hd * c;
  float s1 = 0.0f, s2 = 0.0f;
  for (int k = 0; k < c; ++k) {
    s1 = fmaf(hp[k], as[k], s1);
    s2 = fmaf(hp[k], ad[k], s2);
  }
  als[i] = s1;
  ald[i] = s2;
}

// GAT edge logits: p[e*H+h] = exp(leaky_relu(als[src]+ald[dst])); sum[dst*H+h] += p
template <int HEADS>
__global__ void k_edge_logits_gat(const int* __restrict__ src, const int* __restrict__ dst,
                                  const float* __restrict__ als, const float* __restrict__ ald,
                                  float* __restrict__ p, float* __restrict__ sum,
                                  int nreal, int ntot) {
  int t = blockIdx.x * blockDim.x + threadIdx.x;
  if (t >= ntot * HEADS) return;
  int e = t / HEADS, hd = t - e * HEADS;
  int s = (e < nreal) ? src[e] : (e - nreal);
  int d = (e < nreal) ? dst[e] : (e - nreal);
  float v = als[s * HEADS + hd] + ald[d * HEADS + hd];
  v = (v >= 0.0f) ? v : 0.2f * v;
  float pe = expf(v);   // logits are O(0.1): no max-subtraction needed
  p[t] = pe;
  atomicAdd(&sum[d * HEADS + hd], pe);
}

// GT edge logits: p = exp(<q[dst,h,:],k[src,h,:]> * scale); sum[dst*H+h] += p
template <int HEADS, int C>
__global__ void k_edge_logits_gt(const int* __restrict__ src, const int* __restrict__ dst,
                                 const float* __restrict__ q, const float* __restrict__ k,
                                 float* __restrict__ p, float* __restrict__ sum,
                                 int ne, float scale) {
  int t = blockIdx.x * blockDim.x + threadIdx.x;
  if (t >= ne * HEADS) return;
  int e = t / HEADS, hd = t - e * HEADS;
  int s = src[e], d = dst[e];
  const float* qp = q + ((size_t)d * HEADS + hd) * C;
  const float* kp = k + ((size_t)s * HEADS + hd) * C;
  float acc = 0.0f;
#pragma unroll
  for (int i = 0; i < C; ++i) acc = fmaf(qp[i], kp[i], acc);
  float pe = expf(acc * scale);
  p[t] = pe;
  atomicAdd(&sum[d * HEADS + hd], pe);
}

// out[dst, i] += (p[e,h]/(sum[dst,h]+1e-16)) * feat[src, i]   (i in [0,H*C))
template <int HEADS, int C>
__global__ void k_edge_agg(const int* __restrict__ src, const int* __restrict__ dst,
                           const float* __restrict__ p, const float* __restrict__ sum,
                           const float* __restrict__ feat, float* __restrict__ out,
                           int nreal, int ntot) {
  constexpr int HC = HEADS * C;
  int t = blockIdx.x * blockDim.x + threadIdx.x;
  if (t >= ntot * HC) return;
  int e = t / HC, i = t - e * HC;
  int hd = i / C;
  int s = (e < nreal) ? src[e] : (e - nreal);
  int d = (e < nreal) ? dst[e] : (e - nreal);
  float alpha = p[e * HEADS + hd] / (sum[d * HEADS + hd] + 1e-16f);
  atomicAdd(&out[(size_t)d * HC + i], alpha * feat[(size_t)s * HC + i]);
}

// x2[m, j] = [xg[m,:] | xt[m,:]] @ fuse_w + fuse_b
__global__ void k_fuse(const float* __restrict__ xg, const float* __restrict__ xt,
                       const float* __restrict__ w, const float* __restrict__ b,
                       float* __restrict__ out, int M) {
  int t = blockIdx.x * blockDim.x + threadIdx.x;
  if (t >= M * 32) return;
  int m = t >> 5, j = t & 31;
  const float* xgp = xg + (size_t)m * 32;
  const float* xtp = xt + (size_t)m * 32;
  float acc = b[j];
#pragma unroll
  for (int i = 0; i < 32; ++i) acc = fmaf(xgp[i], w[i * 32 + j], acc);
#pragma unroll
  for (int i = 0; i < 32; ++i) acc = fmaf(xtp[i], w[(32 + i) * 32 + j], acc);
  out[t] = acc;
}

// sig[j] = sigmoid(mean over rows of x[:, j]); one block per column j
__global__ void k_colmean_sig(const float* __restrict__ x, float* __restrict__ sig, int M) {
  __shared__ float red[256];
  int j = blockIdx.x;
  float s = 0.0f;
  for (int m = threadIdx.x; m < M; m += 256) s += x[(size_t)m * 32 + j];
  red[threadIdx.x] = s;
  __syncthreads();
  for (int w = 128; w > 0; w >>= 1) {
    if (threadIdx.x < w) red[threadIdx.x] += red[threadIdx.x + w];
    __syncthreads();
  }
  if (threadIdx.x == 0) sig[j] = 1.0f / (1.0f + expf(-red[0] / (float)M));
}

// h[j] = sig @ mlp1_w[:, j] + mlp1_b[j]   (32 threads)
__global__ void k_summary2(const float* __restrict__ sig, const float* __restrict__ w,
                           const float* __restrict__ b, float* __restrict__ out) {
  int j = threadIdx.x;
  float acc = b[j];
#pragma unroll
  for (int i = 0; i < 32; ++i) acc = fmaf(sig[i], w[i * 32 + j], acc);
  out[j] = acc;
}

// ret_os[n,:] = [t_o.h_os, t_a.h_os]+b ; ret_os_a[n,:] = [t_a.h_osa, t_o.h_osa]+b
__global__ void k_disc(const float* __restrict__ to, const float* __restrict__ ta,
                       const float* __restrict__ hos, const float* __restrict__ hosa,
                       const float* __restrict__ db, float* __restrict__ ret_os,
                       float* __restrict__ ret_os_a, int M) {
  int n = blockIdx.x * blockDim.x + threadIdx.x;
  if (n >= M) return;
  const float* a = to + (size_t)n * 32;
  const float* b = ta + (size_t)n * 32;
  float s_oo = 0, s_ao = 0, s_aa = 0, s_oa = 0;
#pragma unroll
  for (int i = 0; i < 32; ++i) {
    float ho = hos[i], ha = hosa[i];
    s_oo = fmaf(a[i], ho, s_oo);
    s_ao = fmaf(b[i], ho, s_ao);
    s_aa = fmaf(b[i], ha, s_aa);
    s_oa = fmaf(a[i], ha, s_oa);
  }
  float bb = db[0];
  ret_os[n * 2 + 0] = s_oo + bb;
  ret_os[n * 2 + 1] = s_ao + bb;
  ret_os_a[n * 2 + 0] = s_aa + bb;
  ret_os_a[n * 2 + 1] = s_oa + bb;
}

// hh[b, n] = relu([x2o[idx0[b]] | x2o[idx1[b]]] @ fus_w1 + fus_b1)
__global__ void k_dec1(const float* __restrict__ x2o, const int* __restrict__ idx0,
                       const int* __restrict__ idx1, const float* __restrict__ w,
                       const float* __restrict__ b1, float* __restrict__ hh) {
  int t = blockIdx.x * blockDim.x + threadIdx.x;
  if (t >= NB * 512) return;
  int bb = t >> 9, n = t & 511;
  const float* r0 = x2o + (size_t)idx0[bb] * 32;
  const float* r1 = x2o + (size_t)idx1[bb] * 32;
  float acc = b1[n];
#pragma unroll
  for (int i = 0; i < 32; ++i) acc = fmaf(r0[i], w[i * 512 + n], acc);
#pragma unroll
  for (int i = 0; i < 32; ++i) acc = fmaf(r1[i], w[(32 + i) * 512 + n], acc);
  hh[t] = fmaxf(acc, 0.0f);
}

// log[b,:] = hh[b]@fus_w2+fus_b2 ; log1[b,:] = hh[b]@fus_w3+fus_b3
__global__ void k_dec2(const float* __restrict__ hh, const float* __restrict__ w2,
                       const float* __restrict__ b2, const float* __restrict__ w3,
                       const float* __restrict__ b3, float* __restrict__ logo,
                       float* __restrict__ log1, int Bn) {
  int t = blockIdx.x * blockDim.x + threadIdx.x;
  if (t >= Bn * 4) return;
  int bb = t >> 2, j = t & 3;
  const float* h = hh + (size_t)bb * 512;
  if (j < 2) {
    float acc = b2[j];
    for (int k = 0; k < 512; ++k) acc = fmaf(h[k], w2[k * 2 + j], acc);
    logo[bb * 2 + j] = acc;
  } else {
    int jj = j - 2;
    float acc = b3[jj];
    for (int k = 0; k < 512; ++k) acc = fmaf(h[k], w3[k * 2 + jj], acc);
    log1[bb * 2 + jj] = acc;
  }
}

// advr[i] = rowsum of adv_w ; advr[32] = sum(adv_b)
__global__ void k_advprep(const float* __restrict__ w, const float* __restrict__ b,
                          float* __restrict__ out) {
  int i = threadIdx.x;
  if (i < 32) {
    float s = 0.0f;
    for (int j = 0; j < 32; ++j) s += w[i * 32 + j];
    out[i] = s;
  } else if (i == 32) {
    float s = 0.0f;
    for (int j = 0; j < 32; ++j) s += b[j];
    out[32] = s;
  }
}

// logits[n] = x2[n] . advr[:32] + advr[32]   (n<NN from x2o, else x2a)
__global__ void k_adv(const float* __restrict__ x2o, const float* __restrict__ x2a,
                      const float* __restrict__ advr, float* __restrict__ logits) {
  int n = blockIdx.x * blockDim.x + threadIdx.x;
  if (n >= 2 * NN) return;
  const float* row = (n < NN) ? (x2o + (size_t)n * 32) : (x2a + (size_t)(n - NN) * 32);
  float acc = advr[32];
#pragma unroll
  for (int i = 0; i < 32; ++i) acc = fmaf(row[i], advr[i], acc);
  logits[n] = acc;
}

// ---------------------------------------------------------------- host

extern "C" void kernel_launch(void* const* d_in, const int* in_sizes, int n_in,
                              void* d_out, int out_size, void* d_ws, size_t ws_size,
                              hipStream_t stream) {
  const float* x_o = (const float*)d_in[0];
  const float* x_a = (const float*)d_in[1];
  const float* gat1_w = (const float*)d_in[2];
  const float* gat1_asrc = (const float*)d_in[3];
  const float* gat1_adst = (const float*)d_in[4];
  const float* gat1_b = (const float*)d_in[5];
  const float* gat2_w = (const float*)d_in[6];
  const float* gat2_asrc = (const float*)d_in[7];
  const float* gat2_adst = (const float*)d_in[8];
  const float* gat2_b = (const float*)d_in[9];
  const float* pg1 = (const float*)d_in[10];
  const float* pg2 = (const float*)d_in[11];
  const float* gt1_wq = (const float*)d_in[12];
  const float* gt1_bq = (const float*)d_in[13];
  const float* gt1_wk = (const float*)d_in[14];
  const float* gt1_bk = (const float*)d_in[15];
  const float* gt1_wv = (const float*)d_in[16];
  const float* gt1_bv = (const float*)d_in[17];
  const float* gt1_ws = (const float*)d_in[18];
  const float* gt1_bs = (const float*)d_in[19];
  const float* gt2_wq = (const float*)d_in[20];
  const float* gt2_bq = (const float*)d_in[21];
  const float* gt2_wk = (const float*)d_in[22];
  const float* gt2_bk = (const float*)d_in[23];
  const float* gt2_wv = (const float*)d_in[24];
  const float* gt2_bv = (const float*)d_in[25];
  const float* gt2_ws = (const float*)d_in[26];
  const float* gt2_bs = (const float*)d_in[27];
  const float* pt1 = (const float*)d_in[28];
  const float* pt2 = (const float*)d_in[29];
  const float* fuse_w = (const float*)d_in[30];
  const float* fuse_b = (const float*)d_in[31];
  const float* mlp1_w = (const float*)d_in[32];
  const float* mlp1_b = (const float*)d_in[33];
  const float* disc_w = (const float*)d_in[34];
  const float* disc_b = (const float*)d_in[35];
  const float* fus_w1 = (const float*)d_in[36];
  const float* fus_b1 = (const float*)d_in[37];
  const float* fus_w2 = (const float*)d_in[38];
  const float* fus_b2 = (const float*)d_in[39];
  const float* fus_w3 = (const float*)d_in[40];
  const float* fus_b3 = (const float*)d_in[41];
  const float* adv_w = (const float*)d_in[42];
  const float* adv_b = (const float*)d_in[43];
  const int* ei = (const int*)d_in[44];
  const int* idxp = (const int*)d_in[45];
  const int* esrc = ei;
  const int* edst = ei + NE;
  const int* idx0 = idxp;
  const int* idx1 = idxp + NB;

  // workspace layout (floats); total ~29.3M floats = ~117 MB
  float* w = (float*)d_ws;
  float* bufA = w + 0;          // N*256
  float* bufB = w + 5120000;    // N*256
  float* bufD = w + 10240000;   // N*256
  float* bufE = w + 15360000;   // N*256
  float* ep   = w + 20480000;   // EG*4
  float* sums = w + 21840000;   // N*4
  float* als  = w + 21920000;   // N*4
  float* ald  = w + 22000000;   // N*4
  float* q2b  = w + 22080000;   // N*32 (h2 / q2)
  float* k2b  = w + 22720000;   // N*32
  float* v2b  = w + 23360000;   // N*32
  float* xg   = w + 24000000;   // N*32
  float* xt   = w + 24640000;   // N*32
  float* x2a  = w + 25280000;   // N*32
  float* t_o  = w + 25920000;   // N*32
  float* t_a  = w + 26560000;   // N*32
  float* hh   = w + 27200000;   // B*512
  float* sml  = w + 29297152;   // small vectors
  float* sig_o = sml;
  float* sig_a = sml + 32;
  float* h_os = sml + 64;
  float* h_osa = sml + 96;
  float* advr = sml + 128;

  float* out = (float*)d_out;
  float* out_log = out;               // [B,2]
  float* out_ret = out + 8192;        // [N,2]
  float* out_reta = out + 48192;      // [N,2]
  float* out_x2o = out + 88192;       // [N,32]
  float* out_logit = out + 728192;    // [1,2N]
  float* out_log1 = out + 768192;     // [B,2]

  auto gemm = [&](const float* A, const float* W_, const float* bias, float* C,
                  int M, int K, int Nc) {
    int lgw = (Nc >= 64) ? 6 : 5;
    dim3 grid((Nc + (1 << lgw) - 1) >> lgw,
              (M + (256 >> lgw) - 1) / (256 >> lgw));
    k_gemm_bias<<<grid, 256, 0, stream>>>(A, W_, bias, C, M, K, Nc, lgw);
  };

  auto branch = [&](const float* x, float* x2out) {
    // ---- GAT1: h = x@W [N,4,64]; softmax over (E + self loops) ----
    gemm(x, gat1_w, nullptr, bufA, NN, 128, 256);
    k_gat_al<<<(NN * 4 + 255) / 256, 256, 0, stream>>>(bufA, gat1_asrc, gat1_adst,
                                                       als, ald, NN * 4, 4, 64);
    hipMemsetAsync(sums, 0, NN * 4 * sizeof(float), stream);
    k_edge_logits_gat<4><<<(EG * 4 + 255) / 256, 256, 0, stream>>>(esrc, edst, als, ald,
                                                                   ep, sums, NE, EG);
    k_init_rows<<<(NN * 256 + 255) / 256, 256, 0, stream>>>(bufB, gat1_b, NN * 256, 255);
    k_edge_agg<4, 64><<<EG, 256, 0, stream>>>(esrc, edst, ep, sums, bufA, bufB, NE, EG);
    k_prelu<<<(NN * 256 + 255) / 256, 256, 0, stream>>>(bufB, pg1, NN * 256, 255);
    // ---- GAT2 (1 head, C=32) ----
    gemm(bufB, gat2_w, nullptr, q2b, NN, 256, 32);
    k_gat_al<<<(NN + 255) / 256, 256, 0, stream>>>(q2b, gat2_asrc, gat2_adst,
                                                   als, ald, NN, 1, 32);
    hipMemsetAsync(sums, 0, NN * sizeof(float), stream);
    k_edge_logits_gat<1><<<(EG + 255) / 256, 256, 0, stream>>>(esrc, edst, als, ald,
                                                               ep, sums, NE, EG);
    k_init_rows<<<(NN * 32 + 255) / 256, 256, 0, stream>>>(xg, gat2_b, NN * 32, 31);
    k_edge_agg<1, 32><<<(EG * 32 + 255) / 256, 256, 0, stream>>>(esrc, edst, ep, sums,
                                                                 q2b, xg, NE, EG);
    k_prelu<<<(NN * 32 + 255) / 256, 256, 0, stream>>>(xg, pg2, NN * 32, 31);
    // ---- GT1 (4 heads, C=64), real edges only ----
    gemm(x, gt1_wq, gt1_bq, bufA, NN, 128, 256);
    gemm(x, gt1_wk, gt1_bk, bufB, NN, 128, 256);
    gemm(x, gt1_wv, gt1_bv, bufD, NN, 128, 256);
    gemm(x, gt1_ws, gt1_bs, bufE, NN, 128, 256);   // skip: agg accumulates on top
    hipMemsetAsync(sums, 0, NN * 4 * sizeof(float), stream);
    k_edge_logits_gt<4, 64><<<(NE * 4 + 255) / 256, 256, 0, stream>>>(esrc, edst, bufA,
                                                                      bufB, ep, sums, NE,
                                                                      0.125f);
    k_edge_agg<4, 64><<<NE, 256, 0, stream>>>(esrc, edst, ep, sums, bufD, bufE, NE, NE);
    k_prelu<<<(NN * 256 + 255) / 256, 256, 0, stream>>>(bufE, pt1, NN * 256, 255);
    // ---- GT2 (1 head, C=32) ----
    gemm(bufE, gt2_wq, gt2_bq, q2b, NN, 256, 32);
    gemm(bufE, gt2_wk, gt2_bk, k2b, NN, 256, 32);
    gemm(bufE, gt2_wv, gt2_bv, v2b, NN, 256, 32);
    gemm(bufE, gt2_ws, gt2_bs, xt, NN, 256, 32);   // skip
    hipMemsetAsync(sums, 0, NN * sizeof(float), stream);
    k_edge_logits_gt<1, 32><<<(NE + 255) / 256, 256, 0, stream>>>(esrc, edst, q2b, k2b,
                                                                  ep, sums, NE,
                                                                  0.17677669529663687f);
    k_edge_agg<1, 32><<<(NE * 32 + 255) / 256, 256, 0, stream>>>(esrc, edst, ep, sums,
                                                                 v2b, xt, NE, NE);
    k_prelu<<<(NN * 32 + 255) / 256, 256, 0, stream>>>(xt, pt2, NN * 32, 31);
    // ---- fuse ----
    k_fuse<<<(NN * 32 + 255) / 256, 256, 0, stream>>>(xg, xt, fuse_w, fuse_b, x2out, NN);
  };

  branch(x_o, out_x2o);
  branch(x_a, x2a);

  // summary + discriminator
  k_colmean_sig<<<32, 256, 0, stream>>>(out_x2o, sig_o, NN);
  k_colmean_sig<<<32, 256, 0, stream>>>(x2a, sig_a, NN);
  k_summary2<<<1, 32, 0, stream>>>(sig_o, mlp1_w, mlp1_b, h_os);
  k_summary2<<<1, 32, 0, stream>>>(sig_a, mlp1_w, mlp1_b, h_osa);
  gemm(out_x2o, disc_w, nullptr, t_o, NN, 32, 32);
  gemm(x2a, disc_w, nullptr, t_a, NN, 32, 32);
  k_disc<<<(NN + 255) / 256, 256, 0, stream>>>(t_o, t_a, h_os, h_osa, disc_b,
                                               out_ret, out_reta, NN);
  // decoder
  k_dec1<<<(NB * 512 + 255) / 256, 256, 0, stream>>>(out_x2o, idx0, idx1, fus_w1,
                                                     fus_b1, hh);
  k_dec2<<<(NB * 4 + 255) / 256, 256, 0, stream>>>(hh, fus_w2, fus_b2, fus_w3, fus_b3,
                                                   out_log, out_log1, NB);
  // adversarial logits
  k_advprep<<<1, 64, 0, stream>>>(adv_w, adv_b, advr);
  k_adv<<<(2 * NN + 255) / 256, 256, 0, stream>>>(out_x2o, x2a, advr, out_logit);
}

// Round 2
// 1360.982 us; speedup vs baseline: 2.8607x; 2.8607x over previous
//
#include <hip/hip_runtime.h>
#include <math.h>

#define NN 20000
#define NE 320000
#define NB 4096

typedef unsigned short u16;

__device__ __forceinline__ float b2f(u16 u) {
  unsigned int x = ((unsigned int)u) << 16;
  return __uint_as_float(x);
}
__device__ __forceinline__ u16 f2b(float f) {
  unsigned int x = __float_as_uint(f);
  return (u16)((x + 0x7fffu + ((x >> 16) & 1u)) >> 16);
}

__device__ __forceinline__ float loadf(const float* p) { return *p; }
__device__ __forceinline__ float loadf(const u16* p) { return b2f(*p); }
__device__ __forceinline__ void storef(float* p, float v) { *p = v; }
__device__ __forceinline__ void storef(u16* p, float v) { *p = f2b(v); }

// ------------------------------------------------ packing

__global__ void k_pack1(const float* __restrict__ w0, const float* __restrict__ w1,
                        const float* __restrict__ w2, const float* __restrict__ w3,
                        const float* __restrict__ w4, const float* __restrict__ b1,
                        const float* __restrict__ b2, const float* __restrict__ b3,
                        const float* __restrict__ b4, float* __restrict__ Wp,
                        float* __restrict__ bp) {
  int t = blockIdx.x * blockDim.x + threadIdx.x;
  if (t < 128 * 1280) {
    int k = t / 1280, j = t - k * 1280;
    int seg = j >> 8, jj = j & 255;
    const float* s = (seg == 0) ? w0 : (seg == 1) ? w1 : (seg == 2) ? w2 : (seg == 3) ? w3 : w4;
    Wp[t] = s[k * 256 + jj];
  }
  if (t < 1280) {
    int seg = t >> 8, jj = t & 255;
    bp[t] = (seg == 0) ? 0.0f : (seg == 1) ? b1[jj] : (seg == 2) ? b2[jj] : (seg == 3) ? b3[jj] : b4[jj];
  }
}

// layout cols: [wq2|wk2|wv2|ws2|gat2_w]  (gat2 last so col-block 2 selects bufB)
__global__ void k_pack2(const float* __restrict__ wq, const float* __restrict__ wk,
                        const float* __restrict__ wv, const float* __restrict__ ws,
                        const float* __restrict__ wg, const float* __restrict__ bq,
                        const float* __restrict__ bk, const float* __restrict__ bv,
                        const float* __restrict__ bs, float* __restrict__ Wp,
                        float* __restrict__ bp) {
  int t = blockIdx.x * blockDim.x + threadIdx.x;
  if (t < 256 * 160) {
    int k = t / 160, j = t - k * 160;
    int seg = j >> 5, jj = j & 31;
    const float* s = (seg == 0) ? wq : (seg == 1) ? wk : (seg == 2) ? wv : (seg == 3) ? ws : wg;
    Wp[t] = s[k * 32 + jj];
  }
  if (t < 160) {
    int seg = t >> 5, jj = t & 31;
    bp[t] = (seg == 0) ? bq[jj] : (seg == 1) ? bk[jj] : (seg == 2) ? bv[jj] : (seg == 3) ? bs[jj] : 0.0f;
  }
}

// ------------------------------------------------ CSR build

__global__ void k_hist(const int* __restrict__ dst, int* __restrict__ deg) {
  int t = blockIdx.x * blockDim.x + threadIdx.x;
  if (t < NE) atomicAdd(&deg[dst[t]], 1);
}

__global__ void k_scan20000(const int* __restrict__ deg, int* __restrict__ offs) {
  __shared__ int part[1024];
  int t = threadIdx.x;
  int loc[20];
  int s = 0;
#pragma unroll
  for (int i = 0; i < 20; ++i) {
    int idx = t * 20 + i;
    int v = (idx < NN) ? deg[idx] : 0;
    loc[i] = s;
    s += v;
  }
  part[t] = s;
  __syncthreads();
  for (int off = 1; off < 1024; off <<= 1) {
    int v = (t >= off) ? part[t - off] : 0;
    __syncthreads();
    part[t] += v;
    __syncthreads();
  }
  int base = (t > 0) ? part[t - 1] : 0;
#pragma unroll
  for (int i = 0; i < 20; ++i) {
    int idx = t * 20 + i;
    if (idx < NN) offs[idx] = base + loc[i];
  }
  if (t == 1023) offs[NN] = part[1023];
}

__global__ void k_copyoffs(const int* __restrict__ offs, int* __restrict__ cur) {
  int t = blockIdx.x * blockDim.x + threadIdx.x;
  if (t < NN) cur[t] = offs[t];
}

__global__ void k_scatter(const int* __restrict__ src, const int* __restrict__ dst,
                          int* __restrict__ cur, int* __restrict__ eids,
                          int* __restrict__ esrcs) {
  int t = blockIdx.x * blockDim.x + threadIdx.x;
  if (t >= NE) return;
  int d = dst[t];
  int pos = atomicAdd(&cur[d], 1);
  eids[pos] = t;
  esrcs[pos] = src[t];
}

// ------------------------------------------------ GEMM (64x64 tile, 4x4 reg)

template <typename TA, typename TC>
__global__ void k_gemm64(const TA* __restrict__ A0, const TA* __restrict__ A1, int asel,
                         int lda, const float* __restrict__ W,
                         const float* __restrict__ bias, TC* __restrict__ C, int M,
                         int K, int Nc) {
  __shared__ float As[16][68];
  __shared__ float Ws[16][68];
  const TA* A = (blockIdx.x >= (unsigned)asel) ? A1 : A0;
  int m0 = blockIdx.y * 64, n0 = blockIdx.x * 64;
  int tid = threadIdx.x;
  int tx = tid & 15, ty = tid >> 4;
  float acc[4][4] = {};
  for (int k0 = 0; k0 < K; k0 += 16) {
#pragma unroll
    for (int j = 0; j < 4; ++j) {
      int lin = j * 256 + tid;
      int m = lin >> 4, k = lin & 15;
      int mm = m0 + m;
      if (mm > M - 1) mm = M - 1;
      As[k][m] = loadf(&A[(size_t)mm * lda + k0 + k]);
    }
#pragma unroll
    for (int j = 0; j < 4; ++j) {
      int lin = j * 256 + tid;
      int k = lin >> 6, n = lin & 63;
      Ws[k][n] = (n0 + n < Nc) ? W[(size_t)(k0 + k) * Nc + n0 + n] : 0.0f;
    }
    __syncthreads();
#pragma unroll
    for (int kk = 0; kk < 16; ++kk) {
      float4 a4 = *reinterpret_cast<const float4*>(&As[kk][ty * 4]);
      float4 b4 = *reinterpret_cast<const float4*>(&Ws[kk][tx * 4]);
      float av[4] = {a4.x, a4.y, a4.z, a4.w};
      float bv[4] = {b4.x, b4.y, b4.z, b4.w};
#pragma unroll
      for (int i = 0; i < 4; ++i)
#pragma unroll
        for (int j = 0; j < 4; ++j) acc[i][j] = fmaf(av[i], bv[j], acc[i][j]);
    }
    __syncthreads();
  }
#pragma unroll
  for (int i = 0; i < 4; ++i) {
    int m = m0 + ty * 4 + i;
    if (m >= M) continue;
#pragma unroll
    for (int j = 0; j < 4; ++j) {
      int n = n0 + tx * 4 + j;
      if (n >= Nc) continue;
      storef(&C[(size_t)m * Nc + n], acc[i][j] + (bias ? bias[n] : 0.0f));
    }
  }
}

// ------------------------------------------------ attention pieces

// als/ald from bf16 features at (node*stride + coff + head*c)
__global__ void k_gat_al(const u16* __restrict__ h, int stride, int coff,
                         const float* __restrict__ asrc, const float* __restrict__ adst,
                         float* __restrict__ als, float* __restrict__ ald, int total,
                         int heads, int c) {
  int i = blockIdx.x * blockDim.x + threadIdx.x;
  if (i >= total) return;
  int node = i / heads, hd = i - node * heads;
  const u16* hp = h + (size_t)node * stride + coff + hd * c;
  const float* as = asrc + hd * c;
  const float* ad = adst + hd * c;
  float s1 = 0.0f, s2 = 0.0f;
  for (int k = 0; k < c; ++k) {
    float f = b2f(hp[k]);
    s1 = fmaf(f, as[k], s1);
    s2 = fmaf(f, ad[k], s2);
  }
  als[i] = s1;
  ald[i] = s2;
}

// GT1: p[e*4+h] = exp(dot64(q[dst,h],k[src,h]) / 8)
__global__ void k_logits_gt1(const int* __restrict__ src, const int* __restrict__ dst,
                             const u16* __restrict__ C1, float* __restrict__ p) {
  int t = blockIdx.x * blockDim.x + threadIdx.x;
  if (t >= NE * 4) return;
  int e = t >> 2, hd = t & 3;
  const u16* qp = C1 + (size_t)dst[e] * 1280 + 256 + hd * 64;
  const u16* kp = C1 + (size_t)src[e] * 1280 + 512 + hd * 64;
  float acc = 0.0f;
#pragma unroll
  for (int i = 0; i < 16; ++i) {
    ushort4 q = *reinterpret_cast<const ushort4*>(&qp[i * 4]);
    ushort4 k = *reinterpret_cast<const ushort4*>(&kp[i * 4]);
    acc = fmaf(b2f(q.x), b2f(k.x), acc);
    acc = fmaf(b2f(q.y), b2f(k.y), acc);
    acc = fmaf(b2f(q.z), b2f(k.z), acc);
    acc = fmaf(b2f(q.w), b2f(k.w), acc);
  }
  p[t] = expf(acc * 0.125f);
}

// GT2: p[e] = exp(dot32(q2[dst],k2[src]) / sqrt(32))
__global__ void k_logits_gt2(const int* __restrict__ src, const int* __restrict__ dst,
                             const u16* __restrict__ C2, float* __restrict__ p) {
  int e = blockIdx.x * blockDim.x + threadIdx.x;
  if (e >= NE) return;
  const u16* qp = C2 + (size_t)dst[e] * 160;
  const u16* kp = C2 + (size_t)src[e] * 160 + 32;
  float acc = 0.0f;
#pragma unroll
  for (int i = 0; i < 8; ++i) {
    ushort4 q = *reinterpret_cast<const ushort4*>(&qp[i * 4]);
    ushort4 k = *reinterpret_cast<const ushort4*>(&kp[i * 4]);
    acc = fmaf(b2f(q.x), b2f(k.x), acc);
    acc = fmaf(b2f(q.y), b2f(k.y), acc);
    acc = fmaf(b2f(q.z), b2f(k.z), acc);
    acc = fmaf(b2f(q.w), b2f(k.w), acc);
  }
  p[e] = expf(acc * 0.17677669529663687f);
}

// CSR gather-aggregate, HC=256, one wave per dst node.
// GAT: p inline from als/ald (4 heads), + self loop, + bias, prelu -> bf16 out
// GT : p from array, + skip (C1 col 1024, includes bias), prelu -> bf16 out
template <bool GAT>
__global__ void k_agg256(const int* __restrict__ offs, const int* __restrict__ eids,
                         const int* __restrict__ esrcs, const float* __restrict__ p,
                         const float* __restrict__ als, const float* __restrict__ ald,
                         const u16* __restrict__ C1, const float* __restrict__ bias,
                         const float* __restrict__ pa, u16* __restrict__ out) {
  int d = blockIdx.x * 4 + (threadIdx.x >> 6);
  if (d >= NN) return;
  int lane = threadIdx.x & 63;
  int head = lane >> 4, c4 = lane << 2;
  const int FOFF = GAT ? 0 : 768;
  float a0 = 0, a1 = 0, a2 = 0, a3 = 0;
  float den = GAT ? 0.0f : 1e-16f;
  int b0 = offs[d], b1 = offs[d + 1];
  float aldd = GAT ? ald[d * 4 + head] : 0.0f;
  for (int i = b0; i < b1; ++i) {
    int s = esrcs[i];
    float pe;
    if (GAT) {
      float v = als[s * 4 + head] + aldd;
      pe = expf(v >= 0.0f ? v : 0.2f * v);
    } else {
      pe = p[(size_t)eids[i] * 4 + head];
    }
    ushort4 f = *reinterpret_cast<const ushort4*>(&C1[(size_t)s * 1280 + FOFF + c4]);
    a0 = fmaf(pe, b2f(f.x), a0);
    a1 = fmaf(pe, b2f(f.y), a1);
    a2 = fmaf(pe, b2f(f.z), a2);
    a3 = fmaf(pe, b2f(f.w), a3);
    den += pe;
  }
  if (GAT) {
    float v = als[d * 4 + head] + aldd;
    float pe = expf(v >= 0.0f ? v : 0.2f * v);
    ushort4 f = *reinterpret_cast<const ushort4*>(&C1[(size_t)d * 1280 + c4]);
    a0 = fmaf(pe, b2f(f.x), a0);
    a1 = fmaf(pe, b2f(f.y), a1);
    a2 = fmaf(pe, b2f(f.z), a2);
    a3 = fmaf(pe, b2f(f.w), a3);
    den += pe;
  }
  float inv = 1.0f / den;
  float o0 = a0 * inv, o1 = a1 * inv, o2 = a2 * inv, o3 = a3 * inv;
  if (GAT) {
    o0 += bias[c4 + 0]; o1 += bias[c4 + 1]; o2 += bias[c4 + 2]; o3 += bias[c4 + 3];
  } else {
    ushort4 sk = *reinterpret_cast<const ushort4*>(&C1[(size_t)d * 1280 + 1024 + c4]);
    o0 += b2f(sk.x); o1 += b2f(sk.y); o2 += b2f(sk.z); o3 += b2f(sk.w);
  }
  o0 = o0 >= 0.0f ? o0 : pa[c4 + 0] * o0;
  o1 = o1 >= 0.0f ? o1 : pa[c4 + 1] * o1;
  o2 = o2 >= 0.0f ? o2 : pa[c4 + 2] * o2;
  o3 = o3 >= 0.0f ? o3 : pa[c4 + 3] * o3;
  ushort4 w4;
  w4.x = f2b(o0); w4.y = f2b(o1); w4.z = f2b(o2); w4.w = f2b(o3);
  *reinterpret_cast<ushort4*>(&out[(size_t)d * 256 + c4]) = w4;
}

// CSR gather-aggregate, HC=32 (1 head), 32 lanes per dst node, f32 out.
// C2 cols: q2@0 k2@32 v2@64 s2@96 gat2h@128
template <bool GAT>
__global__ void k_agg32(const int* __restrict__ offs, const int* __restrict__ eids,
                        const int* __restrict__ esrcs, const float* __restrict__ p,
                        const float* __restrict__ als, const float* __restrict__ ald,
                        const u16* __restrict__ C2, const float* __restrict__ bias,
                        const float* __restrict__ pa, float* __restrict__ out) {
  int d = blockIdx.x * 8 + (threadIdx.x >> 5);
  if (d >= NN) return;
  int l = threadIdx.x & 31;
  const int FOFF = GAT ? 128 : 64;
  float acc = 0.0f;
  float den = GAT ? 0.0f : 1e-16f;
  int b0 = offs[d], b1 = offs[d + 1];
  float aldd = GAT ? ald[d] : 0.0f;
  for (int i = b0; i < b1; ++i) {
    int s = esrcs[i];
    float pe;
    if (GAT) {
      float v = als[s] + aldd;
      pe = expf(v >= 0.0f ? v : 0.2f * v);
    } else {
      pe = p[eids[i]];
    }
    acc = fmaf(pe, b2f(C2[(size_t)s * 160 + FOFF + l]), acc);
    den += pe;
  }
  if (GAT) {
    float v = als[d] + aldd;
    float pe = expf(v >= 0.0f ? v : 0.2f * v);
    acc = fmaf(pe, b2f(C2[(size_t)d * 160 + 128 + l]), acc);
    den += pe;
  }
  float o = acc / den + (GAT ? bias[l] : b2f(C2[(size_t)d * 160 + 96 + l]));
  o = o >= 0.0f ? o : pa[l] * o;
  out[(size_t)d * 32 + l] = o;
}

// ------------------------------------------------ epilogue (round-1, proven)

__global__ void k_fuse(const float* __restrict__ xg, const float* __restrict__ xt,
                       const float* __restrict__ w, const float* __restrict__ b,
                       float* __restrict__ out, int M) {
  int t = blockIdx.x * blockDim.x + threadIdx.x;
  if (t >= M * 32) return;
  int m = t >> 5, j = t & 31;
  const float* xgp = xg + (size_t)m * 32;
  const float* xtp = xt + (size_t)m * 32;
  float acc = b[j];
#pragma unroll
  for (int i = 0; i < 32; ++i) acc = fmaf(xgp[i], w[i * 32 + j], acc);
#pragma unroll
  for (int i = 0; i < 32; ++i) acc = fmaf(xtp[i], w[(32 + i) * 32 + j], acc);
  out[t] = acc;
}

__global__ void k_gemm_bias(const float* __restrict__ A, const float* __restrict__ W,
                            const float* __restrict__ bias, float* __restrict__ C,
                            int M, int K, int Nc, int lgw) {
  int wmask = (1 << lgw) - 1;
  int n = blockIdx.x * (1 << lgw) + (threadIdx.x & wmask);
  int m = blockIdx.y * (256 >> lgw) + (threadIdx.x >> lgw);
  if (m >= M || n >= Nc) return;
  const float* a = A + (size_t)m * K;
  float acc = bias ? bias[n] : 0.0f;
#pragma unroll 4
  for (int k = 0; k < K; ++k) acc = fmaf(a[k], W[(size_t)k * Nc + n], acc);
  C[(size_t)m * Nc + n] = acc;
}

__global__ void k_colmean_sig(const float* __restrict__ x, float* __restrict__ sig, int M) {
  __shared__ float red[256];
  int j = blockIdx.x;
  float s = 0.0f;
  for (int m = threadIdx.x; m < M; m += 256) s += x[(size_t)m * 32 + j];
  red[threadIdx.x] = s;
  __syncthreads();
  for (int w = 128; w > 0; w >>= 1) {
    if (threadIdx.x < w) red[threadIdx.x] += red[threadIdx.x + w];
    __syncthreads();
  }
  if (threadIdx.x == 0) sig[j] = 1.0f / (1.0f + expf(-red[0] / (float)M));
}

__global__ void k_summary2(const float* __restrict__ sig, const float* __restrict__ w,
                           const float* __restrict__ b, float* __restrict__ out) {
  int j = threadIdx.x;
  float acc = b[j];
#pragma unroll
  for (int i = 0; i < 32; ++i) acc = fmaf(sig[i], w[i * 32 + j], acc);
  out[j] = acc;
}

__global__ void k_disc(const float* __restrict__ to, const float* __restrict__ ta,
                       const float* __restrict__ hos, const float* __restrict__ hosa,
                       const float* __restrict__ db, float* __restrict__ ret_os,
                       float* __restrict__ ret_os_a, int M) {
  int n = blockIdx.x * blockDim.x + threadIdx.x;
  if (n >= M) return;
  const float* a = to + (size_t)n * 32;
  const float* b = ta + (size_t)n * 32;
  float s_oo = 0, s_ao = 0, s_aa = 0, s_oa = 0;
#pragma unroll
  for (int i = 0; i < 32; ++i) {
    float ho = hos[i], ha = hosa[i];
    s_oo = fmaf(a[i], ho, s_oo);
    s_ao = fmaf(b[i], ho, s_ao);
    s_aa = fmaf(b[i], ha, s_aa);
    s_oa = fmaf(a[i], ha, s_oa);
  }
  float bb = db[0];
  ret_os[n * 2 + 0] = s_oo + bb;
  ret_os[n * 2 + 1] = s_ao + bb;
  ret_os_a[n * 2 + 0] = s_aa + bb;
  ret_os_a[n * 2 + 1] = s_oa + bb;
}

__global__ void k_dec1(const float* __restrict__ x2o, const int* __restrict__ idx0,
                       const int* __restrict__ idx1, const float* __restrict__ w,
                       const float* __restrict__ b1, float* __restrict__ hh) {
  int t = blockIdx.x * blockDim.x + threadIdx.x;
  if (t >= NB * 512) return;
  int bb = t >> 9, n = t & 511;
  const float* r0 = x2o + (size_t)idx0[bb] * 32;
  const float* r1 = x2o + (size_t)idx1[bb] * 32;
  float acc = b1[n];
#pragma unroll
  for (int i = 0; i < 32; ++i) acc = fmaf(r0[i], w[i * 512 + n], acc);
#pragma unroll
  for (int i = 0; i < 32; ++i) acc = fmaf(r1[i], w[(32 + i) * 512 + n], acc);
  hh[t] = fmaxf(acc, 0.0f);
}

__global__ void k_dec2(const float* __restrict__ hh, const float* __restrict__ w2,
                       const float* __restrict__ b2, const float* __restrict__ w3,
                       const float* __restrict__ b3, float* __restrict__ logo,
                       float* __restrict__ log1, int Bn) {
  int t = blockIdx.x * blockDim.x + threadIdx.x;
  if (t >= Bn * 4) return;
  int bb = t >> 2, j = t & 3;
  const float* h = hh + (size_t)bb * 512;
  if (j < 2) {
    float acc = b2[j];
    for (int k = 0; k < 512; ++k) acc = fmaf(h[k], w2[k * 2 + j], acc);
    logo[bb * 2 + j] = acc;
  } else {
    int jj = j - 2;
    float acc = b3[jj];
    for (int k = 0; k < 512; ++k) acc = fmaf(h[k], w3[k * 2 + jj], acc);
    log1[bb * 2 + jj] = acc;
  }
}

__global__ void k_advprep(const float* __restrict__ w, const float* __restrict__ b,
                          float* __restrict__ out) {
  int i = threadIdx.x;
  if (i < 32) {
    float s = 0.0f;
    for (int j = 0; j < 32; ++j) s += w[i * 32 + j];
    out[i] = s;
  } else if (i == 32) {
    float s = 0.0f;
    for (int j = 0; j < 32; ++j) s += b[j];
    out[32] = s;
  }
}

__global__ void k_adv(const float* __restrict__ x2o, const float* __restrict__ x2a,
                      const float* __restrict__ advr, float* __restrict__ logits) {
  int n = blockIdx.x * blockDim.x + threadIdx.x;
  if (n >= 2 * NN) return;
  const float* row = (n < NN) ? (x2o + (size_t)n * 32) : (x2a + (size_t)(n - NN) * 32);
  float acc = advr[32];
#pragma unroll
  for (int i = 0; i < 32; ++i) acc = fmaf(row[i], advr[i], acc);
  logits[n] = acc;
}

// ------------------------------------------------ host

extern "C" void kernel_launch(void* const* d_in, const int* in_sizes, int n_in,
                              void* d_out, int out_size, void* d_ws, size_t ws_size,
                              hipStream_t stream) {
  const float* x_o = (const float*)d_in[0];
  const float* x_a = (const float*)d_in[1];
  const float* gat1_w = (const float*)d_in[2];
  const float* gat1_asrc = (const float*)d_in[3];
  const float* gat1_adst = (const float*)d_in[4];
  const float* gat1_b = (const float*)d_in[5];
  const float* gat2_w = (const float*)d_in[6];
  const float* gat2_asrc = (const float*)d_in[7];
  const float* gat2_adst = (const float*)d_in[8];
  const float* gat2_b = (const float*)d_in[9];
  const float* pg1 = (const float*)d_in[10];
  const float* pg2 = (const float*)d_in[11];
  const float* gt1_wq = (const float*)d_in[12];
  const float* gt1_bq = (const float*)d_in[13];
  const float* gt1_wk = (const float*)d_in[14];
  const float* gt1_bk = (const float*)d_in[15];
  const float* gt1_wv = (const float*)d_in[16];
  const float* gt1_bv = (const float*)d_in[17];
  const float* gt1_ws = (const float*)d_in[18];
  const float* gt1_bs = (const float*)d_in[19];
  const float* gt2_wq = (const float*)d_in[20];
  const float* gt2_bq = (const float*)d_in[21];
  const float* gt2_wk = (const float*)d_in[22];
  const float* gt2_bk = (const float*)d_in[23];
  const float* gt2_wv = (const float*)d_in[24];
  const float* gt2_bv = (const float*)d_in[25];
  const float* gt2_ws = (const float*)d_in[26];
  const float* gt2_bs = (const float*)d_in[27];
  const float* pt1 = (const float*)d_in[28];
  const float* pt2 = (const float*)d_in[29];
  const float* fuse_w = (const float*)d_in[30];
  const float* fuse_b = (const float*)d_in[31];
  const float* mlp1_w = (const float*)d_in[32];
  const float* mlp1_b = (const float*)d_in[33];
  const float* disc_w = (const float*)d_in[34];
  const float* disc_b = (const float*)d_in[35];
  const float* fus_w1 = (const float*)d_in[36];
  const float* fus_b1 = (const float*)d_in[37];
  const float* fus_w2 = (const float*)d_in[38];
  const float* fus_b2 = (const float*)d_in[39];
  const float* fus_w3 = (const float*)d_in[40];
  const float* fus_b3 = (const float*)d_in[41];
  const float* adv_w = (const float*)d_in[42];
  const float* adv_b = (const float*)d_in[43];
  const int* ei = (const int*)d_in[44];
  const int* idxp = (const int*)d_in[45];
  const int* esrc = ei;
  const int* edst = ei + NE;
  const int* idx0 = idxp;
  const int* idx1 = idxp + NB;

  // ---- workspace carve (float units; bf16 buffers counted /2) ----
  float* w = (float*)d_ws;
  size_t o = 0;
  u16* C1 = (u16*)(w + o); o += 12800000;            // 20000*1280 bf16
  u16* C2 = (u16*)(w + o); o += 1600000;             // 20000*160 bf16
  u16* bufB = (u16*)(w + o); o += 2560000;           // 20000*256 bf16
  u16* bufE = (u16*)(w + o); o += 2560000;           // 20000*256 bf16
  float* p = w + o; o += NE * 4;                     // 1.28M
  float* als = w + o; o += NN * 4;
  float* ald = w + o; o += NN * 4;
  float* xg = w + o; o += NN * 32;
  float* xt = w + o; o += NN * 32;
  float* x2a = w + o; o += NN * 32;
  float* t_o = w + o; o += NN * 32;
  float* t_a = w + o; o += NN * 32;
  float* hh = w + o; o += NB * 512;
  float* Wp1 = w + o; o += 128 * 1280;
  float* bp1 = w + o; o += 1280;
  float* Wp2 = w + o; o += 256 * 160;
  float* bp2 = w + o; o += 160;
  int* deg = (int*)(w + o); o += NN;
  int* offs = (int*)(w + o); o += NN + 8;
  int* cur = (int*)(w + o); o += NN;
  int* eids = (int*)(w + o); o += NE;
  int* esrcs = (int*)(w + o); o += NE;
  float* sml = w + o; o += 256;
  float* sig_o = sml;
  float* sig_a = sml + 32;
  float* h_os = sml + 64;
  float* h_osa = sml + 96;
  float* advr = sml + 128;

  float* out = (float*)d_out;
  float* out_log = out;               // [B,2]
  float* out_ret = out + 8192;        // [N,2]
  float* out_reta = out + 48192;      // [N,2]
  float* out_x2o = out + 88192;       // [N,32]
  float* out_logit = out + 728192;    // [1,2N]
  float* out_log1 = out + 768192;     // [B,2]

  // ---- weight packing ----
  k_pack1<<<(128 * 1280 + 255) / 256, 256, 0, stream>>>(gat1_w, gt1_wq, gt1_wk, gt1_wv,
                                                        gt1_ws, gt1_bq, gt1_bk, gt1_bv,
                                                        gt1_bs, Wp1, bp1);
  k_pack2<<<(256 * 160 + 255) / 256, 256, 0, stream>>>(gt2_wq, gt2_wk, gt2_wv, gt2_ws,
                                                       gat2_w, gt2_bq, gt2_bk, gt2_bv,
                                                       gt2_bs, Wp2, bp2);
  // ---- CSR build ----
  hipMemsetAsync(deg, 0, NN * sizeof(int), stream);
  k_hist<<<(NE + 255) / 256, 256, 0, stream>>>(edst, deg);
  k_scan20000<<<1, 1024, 0, stream>>>(deg, offs);
  k_copyoffs<<<(NN + 255) / 256, 256, 0, stream>>>(offs, cur);
  k_scatter<<<(NE + 255) / 256, 256, 0, stream>>>(esrc, edst, cur, eids, esrcs);

  auto branch = [&](const float* x, float* x2out) {
    // layer 1: one packed GEMM -> C1 = [gat_h | q | k | v | skip] bf16
    {
      dim3 g(20, (NN + 63) / 64);
      k_gemm64<float, u16><<<g, 256, 0, stream>>>(x, x, 999, 128, Wp1, bp1, C1, NN, 128, 1280);
    }
    k_gat_al<<<(NN * 4 + 255) / 256, 256, 0, stream>>>(C1, 1280, 0, gat1_asrc, gat1_adst,
                                                       als, ald, NN * 4, 4, 64);
    k_agg256<true><<<(NN + 3) / 4, 256, 0, stream>>>(offs, eids, esrcs, nullptr, als, ald,
                                                     C1, gat1_b, pg1, bufB);
    k_logits_gt1<<<(NE * 4 + 255) / 256, 256, 0, stream>>>(esrc, edst, C1, p);
    k_agg256<false><<<(NN + 3) / 4, 256, 0, stream>>>(offs, eids, esrcs, p, nullptr,
                                                      nullptr, C1, nullptr, pt1, bufE);
    // layer 2: packed GEMM, col-blocks {0,1}=bufE (gt2), {2}=bufB (gat2)
    {
      dim3 g(3, (NN + 63) / 64);
      k_gemm64<u16, u16><<<g, 256, 0, stream>>>(bufE, bufB, 2, 256, Wp2, bp2, C2, NN, 256, 160);
    }
    k_gat_al<<<(NN + 255) / 256, 256, 0, stream>>>(C2, 160, 128, gat2_asrc, gat2_adst,
                                                   als, ald, NN, 1, 32);
    k_agg32<true><<<(NN + 7) / 8, 256, 0, stream>>>(offs, eids, esrcs, nullptr, als, ald,
                                                    C2, gat2_b, pg2, xg);
    k_logits_gt2<<<(NE + 255) / 256, 256, 0, stream>>>(esrc, edst, C2, p);
    k_agg32<false><<<(NN + 7) / 8, 256, 0, stream>>>(offs, eids, esrcs, p, nullptr,
                                                     nullptr, C2, nullptr, pt2, xt);
    k_fuse<<<(NN * 32 + 255) / 256, 256, 0, stream>>>(xg, xt, fuse_w, fuse_b, x2out, NN);
  };

  branch(x_o, out_x2o);
  branch(x_a, x2a);

  // ---- summary + discriminator ----
  k_colmean_sig<<<32, 256, 0, stream>>>(out_x2o, sig_o, NN);
  k_colmean_sig<<<32, 256, 0, stream>>>(x2a, sig_a, NN);
  k_summary2<<<1, 32, 0, stream>>>(sig_o, mlp1_w, mlp1_b, h_os);
  k_summary2<<<1, 32, 0, stream>>>(sig_a, mlp1_w, mlp1_b, h_osa);
  {
    dim3 g(1, (NN + 7) / 8);
    k_gemm_bias<<<g, 256, 0, stream>>>(out_x2o, disc_w, nullptr, t_o, NN, 32, 32, 5);
    k_gemm_bias<<<g, 256, 0, stream>>>(x2a, disc_w, nullptr, t_a, NN, 32, 32, 5);
  }
  k_disc<<<(NN + 255) / 256, 256, 0, stream>>>(t_o, t_a, h_os, h_osa, disc_b,
                                               out_ret, out_reta, NN);
  // ---- decoder ----
  k_dec1<<<(NB * 512 + 255) / 256, 256, 0, stream>>>(out_x2o, idx0, idx1, fus_w1,
                                                     fus_b1, hh);
  k_dec2<<<(NB * 4 + 255) / 256, 256, 0, stream>>>(hh, fus_w2, fus_b2, fus_w3, fus_b3,
                                                   out_log, out_log1, NB);
  // ---- adversarial logits ----
  k_advprep<<<1, 64, 0, stream>>>(adv_w, adv_b, advr);
  k_adv<<<(2 * NN + 255) / 256, 256, 0, stream>>>(out_x2o, x2a, advr, out_logit);
}

// Round 3
// 888.285 us; speedup vs baseline: 4.3830x; 1.5321x over previous
//
#include <hip/hip_runtime.h>
#include <math.h>

#define NN 20000
#define NE 320000
#define NB 4096

typedef unsigned short u16;

__device__ __forceinline__ float b2f(u16 u) {
  unsigned int x = ((unsigned int)u) << 16;
  return __uint_as_float(x);
}
__device__ __forceinline__ u16 f2b(float f) {
  unsigned int x = __float_as_uint(f);
  return (u16)((x + 0x7fffu + ((x >> 16) & 1u)) >> 16);
}

__device__ __forceinline__ float loadf(const float* p) { return *p; }
__device__ __forceinline__ float loadf(const u16* p) { return b2f(*p); }
__device__ __forceinline__ void storef(float* p, float v) { *p = v; }
__device__ __forceinline__ void storef(u16* p, float v) { *p = f2b(v); }

// ------------------------------------------------ packing

__global__ void k_pack1(const float* __restrict__ w0, const float* __restrict__ w1,
                        const float* __restrict__ w2, const float* __restrict__ w3,
                        const float* __restrict__ w4, const float* __restrict__ b1,
                        const float* __restrict__ b2, const float* __restrict__ b3,
                        const float* __restrict__ b4, float* __restrict__ Wp,
                        float* __restrict__ bp) {
  int t = blockIdx.x * blockDim.x + threadIdx.x;
  if (t < 128 * 1280) {
    int k = t / 1280, j = t - k * 1280;
    int seg = j >> 8, jj = j & 255;
    const float* s = (seg == 0) ? w0 : (seg == 1) ? w1 : (seg == 2) ? w2 : (seg == 3) ? w3 : w4;
    Wp[t] = s[k * 256 + jj];
  }
  if (t < 1280) {
    int seg = t >> 8, jj = t & 255;
    bp[t] = (seg == 0) ? 0.0f : (seg == 1) ? b1[jj] : (seg == 2) ? b2[jj] : (seg == 3) ? b3[jj] : b4[jj];
  }
}

// layout cols: [wq2|wk2|wv2|ws2|gat2_w]
__global__ void k_pack2(const float* __restrict__ wq, const float* __restrict__ wk,
                        const float* __restrict__ wv, const float* __restrict__ ws,
                        const float* __restrict__ wg, const float* __restrict__ bq,
                        const float* __restrict__ bk, const float* __restrict__ bv,
                        const float* __restrict__ bs, float* __restrict__ Wp,
                        float* __restrict__ bp) {
  int t = blockIdx.x * blockDim.x + threadIdx.x;
  if (t < 256 * 160) {
    int k = t / 160, j = t - k * 160;
    int seg = j >> 5, jj = j & 31;
    const float* s = (seg == 0) ? wq : (seg == 1) ? wk : (seg == 2) ? wv : (seg == 3) ? ws : wg;
    Wp[t] = s[k * 32 + jj];
  }
  if (t < 160) {
    int seg = t >> 5, jj = t & 31;
    bp[t] = (seg == 0) ? bq[jj] : (seg == 1) ? bk[jj] : (seg == 2) ? bv[jj] : (seg == 3) ? bs[jj] : 0.0f;
  }
}

// ------------------------------------------------ CSR build

__global__ void k_hist(const int* __restrict__ dst, int* __restrict__ deg) {
  int t = blockIdx.x * blockDim.x + threadIdx.x;
  if (t < NE) atomicAdd(&deg[dst[t]], 1);
}

__global__ void k_scan20000(const int* __restrict__ deg, int* __restrict__ offs) {
  __shared__ int part[1024];
  int t = threadIdx.x;
  int loc[20];
  int s = 0;
#pragma unroll
  for (int i = 0; i < 20; ++i) {
    int idx = t * 20 + i;
    int v = (idx < NN) ? deg[idx] : 0;
    loc[i] = s;
    s += v;
  }
  part[t] = s;
  __syncthreads();
  for (int off = 1; off < 1024; off <<= 1) {
    int v = (t >= off) ? part[t - off] : 0;
    __syncthreads();
    part[t] += v;
    __syncthreads();
  }
  int base = (t > 0) ? part[t - 1] : 0;
#pragma unroll
  for (int i = 0; i < 20; ++i) {
    int idx = t * 20 + i;
    if (idx < NN) offs[idx] = base + loc[i];
  }
  if (t == 1023) offs[NN] = part[1023];
}

__global__ void k_copyoffs(const int* __restrict__ offs, int* __restrict__ cur) {
  int t = blockIdx.x * blockDim.x + threadIdx.x;
  if (t < NN) cur[t] = offs[t];
}

__global__ void k_scatter(const int* __restrict__ src, const int* __restrict__ dst,
                          int* __restrict__ cur, int* __restrict__ esrcs) {
  int t = blockIdx.x * blockDim.x + threadIdx.x;
  if (t >= NE) return;
  int d = dst[t];
  int pos = atomicAdd(&cur[d], 1);
  esrcs[pos] = src[t];
}

// ------------------------------------------------ GEMM (64x64 tile, 4x4 reg)

template <typename TA, typename TC>
__global__ void k_gemm64(const TA* __restrict__ A0, const TA* __restrict__ A1, int asel,
                         int lda, const float* __restrict__ W,
                         const float* __restrict__ bias, TC* __restrict__ C, int M,
                         int K, int Nc) {
  __shared__ float As[16][68];
  __shared__ float Ws[16][68];
  const TA* A = (blockIdx.x >= (unsigned)asel) ? A1 : A0;
  int m0 = blockIdx.y * 64, n0 = blockIdx.x * 64;
  int tid = threadIdx.x;
  int tx = tid & 15, ty = tid >> 4;
  float acc[4][4] = {};
  for (int k0 = 0; k0 < K; k0 += 16) {
#pragma unroll
    for (int j = 0; j < 4; ++j) {
      int lin = j * 256 + tid;
      int m = lin >> 4, k = lin & 15;
      int mm = m0 + m;
      if (mm > M - 1) mm = M - 1;
      As[k][m] = loadf(&A[(size_t)mm * lda + k0 + k]);
    }
#pragma unroll
    for (int j = 0; j < 4; ++j) {
      int lin = j * 256 + tid;
      int k = lin >> 6, n = lin & 63;
      Ws[k][n] = (n0 + n < Nc) ? W[(size_t)(k0 + k) * Nc + n0 + n] : 0.0f;
    }
    __syncthreads();
#pragma unroll
    for (int kk = 0; kk < 16; ++kk) {
      float4 a4 = *reinterpret_cast<const float4*>(&As[kk][ty * 4]);
      float4 b4 = *reinterpret_cast<const float4*>(&Ws[kk][tx * 4]);
      float av[4] = {a4.x, a4.y, a4.z, a4.w};
      float bv[4] = {b4.x, b4.y, b4.z, b4.w};
#pragma unroll
      for (int i = 0; i < 4; ++i)
#pragma unroll
        for (int j = 0; j < 4; ++j) acc[i][j] = fmaf(av[i], bv[j], acc[i][j]);
    }
    __syncthreads();
  }
#pragma unroll
  for (int i = 0; i < 4; ++i) {
    int m = m0 + ty * 4 + i;
    if (m >= M) continue;
#pragma unroll
    for (int j = 0; j < 4; ++j) {
      int n = n0 + tx * 4 + j;
      if (n >= Nc) continue;
      storef(&C[(size_t)m * Nc + n], acc[i][j] + (bias ? bias[n] : 0.0f));
    }
  }
}

// ------------------------------------------------ attention pieces

__global__ void k_gat_al(const u16* __restrict__ h, int stride, int coff,
                         const float* __restrict__ asrc, const float* __restrict__ adst,
                         float* __restrict__ als, float* __restrict__ ald, int total,
                         int heads, int c) {
  int i = blockIdx.x * blockDim.x + threadIdx.x;
  if (i >= total) return;
  int node = i / heads, hd = i - node * heads;
  const u16* hp = h + (size_t)node * stride + coff + hd * c;
  const float* as = asrc + hd * c;
  const float* ad = adst + hd * c;
  float s1 = 0.0f, s2 = 0.0f;
  for (int k = 0; k < c; ++k) {
    float f = b2f(hp[k]);
    s1 = fmaf(f, as[k], s1);
    s2 = fmaf(f, ad[k], s2);
  }
  als[i] = s1;
  ald[i] = s2;
}

// GAT1 aggregate (4 heads x 64): one wave per dst. p inline from als/ald;
// + self loop, + bias, prelu -> bf16 out
__global__ void k_agg256_gat(const int* __restrict__ offs, const int* __restrict__ esrcs,
                             const float* __restrict__ als, const float* __restrict__ ald,
                             const u16* __restrict__ C1, const float* __restrict__ bias,
                             const float* __restrict__ pa, u16* __restrict__ out) {
  int d = blockIdx.x * 4 + (threadIdx.x >> 6);
  if (d >= NN) return;
  int lane = threadIdx.x & 63;
  int head = lane >> 4, c4 = lane << 2;
  float a0 = 0, a1 = 0, a2 = 0, a3 = 0, den = 0.0f;
  int b0 = offs[d], b1 = offs[d + 1];
  float aldd = ald[d * 4 + head];
  for (int i = b0; i < b1; ++i) {
    int s = esrcs[i];
    float v = als[s * 4 + head] + aldd;
    float pe = expf(v >= 0.0f ? v : 0.2f * v);
    ushort4 f = *reinterpret_cast<const ushort4*>(&C1[(size_t)s * 1280 + c4]);
    a0 = fmaf(pe, b2f(f.x), a0);
    a1 = fmaf(pe, b2f(f.y), a1);
    a2 = fmaf(pe, b2f(f.z), a2);
    a3 = fmaf(pe, b2f(f.w), a3);
    den += pe;
  }
  { // self loop
    float v = als[d * 4 + head] + aldd;
    float pe = expf(v >= 0.0f ? v : 0.2f * v);
    ushort4 f = *reinterpret_cast<const ushort4*>(&C1[(size_t)d * 1280 + c4]);
    a0 = fmaf(pe, b2f(f.x), a0);
    a1 = fmaf(pe, b2f(f.y), a1);
    a2 = fmaf(pe, b2f(f.z), a2);
    a3 = fmaf(pe, b2f(f.w), a3);
    den += pe;
  }
  float inv = 1.0f / den;
  float o0 = a0 * inv + bias[c4 + 0];
  float o1 = a1 * inv + bias[c4 + 1];
  float o2 = a2 * inv + bias[c4 + 2];
  float o3 = a3 * inv + bias[c4 + 3];
  o0 = o0 >= 0.0f ? o0 : pa[c4 + 0] * o0;
  o1 = o1 >= 0.0f ? o1 : pa[c4 + 1] * o1;
  o2 = o2 >= 0.0f ? o2 : pa[c4 + 2] * o2;
  o3 = o3 >= 0.0f ? o3 : pa[c4 + 3] * o3;
  ushort4 w4;
  w4.x = f2b(o0); w4.y = f2b(o1); w4.z = f2b(o2); w4.w = f2b(o3);
  *reinterpret_cast<ushort4*>(&out[(size_t)d * 256 + c4]) = w4;
}

// GT1 aggregate with INLINE logits: one wave per dst. q[d] in regs; per edge
// gather k[src]+v[src] (contiguous cols 512..1023), 16-lane shuffle dot,
// exp, accumulate. + skip (cols 1024..1279, incl bias), prelu -> bf16 out
__global__ void k_agg256_gt(const int* __restrict__ offs, const int* __restrict__ esrcs,
                            const u16* __restrict__ C1, const float* __restrict__ pa,
                            u16* __restrict__ out) {
  int d = blockIdx.x * 4 + (threadIdx.x >> 6);
  if (d >= NN) return;
  int lane = threadIdx.x & 63;
  int c4 = lane << 2;
  // q[d] channels for this lane (head = lane>>4 owns cols [head*64, head*64+63])
  ushort4 q4 = *reinterpret_cast<const ushort4*>(&C1[(size_t)d * 1280 + 256 + c4]);
  float q0 = b2f(q4.x), q1 = b2f(q4.y), q2 = b2f(q4.z), q3 = b2f(q4.w);
  float a0 = 0, a1 = 0, a2 = 0, a3 = 0, den = 1e-16f;
  int b0 = offs[d], b1 = offs[d + 1];
  for (int i = b0; i < b1; ++i) {
    int s = esrcs[i];
    const u16* row = &C1[(size_t)s * 1280];
    ushort4 k4 = *reinterpret_cast<const ushort4*>(&row[512 + c4]);
    ushort4 v4 = *reinterpret_cast<const ushort4*>(&row[768 + c4]);
    float pp = q0 * b2f(k4.x);
    pp = fmaf(q1, b2f(k4.y), pp);
    pp = fmaf(q2, b2f(k4.z), pp);
    pp = fmaf(q3, b2f(k4.w), pp);
    // reduce over the 16-lane head group
    pp += __shfl_xor(pp, 1, 16);
    pp += __shfl_xor(pp, 2, 16);
    pp += __shfl_xor(pp, 4, 16);
    pp += __shfl_xor(pp, 8, 16);
    float pe = expf(pp * 0.125f);
    a0 = fmaf(pe, b2f(v4.x), a0);
    a1 = fmaf(pe, b2f(v4.y), a1);
    a2 = fmaf(pe, b2f(v4.z), a2);
    a3 = fmaf(pe, b2f(v4.w), a3);
    den += pe;
  }
  float inv = 1.0f / den;
  ushort4 sk = *reinterpret_cast<const ushort4*>(&C1[(size_t)d * 1280 + 1024 + c4]);
  float o0 = a0 * inv + b2f(sk.x);
  float o1 = a1 * inv + b2f(sk.y);
  float o2 = a2 * inv + b2f(sk.z);
  float o3 = a3 * inv + b2f(sk.w);
  o0 = o0 >= 0.0f ? o0 : pa[c4 + 0] * o0;
  o1 = o1 >= 0.0f ? o1 : pa[c4 + 1] * o1;
  o2 = o2 >= 0.0f ? o2 : pa[c4 + 2] * o2;
  o3 = o3 >= 0.0f ? o3 : pa[c4 + 3] * o3;
  ushort4 w4;
  w4.x = f2b(o0); w4.y = f2b(o1); w4.z = f2b(o2); w4.w = f2b(o3);
  *reinterpret_cast<ushort4*>(&out[(size_t)d * 256 + c4]) = w4;
}

// GAT2 aggregate (1 head x 32): 32 lanes per dst, f32 out.
// C2 cols: q2@0 k2@32 v2@64 s2@96 gat2h@128
__global__ void k_agg32_gat(const int* __restrict__ offs, const int* __restrict__ esrcs,
                            const float* __restrict__ als, const float* __restrict__ ald,
                            const u16* __restrict__ C2, const float* __restrict__ bias,
                            const float* __restrict__ pa, float* __restrict__ out) {
  int d = blockIdx.x * 8 + (threadIdx.x >> 5);
  if (d >= NN) return;
  int l = threadIdx.x & 31;
  float acc = 0.0f, den = 0.0f;
  int b0 = offs[d], b1 = offs[d + 1];
  float aldd = ald[d];
  for (int i = b0; i < b1; ++i) {
    int s = esrcs[i];
    float v = als[s] + aldd;
    float pe = expf(v >= 0.0f ? v : 0.2f * v);
    acc = fmaf(pe, b2f(C2[(size_t)s * 160 + 128 + l]), acc);
    den += pe;
  }
  {
    float v = als[d] + aldd;
    float pe = expf(v >= 0.0f ? v : 0.2f * v);
    acc = fmaf(pe, b2f(C2[(size_t)d * 160 + 128 + l]), acc);
    den += pe;
  }
  float o = acc / den + bias[l];
  o = o >= 0.0f ? o : pa[l] * o;
  out[(size_t)d * 32 + l] = o;
}

// GT2 aggregate with INLINE logits: 32 lanes per dst; q2[d] in regs;
// per edge 32-lane shuffle dot over k2[src], exp, accumulate v2[src].
__global__ void k_agg32_gt(const int* __restrict__ offs, const int* __restrict__ esrcs,
                           const u16* __restrict__ C2, const float* __restrict__ pa,
                           float* __restrict__ out) {
  int d = blockIdx.x * 8 + (threadIdx.x >> 5);
  if (d >= NN) return;
  int l = threadIdx.x & 31;
  float qv = b2f(C2[(size_t)d * 160 + l]);
  float acc = 0.0f, den = 1e-16f;
  int b0 = offs[d], b1 = offs[d + 1];
  for (int i = b0; i < b1; ++i) {
    int s = esrcs[i];
    float kv = b2f(C2[(size_t)s * 160 + 32 + l]);
    float vv = b2f(C2[(size_t)s * 160 + 64 + l]);
    float pp = qv * kv;
    pp += __shfl_xor(pp, 1, 32);
    pp += __shfl_xor(pp, 2, 32);
    pp += __shfl_xor(pp, 4, 32);
    pp += __shfl_xor(pp, 8, 32);
    pp += __shfl_xor(pp, 16, 32);
    float pe = expf(pp * 0.17677669529663687f);
    acc = fmaf(pe, vv, acc);
    den += pe;
  }
  float o = acc / den + b2f(C2[(size_t)d * 160 + 96 + l]);
  o = o >= 0.0f ? o : pa[l] * o;
  out[(size_t)d * 32 + l] = o;
}

// ------------------------------------------------ epilogue (proven)

__global__ void k_fuse(const float* __restrict__ xg, const float* __restrict__ xt,
                       const float* __restrict__ w, const float* __restrict__ b,
                       float* __restrict__ out, int M) {
  int t = blockIdx.x * blockDim.x + threadIdx.x;
  if (t >= M * 32) return;
  int m = t >> 5, j = t & 31;
  const float* xgp = xg + (size_t)m * 32;
  const float* xtp = xt + (size_t)m * 32;
  float acc = b[j];
#pragma unroll
  for (int i = 0; i < 32; ++i) acc = fmaf(xgp[i], w[i * 32 + j], acc);
#pragma unroll
  for (int i = 0; i < 32; ++i) acc = fmaf(xtp[i], w[(32 + i) * 32 + j], acc);
  out[t] = acc;
}

__global__ void k_gemm_bias(const float* __restrict__ A, const float* __restrict__ W,
                            const float* __restrict__ bias, float* __restrict__ C,
                            int M, int K, int Nc, int lgw) {
  int wmask = (1 << lgw) - 1;
  int n = blockIdx.x * (1 << lgw) + (threadIdx.x & wmask);
  int m = blockIdx.y * (256 >> lgw) + (threadIdx.x >> lgw);
  if (m >= M || n >= Nc) return;
  const float* a = A + (size_t)m * K;
  float acc = bias ? bias[n] : 0.0f;
#pragma unroll 4
  for (int k = 0; k < K; ++k) acc = fmaf(a[k], W[(size_t)k * Nc + n], acc);
  C[(size_t)m * Nc + n] = acc;
}

__global__ void k_colmean_sig(const float* __restrict__ x, float* __restrict__ sig, int M) {
  __shared__ float red[256];
  int j = blockIdx.x;
  float s = 0.0f;
  for (int m = threadIdx.x; m < M; m += 256) s += x[(size_t)m * 32 + j];
  red[threadIdx.x] = s;
  __syncthreads();
  for (int w = 128; w > 0; w >>= 1) {
    if (threadIdx.x < w) red[threadIdx.x] += red[threadIdx.x + w];
    __syncthreads();
  }
  if (threadIdx.x == 0) sig[j] = 1.0f / (1.0f + expf(-red[0] / (float)M));
}

__global__ void k_summary2(const float* __restrict__ sig, const float* __restrict__ w,
                           const float* __restrict__ b, float* __restrict__ out) {
  int j = threadIdx.x;
  float acc = b[j];
#pragma unroll
  for (int i = 0; i < 32; ++i) acc = fmaf(sig[i], w[i * 32 + j], acc);
  out[j] = acc;
}

__global__ void k_disc(const float* __restrict__ to, const float* __restrict__ ta,
                       const float* __restrict__ hos, const float* __restrict__ hosa,
                       const float* __restrict__ db, float* __restrict__ ret_os,
                       float* __restrict__ ret_os_a, int M) {
  int n = blockIdx.x * blockDim.x + threadIdx.x;
  if (n >= M) return;
  const float* a = to + (size_t)n * 32;
  const float* b = ta + (size_t)n * 32;
  float s_oo = 0, s_ao = 0, s_aa = 0, s_oa = 0;
#pragma unroll
  for (int i = 0; i < 32; ++i) {
    float ho = hos[i], ha = hosa[i];
    s_oo = fmaf(a[i], ho, s_oo);
    s_ao = fmaf(b[i], ho, s_ao);
    s_aa = fmaf(b[i], ha, s_aa);
    s_oa = fmaf(a[i], ha, s_oa);
  }
  float bb = db[0];
  ret_os[n * 2 + 0] = s_oo + bb;
  ret_os[n * 2 + 1] = s_ao + bb;
  ret_os_a[n * 2 + 0] = s_aa + bb;
  ret_os_a[n * 2 + 1] = s_oa + bb;
}

__global__ void k_dec1(const float* __restrict__ x2o, const int* __restrict__ idx0,
                       const int* __restrict__ idx1, const float* __restrict__ w,
                       const float* __restrict__ b1, float* __restrict__ hh) {
  int t = blockIdx.x * blockDim.x + threadIdx.x;
  if (t >= NB * 512) return;
  int bb = t >> 9, n = t & 511;
  const float* r0 = x2o + (size_t)idx0[bb] * 32;
  const float* r1 = x2o + (size_t)idx1[bb] * 32;
  float acc = b1[n];
#pragma unroll
  for (int i = 0; i < 32; ++i) acc = fmaf(r0[i], w[i * 512 + n], acc);
#pragma unroll
  for (int i = 0; i < 32; ++i) acc = fmaf(r1[i], w[(32 + i) * 512 + n], acc);
  hh[t] = fmaxf(acc, 0.0f);
}

__global__ void k_dec2(const float* __restrict__ hh, const float* __restrict__ w2,
                       const float* __restrict__ b2, const float* __restrict__ w3,
                       const float* __restrict__ b3, float* __restrict__ logo,
                       float* __restrict__ log1, int Bn) {
  int t = blockIdx.x * blockDim.x + threadIdx.x;
  if (t >= Bn * 4) return;
  int bb = t >> 2, j = t & 3;
  const float* h = hh + (size_t)bb * 512;
  if (j < 2) {
    float acc = b2[j];
    for (int k = 0; k < 512; ++k) acc = fmaf(h[k], w2[k * 2 + j], acc);
    logo[bb * 2 + j] = acc;
  } else {
    int jj = j - 2;
    float acc = b3[jj];
    for (int k = 0; k < 512; ++k) acc = fmaf(h[k], w3[k * 2 + jj], acc);
    log1[bb * 2 + jj] = acc;
  }
}

__global__ void k_advprep(const float* __restrict__ w, const float* __restrict__ b,
                          float* __restrict__ out) {
  int i = threadIdx.x;
  if (i < 32) {
    float s = 0.0f;
    for (int j = 0; j < 32; ++j) s += w[i * 32 + j];
    out[i] = s;
  } else if (i == 32) {
    float s = 0.0f;
    for (int j = 0; j < 32; ++j) s += b[j];
    out[32] = s;
  }
}

__global__ void k_adv(const float* __restrict__ x2o, const float* __restrict__ x2a,
                      const float* __restrict__ advr, float* __restrict__ logits) {
  int n = blockIdx.x * blockDim.x + threadIdx.x;
  if (n >= 2 * NN) return;
  const float* row = (n < NN) ? (x2o + (size_t)n * 32) : (x2a + (size_t)(n - NN) * 32);
  float acc = advr[32];
#pragma unroll
  for (int i = 0; i < 32; ++i) acc = fmaf(row[i], advr[i], acc);
  logits[n] = acc;
}

// ------------------------------------------------ host

extern "C" void kernel_launch(void* const* d_in, const int* in_sizes, int n_in,
                              void* d_out, int out_size, void* d_ws, size_t ws_size,
                              hipStream_t stream) {
  const float* x_o = (const float*)d_in[0];
  const float* x_a = (const float*)d_in[1];
  const float* gat1_w = (const float*)d_in[2];
  const float* gat1_asrc = (const float*)d_in[3];
  const float* gat1_adst = (const float*)d_in[4];
  const float* gat1_b = (const float*)d_in[5];
  const float* gat2_w = (const float*)d_in[6];
  const float* gat2_asrc = (const float*)d_in[7];
  const float* gat2_adst = (const float*)d_in[8];
  const float* gat2_b = (const float*)d_in[9];
  const float* pg1 = (const float*)d_in[10];
  const float* pg2 = (const float*)d_in[11];
  const float* gt1_wq = (const float*)d_in[12];
  const float* gt1_bq = (const float*)d_in[13];
  const float* gt1_wk = (const float*)d_in[14];
  const float* gt1_bk = (const float*)d_in[15];
  const float* gt1_wv = (const float*)d_in[16];
  const float* gt1_bv = (const float*)d_in[17];
  const float* gt1_ws = (const float*)d_in[18];
  const float* gt1_bs = (const float*)d_in[19];
  const float* gt2_wq = (const float*)d_in[20];
  const float* gt2_bq = (const float*)d_in[21];
  const float* gt2_wk = (const float*)d_in[22];
  const float* gt2_bk = (const float*)d_in[23];
  const float* gt2_wv = (const float*)d_in[24];
  const float* gt2_bv = (const float*)d_in[25];
  const float* gt2_ws = (const float*)d_in[26];
  const float* gt2_bs = (const float*)d_in[27];
  const float* pt1 = (const float*)d_in[28];
  const float* pt2 = (const float*)d_in[29];
  const float* fuse_w = (const float*)d_in[30];
  const float* fuse_b = (const float*)d_in[31];
  const float* mlp1_w = (const float*)d_in[32];
  const float* mlp1_b = (const float*)d_in[33];
  const float* disc_w = (const float*)d_in[34];
  const float* disc_b = (const float*)d_in[35];
  const float* fus_w1 = (const float*)d_in[36];
  const float* fus_b1 = (const float*)d_in[37];
  const float* fus_w2 = (const float*)d_in[38];
  const float* fus_b2 = (const float*)d_in[39];
  const float* fus_w3 = (const float*)d_in[40];
  const float* fus_b3 = (const float*)d_in[41];
  const float* adv_w = (const float*)d_in[42];
  const float* adv_b = (const float*)d_in[43];
  const int* ei = (const int*)d_in[44];
  const int* idxp = (const int*)d_in[45];
  const int* esrc = ei;
  const int* edst = ei + NE;
  const int* idx0 = idxp;
  const int* idx1 = idxp + NB;

  // ---- workspace carve (float units; bf16 buffers counted /2) ----
  float* w = (float*)d_ws;
  size_t o = 0;
  u16* C1 = (u16*)(w + o); o += 12800000;            // 20000*1280 bf16
  u16* C2 = (u16*)(w + o); o += 1600000;             // 20000*160 bf16
  u16* bufB = (u16*)(w + o); o += 2560000;           // 20000*256 bf16
  u16* bufE = (u16*)(w + o); o += 2560000;           // 20000*256 bf16
  float* als = w + o; o += NN * 4;
  float* ald = w + o; o += NN * 4;
  float* xg = w + o; o += NN * 32;
  float* xt = w + o; o += NN * 32;
  float* x2a = w + o; o += NN * 32;
  float* t_o = w + o; o += NN * 32;
  float* t_a = w + o; o += NN * 32;
  float* hh = w + o; o += NB * 512;
  float* Wp1 = w + o; o += 128 * 1280;
  float* bp1 = w + o; o += 1280;
  float* Wp2 = w + o; o += 256 * 160;
  float* bp2 = w + o; o += 160;
  int* deg = (int*)(w + o); o += NN;
  int* offs = (int*)(w + o); o += NN + 8;
  int* cur = (int*)(w + o); o += NN;
  int* esrcs = (int*)(w + o); o += NE;
  float* sml = w + o; o += 256;
  float* sig_o = sml;
  float* sig_a = sml + 32;
  float* h_os = sml + 64;
  float* h_osa = sml + 96;
  float* advr = sml + 128;

  float* out = (float*)d_out;
  float* out_log = out;               // [B,2]
  float* out_ret = out + 8192;        // [N,2]
  float* out_reta = out + 48192;      // [N,2]
  float* out_x2o = out + 88192;       // [N,32]
  float* out_logit = out + 728192;    // [1,2N]
  float* out_log1 = out + 768192;     // [B,2]

  // ---- weight packing ----
  k_pack1<<<(128 * 1280 + 255) / 256, 256, 0, stream>>>(gat1_w, gt1_wq, gt1_wk, gt1_wv,
                                                        gt1_ws, gt1_bq, gt1_bk, gt1_bv,
                                                        gt1_bs, Wp1, bp1);
  k_pack2<<<(256 * 160 + 255) / 256, 256, 0, stream>>>(gt2_wq, gt2_wk, gt2_wv, gt2_ws,
                                                       gat2_w, gt2_bq, gt2_bk, gt2_bv,
                                                       gt2_bs, Wp2, bp2);
  // ---- CSR build ----
  hipMemsetAsync(deg, 0, NN * sizeof(int), stream);
  k_hist<<<(NE + 255) / 256, 256, 0, stream>>>(edst, deg);
  k_scan20000<<<1, 1024, 0, stream>>>(deg, offs);
  k_copyoffs<<<(NN + 255) / 256, 256, 0, stream>>>(offs, cur);
  k_scatter<<<(NE + 255) / 256, 256, 0, stream>>>(esrc, edst, cur, esrcs);

  auto branch = [&](const float* x, float* x2out) {
    // layer 1: one packed GEMM -> C1 = [gat_h | q | k | v | skip] bf16
    {
      dim3 g(20, (NN + 63) / 64);
      k_gemm64<float, u16><<<g, 256, 0, stream>>>(x, x, 999, 128, Wp1, bp1, C1, NN, 128, 1280);
    }
    k_gat_al<<<(NN * 4 + 255) / 256, 256, 0, stream>>>(C1, 1280, 0, gat1_asrc, gat1_adst,
                                                       als, ald, NN * 4, 4, 64);
    k_agg256_gat<<<(NN + 3) / 4, 256, 0, stream>>>(offs, esrcs, als, ald, C1, gat1_b,
                                                   pg1, bufB);
    k_agg256_gt<<<(NN + 3) / 4, 256, 0, stream>>>(offs, esrcs, C1, pt1, bufE);
    // layer 2: packed GEMM, col-blocks {0,1}=bufE (gt2), {2}=bufB (gat2)
    {
      dim3 g(3, (NN + 63) / 64);
      k_gemm64<u16, u16><<<g, 256, 0, stream>>>(bufE, bufB, 2, 256, Wp2, bp2, C2, NN, 256, 160);
    }
    k_gat_al<<<(NN + 255) / 256, 256, 0, stream>>>(C2, 160, 128, gat2_asrc, gat2_adst,
                                                   als, ald, NN, 1, 32);
    k_agg32_gat<<<(NN + 7) / 8, 256, 0, stream>>>(offs, esrcs, als, ald, C2, gat2_b,
                                                  pg2, xg);
    k_agg32_gt<<<(NN + 7) / 8, 256, 0, stream>>>(offs, esrcs, C2, pt2, xt);
    k_fuse<<<(NN * 32 + 255) / 256, 256, 0, stream>>>(xg, xt, fuse_w, fuse_b, x2out, NN);
  };

  branch(x_o, out_x2o);
  branch(x_a, x2a);

  // ---- summary + discriminator ----
  k_colmean_sig<<<32, 256, 0, stream>>>(out_x2o, sig_o, NN);
  k_colmean_sig<<<32, 256, 0, stream>>>(x2a, sig_a, NN);
  k_summary2<<<1, 32, 0, stream>>>(sig_o, mlp1_w, mlp1_b, h_os);
  k_summary2<<<1, 32, 0, stream>>>(sig_a, mlp1_w, mlp1_b, h_osa);
  {
    dim3 g(1, (NN + 7) / 8);
    k_gemm_bias<<<g, 256, 0, stream>>>(out_x2o, disc_w, nullptr, t_o, NN, 32, 32, 5);
    k_gemm_bias<<<g, 256, 0, stream>>>(x2a, disc_w, nullptr, t_a, NN, 32, 32, 5);
  }
  k_disc<<<(NN + 255) / 256, 256, 0, stream>>>(t_o, t_a, h_os, h_osa, disc_b,
                                               out_ret, out_reta, NN);
  // ---- decoder ----
  k_dec1<<<(NB * 512 + 255) / 256, 256, 0, stream>>>(out_x2o, idx0, idx1, fus_w1,
                                                     fus_b1, hh);
  k_dec2<<<(NB * 4 + 255) / 256, 256, 0, stream>>>(hh, fus_w2, fus_b2, fus_w3, fus_b3,
                                                   out_log, out_log1, NB);
  // ---- adversarial logits ----
  k_advprep<<<1, 64, 0, stream>>>(adv_w, adv_b, advr);
  k_adv<<<(2 * NN + 255) / 256, 256, 0, stream>>>(out_x2o, x2a, advr, out_logit);
}

// Round 4
// 779.629 us; speedup vs baseline: 4.9939x; 1.1394x over previous
//
#include <hip/hip_runtime.h>
#include <math.h>

#define NN 20000
#define NE 320000
#define NB 4096

typedef unsigned short u16;
typedef __attribute__((ext_vector_type(8))) short short8;
typedef __attribute__((ext_vector_type(4))) float f32x4;

__device__ __forceinline__ float b2f(u16 u) {
  unsigned int x = ((unsigned int)u) << 16;
  return __uint_as_float(x);
}
__device__ __forceinline__ u16 f2b(float f) {
  unsigned int x = __float_as_uint(f);
  return (u16)((x + 0x7fffu + ((x >> 16) & 1u)) >> 16);
}

// ------------------------------------------------ packing (transposed bf16 weights)

// Wt1[j][k] (j<1280, k<128) bf16 = seg(j)[k][j&255]; bp1[j] f32
__global__ void k_pack1(const float* __restrict__ w0, const float* __restrict__ w1,
                        const float* __restrict__ w2, const float* __restrict__ w3,
                        const float* __restrict__ w4, const float* __restrict__ b1,
                        const float* __restrict__ b2, const float* __restrict__ b3,
                        const float* __restrict__ b4, u16* __restrict__ Wt,
                        float* __restrict__ bp) {
  int t = blockIdx.x * blockDim.x + threadIdx.x;
  if (t < 1280 * 128) {
    int j = t >> 7, k = t & 127;
    int seg = j >> 8, jj = j & 255;
    const float* s = (seg == 0) ? w0 : (seg == 1) ? w1 : (seg == 2) ? w2 : (seg == 3) ? w3 : w4;
    Wt[t] = f2b(s[k * 256 + jj]);
  }
  if (t < 1280) {
    int seg = t >> 8, jj = t & 255;
    bp[t] = (seg == 0) ? 0.0f : (seg == 1) ? b1[jj] : (seg == 2) ? b2[jj] : (seg == 3) ? b3[jj] : b4[jj];
  }
}

// cols: [wq2|wk2|wv2|ws2|gat2_w]; Wt2[j][k] (j<160, k<256)
__global__ void k_pack2(const float* __restrict__ wq, const float* __restrict__ wk,
                        const float* __restrict__ wv, const float* __restrict__ ws,
                        const float* __restrict__ wg, const float* __restrict__ bq,
                        const float* __restrict__ bk, const float* __restrict__ bv,
                        const float* __restrict__ bs, u16* __restrict__ Wt,
                        float* __restrict__ bp) {
  int t = blockIdx.x * blockDim.x + threadIdx.x;
  if (t < 160 * 256) {
    int j = t >> 8, k = t & 255;
    int seg = j >> 5, jj = j & 31;
    const float* s = (seg == 0) ? wq : (seg == 1) ? wk : (seg == 2) ? wv : (seg == 3) ? ws : wg;
    Wt[t] = f2b(s[k * 32 + jj]);
  }
  if (t < 160) {
    int seg = t >> 5, jj = t & 31;
    bp[t] = (seg == 0) ? bq[jj] : (seg == 1) ? bk[jj] : (seg == 2) ? bv[jj] : (seg == 3) ? bs[jj] : 0.0f;
  }
}

__global__ void k_tobf16(const float* __restrict__ x, u16* __restrict__ xb, int total) {
  int t = blockIdx.x * blockDim.x + threadIdx.x;
  if (t < total) xb[t] = f2b(x[t]);
}

// ------------------------------------------------ CSR build

__global__ void k_hist(const int* __restrict__ dst, int* __restrict__ deg) {
  int t = blockIdx.x * blockDim.x + threadIdx.x;
  if (t < NE) atomicAdd(&deg[dst[t]], 1);
}

__global__ void k_scan20000(const int* __restrict__ deg, int* __restrict__ offs) {
  __shared__ int part[1024];
  int t = threadIdx.x;
  int loc[20];
  int s = 0;
#pragma unroll
  for (int i = 0; i < 20; ++i) {
    int idx = t * 20 + i;
    int v = (idx < NN) ? deg[idx] : 0;
    loc[i] = s;
    s += v;
  }
  part[t] = s;
  __syncthreads();
  for (int off = 1; off < 1024; off <<= 1) {
    int v = (t >= off) ? part[t - off] : 0;
    __syncthreads();
    part[t] += v;
    __syncthreads();
  }
  int base = (t > 0) ? part[t - 1] : 0;
#pragma unroll
  for (int i = 0; i < 20; ++i) {
    int idx = t * 20 + i;
    if (idx < NN) offs[idx] = base + loc[i];
  }
  if (t == 1023) offs[NN] = part[1023];
}

__global__ void k_copyoffs(const int* __restrict__ offs, int* __restrict__ cur) {
  int t = blockIdx.x * blockDim.x + threadIdx.x;
  if (t < NN) cur[t] = offs[t];
}

__global__ void k_scatter(const int* __restrict__ src, const int* __restrict__ dst,
                          int* __restrict__ cur, int* __restrict__ esrcs) {
  int t = blockIdx.x * blockDim.x + threadIdx.x;
  if (t >= NE) return;
  int d = dst[t];
  int pos = atomicAdd(&cur[d], 1);
  esrcs[pos] = src[t];
}

// ------------------------------------------------ MFMA GEMM
// C[M,Nc] = A[M,K](bf16) @ Wt[Nc,K]^T (+bias). 256 thr = 2x2 waves, 128x128/block.
// A/B frag: row/col = lane&15, k = (lane>>4)*8 + 0..7 (contiguous 8).
// C/D frag: col = lane&15, row = (lane>>4)*4 + reg.
__global__ void k_mfma_gemm(const u16* __restrict__ A0, const u16* __restrict__ A1,
                            int asel, const u16* __restrict__ Bt,
                            const float* __restrict__ bias, u16* __restrict__ C,
                            int M, int K, int Nc) {
  const u16* A = (blockIdx.x >= (unsigned)asel) ? A1 : A0;
  int m0 = blockIdx.y * 128, n0 = blockIdx.x * 128;
  int wid = threadIdx.x >> 6, lane = threadIdx.x & 63;
  int mw = m0 + (wid & 1) * 64, nw = n0 + (wid >> 1) * 64;
  int arow = mw + (lane & 15);
  int bcol = nw + (lane & 15);
  int kblk = (lane >> 4) * 8;
  f32x4 acc[4][4] = {};
  const short8 zero8 = {0, 0, 0, 0, 0, 0, 0, 0};
  for (int k0 = 0; k0 < K; k0 += 32) {
    short8 af[4], bf[4];
#pragma unroll
    for (int mf = 0; mf < 4; ++mf) {
      int r = arow + mf * 16;
      if (r > M - 1) r = M - 1;
      af[mf] = *reinterpret_cast<const short8*>(&A[(size_t)r * K + k0 + kblk]);
    }
#pragma unroll
    for (int nf = 0; nf < 4; ++nf) {
      int c = bcol + nf * 16;
      bf[nf] = (c < Nc) ? *reinterpret_cast<const short8*>(&Bt[(size_t)c * K + k0 + kblk])
                        : zero8;
    }
#pragma unroll
    for (int mf = 0; mf < 4; ++mf)
#pragma unroll
      for (int nf = 0; nf < 4; ++nf)
        acc[mf][nf] = __builtin_amdgcn_mfma_f32_16x16x32_bf16(af[mf], bf[nf],
                                                              acc[mf][nf], 0, 0, 0);
  }
#pragma unroll
  for (int nf = 0; nf < 4; ++nf) {
    int col = nw + nf * 16 + (lane & 15);
    if (col >= Nc) continue;
    float bs = bias ? bias[col] : 0.0f;
#pragma unroll
    for (int mf = 0; mf < 4; ++mf) {
      int rbase = mw + mf * 16 + (lane >> 4) * 4;
#pragma unroll
      for (int r = 0; r < 4; ++r) {
        int row = rbase + r;
        if (row < M) C[(size_t)row * Nc + col] = f2b(acc[mf][nf][r] + bs);
      }
    }
  }
}

// ------------------------------------------------ attention pieces

__global__ void k_gat_al(const u16* __restrict__ h, int stride, int coff,
                         const float* __restrict__ asrc, const float* __restrict__ adst,
                         float* __restrict__ als, float* __restrict__ ald, int total,
                         int heads, int c) {
  int i = blockIdx.x * blockDim.x + threadIdx.x;
  if (i >= total) return;
  int node = i / heads, hd = i - node * heads;
  const u16* hp = h + (size_t)node * stride + coff + hd * c;
  const float* as = asrc + hd * c;
  const float* ad = adst + hd * c;
  float s1 = 0.0f, s2 = 0.0f;
  for (int k = 0; k < c; ++k) {
    float f = b2f(hp[k]);
    s1 = fmaf(f, as[k], s1);
    s2 = fmaf(f, ad[k], s2);
  }
  als[i] = s1;
  ald[i] = s2;
}

// GAT1 aggregate (4 heads x 64): one wave per dst.
__global__ void k_agg256_gat(const int* __restrict__ offs, const int* __restrict__ esrcs,
                             const float* __restrict__ als, const float* __restrict__ ald,
                             const u16* __restrict__ C1, const float* __restrict__ bias,
                             const float* __restrict__ pa, u16* __restrict__ out) {
  int d = blockIdx.x * 4 + (threadIdx.x >> 6);
  if (d >= NN) return;
  int lane = threadIdx.x & 63;
  int head = lane >> 4, c4 = lane << 2;
  float a0 = 0, a1 = 0, a2 = 0, a3 = 0, den = 0.0f;
  int b0 = offs[d], b1 = offs[d + 1];
  float aldd = ald[d * 4 + head];
  for (int i = b0; i < b1; ++i) {
    int s = esrcs[i];
    float v = als[s * 4 + head] + aldd;
    float pe = expf(v >= 0.0f ? v : 0.2f * v);
    ushort4 f = *reinterpret_cast<const ushort4*>(&C1[(size_t)s * 1280 + c4]);
    a0 = fmaf(pe, b2f(f.x), a0);
    a1 = fmaf(pe, b2f(f.y), a1);
    a2 = fmaf(pe, b2f(f.z), a2);
    a3 = fmaf(pe, b2f(f.w), a3);
    den += pe;
  }
  { // self loop
    float v = als[d * 4 + head] + aldd;
    float pe = expf(v >= 0.0f ? v : 0.2f * v);
    ushort4 f = *reinterpret_cast<const ushort4*>(&C1[(size_t)d * 1280 + c4]);
    a0 = fmaf(pe, b2f(f.x), a0);
    a1 = fmaf(pe, b2f(f.y), a1);
    a2 = fmaf(pe, b2f(f.z), a2);
    a3 = fmaf(pe, b2f(f.w), a3);
    den += pe;
  }
  float inv = 1.0f / den;
  float o0 = a0 * inv + bias[c4 + 0];
  float o1 = a1 * inv + bias[c4 + 1];
  float o2 = a2 * inv + bias[c4 + 2];
  float o3 = a3 * inv + bias[c4 + 3];
  o0 = o0 >= 0.0f ? o0 : pa[c4 + 0] * o0;
  o1 = o1 >= 0.0f ? o1 : pa[c4 + 1] * o1;
  o2 = o2 >= 0.0f ? o2 : pa[c4 + 2] * o2;
  o3 = o3 >= 0.0f ? o3 : pa[c4 + 3] * o3;
  ushort4 w4;
  w4.x = f2b(o0); w4.y = f2b(o1); w4.z = f2b(o2); w4.w = f2b(o3);
  *reinterpret_cast<ushort4*>(&out[(size_t)d * 256 + c4]) = w4;
}

// GT1 aggregate with inline logits: one wave per dst.
__global__ void k_agg256_gt(const int* __restrict__ offs, const int* __restrict__ esrcs,
                            const u16* __restrict__ C1, const float* __restrict__ pa,
                            u16* __restrict__ out) {
  int d = blockIdx.x * 4 + (threadIdx.x >> 6);
  if (d >= NN) return;
  int lane = threadIdx.x & 63;
  int c4 = lane << 2;
  ushort4 q4 = *reinterpret_cast<const ushort4*>(&C1[(size_t)d * 1280 + 256 + c4]);
  float q0 = b2f(q4.x), q1 = b2f(q4.y), q2 = b2f(q4.z), q3 = b2f(q4.w);
  float a0 = 0, a1 = 0, a2 = 0, a3 = 0, den = 1e-16f;
  int b0 = offs[d], b1 = offs[d + 1];
  for (int i = b0; i < b1; ++i) {
    int s = esrcs[i];
    const u16* row = &C1[(size_t)s * 1280];
    ushort4 k4 = *reinterpret_cast<const ushort4*>(&row[512 + c4]);
    ushort4 v4 = *reinterpret_cast<const ushort4*>(&row[768 + c4]);
    float pp = q0 * b2f(k4.x);
    pp = fmaf(q1, b2f(k4.y), pp);
    pp = fmaf(q2, b2f(k4.z), pp);
    pp = fmaf(q3, b2f(k4.w), pp);
    pp += __shfl_xor(pp, 1, 16);
    pp += __shfl_xor(pp, 2, 16);
    pp += __shfl_xor(pp, 4, 16);
    pp += __shfl_xor(pp, 8, 16);
    float pe = expf(pp * 0.125f);
    a0 = fmaf(pe, b2f(v4.x), a0);
    a1 = fmaf(pe, b2f(v4.y), a1);
    a2 = fmaf(pe, b2f(v4.z), a2);
    a3 = fmaf(pe, b2f(v4.w), a3);
    den += pe;
  }
  float inv = 1.0f / den;
  ushort4 sk = *reinterpret_cast<const ushort4*>(&C1[(size_t)d * 1280 + 1024 + c4]);
  float o0 = a0 * inv + b2f(sk.x);
  float o1 = a1 * inv + b2f(sk.y);
  float o2 = a2 * inv + b2f(sk.z);
  float o3 = a3 * inv + b2f(sk.w);
  o0 = o0 >= 0.0f ? o0 : pa[c4 + 0] * o0;
  o1 = o1 >= 0.0f ? o1 : pa[c4 + 1] * o1;
  o2 = o2 >= 0.0f ? o2 : pa[c4 + 2] * o2;
  o3 = o3 >= 0.0f ? o3 : pa[c4 + 3] * o3;
  ushort4 w4;
  w4.x = f2b(o0); w4.y = f2b(o1); w4.z = f2b(o2); w4.w = f2b(o3);
  *reinterpret_cast<ushort4*>(&out[(size_t)d * 256 + c4]) = w4;
}

// GAT2 aggregate (1 head x 32). C2 cols: q2@0 k2@32 v2@64 s2@96 gat2h@128
__global__ void k_agg32_gat(const int* __restrict__ offs, const int* __restrict__ esrcs,
                            const float* __restrict__ als, const float* __restrict__ ald,
                            const u16* __restrict__ C2, const float* __restrict__ bias,
                            const float* __restrict__ pa, float* __restrict__ out) {
  int d = blockIdx.x * 8 + (threadIdx.x >> 5);
  if (d >= NN) return;
  int l = threadIdx.x & 31;
  float acc = 0.0f, den = 0.0f;
  int b0 = offs[d], b1 = offs[d + 1];
  float aldd = ald[d];
  for (int i = b0; i < b1; ++i) {
    int s = esrcs[i];
    float v = als[s] + aldd;
    float pe = expf(v >= 0.0f ? v : 0.2f * v);
    acc = fmaf(pe, b2f(C2[(size_t)s * 160 + 128 + l]), acc);
    den += pe;
  }
  {
    float v = als[d] + aldd;
    float pe = expf(v >= 0.0f ? v : 0.2f * v);
    acc = fmaf(pe, b2f(C2[(size_t)d * 160 + 128 + l]), acc);
    den += pe;
  }
  float o = acc / den + bias[l];
  o = o >= 0.0f ? o : pa[l] * o;
  out[(size_t)d * 32 + l] = o;
}

// GT2 aggregate with inline logits.
__global__ void k_agg32_gt(const int* __restrict__ offs, const int* __restrict__ esrcs,
                           const u16* __restrict__ C2, const float* __restrict__ pa,
                           float* __restrict__ out) {
  int d = blockIdx.x * 8 + (threadIdx.x >> 5);
  if (d >= NN) return;
  int l = threadIdx.x & 31;
  float qv = b2f(C2[(size_t)d * 160 + l]);
  float acc = 0.0f, den = 1e-16f;
  int b0 = offs[d], b1 = offs[d + 1];
  for (int i = b0; i < b1; ++i) {
    int s = esrcs[i];
    float kv = b2f(C2[(size_t)s * 160 + 32 + l]);
    float vv = b2f(C2[(size_t)s * 160 + 64 + l]);
    float pp = qv * kv;
    pp += __shfl_xor(pp, 1, 32);
    pp += __shfl_xor(pp, 2, 32);
    pp += __shfl_xor(pp, 4, 32);
    pp += __shfl_xor(pp, 8, 32);
    pp += __shfl_xor(pp, 16, 32);
    float pe = expf(pp * 0.17677669529663687f);
    acc = fmaf(pe, vv, acc);
    den += pe;
  }
  float o = acc / den + b2f(C2[(size_t)d * 160 + 96 + l]);
  o = o >= 0.0f ? o : pa[l] * o;
  out[(size_t)d * 32 + l] = o;
}

// ------------------------------------------------ epilogue (proven)

__global__ void k_fuse(const float* __restrict__ xg, const float* __restrict__ xt,
                       const float* __restrict__ w, const float* __restrict__ b,
                       float* __restrict__ out, int M) {
  int t = blockIdx.x * blockDim.x + threadIdx.x;
  if (t >= M * 32) return;
  int m = t >> 5, j = t & 31;
  const float* xgp = xg + (size_t)m * 32;
  const float* xtp = xt + (size_t)m * 32;
  float acc = b[j];
#pragma unroll
  for (int i = 0; i < 32; ++i) acc = fmaf(xgp[i], w[i * 32 + j], acc);
#pragma unroll
  for (int i = 0; i < 32; ++i) acc = fmaf(xtp[i], w[(32 + i) * 32 + j], acc);
  out[t] = acc;
}

__global__ void k_gemm_bias(const float* __restrict__ A, const float* __restrict__ W,
                            const float* __restrict__ bias, float* __restrict__ C,
                            int M, int K, int Nc, int lgw) {
  int wmask = (1 << lgw) - 1;
  int n = blockIdx.x * (1 << lgw) + (threadIdx.x & wmask);
  int m = blockIdx.y * (256 >> lgw) + (threadIdx.x >> lgw);
  if (m >= M || n >= Nc) return;
  const float* a = A + (size_t)m * K;
  float acc = bias ? bias[n] : 0.0f;
#pragma unroll 4
  for (int k = 0; k < K; ++k) acc = fmaf(a[k], W[(size_t)k * Nc + n], acc);
  C[(size_t)m * Nc + n] = acc;
}

__global__ void k_colmean_sig(const float* __restrict__ x, float* __restrict__ sig, int M) {
  __shared__ float red[256];
  int j = blockIdx.x;
  float s = 0.0f;
  for (int m = threadIdx.x; m < M; m += 256) s += x[(size_t)m * 32 + j];
  red[threadIdx.x] = s;
  __syncthreads();
  for (int w = 128; w > 0; w >>= 1) {
    if (threadIdx.x < w) red[threadIdx.x] += red[threadIdx.x + w];
    __syncthreads();
  }
  if (threadIdx.x == 0) sig[j] = 1.0f / (1.0f + expf(-red[0] / (float)M));
}

__global__ void k_summary2(const float* __restrict__ sig, const float* __restrict__ w,
                           const float* __restrict__ b, float* __restrict__ out) {
  int j = threadIdx.x;
  float acc = b[j];
#pragma unroll
  for (int i = 0; i < 32; ++i) acc = fmaf(sig[i], w[i * 32 + j], acc);
  out[j] = acc;
}

__global__ void k_disc(const float* __restrict__ to, const float* __restrict__ ta,
                       const float* __restrict__ hos, const float* __restrict__ hosa,
                       const float* __restrict__ db, float* __restrict__ ret_os,
                       float* __restrict__ ret_os_a, int M) {
  int n = blockIdx.x * blockDim.x + threadIdx.x;
  if (n >= M) return;
  const float* a = to + (size_t)n * 32;
  const float* b = ta + (size_t)n * 32;
  float s_oo = 0, s_ao = 0, s_aa = 0, s_oa = 0;
#pragma unroll
  for (int i = 0; i < 32; ++i) {
    float ho = hos[i], ha = hosa[i];
    s_oo = fmaf(a[i], ho, s_oo);
    s_ao = fmaf(b[i], ho, s_ao);
    s_aa = fmaf(b[i], ha, s_aa);
    s_oa = fmaf(a[i], ha, s_oa);
  }
  float bb = db[0];
  ret_os[n * 2 + 0] = s_oo + bb;
  ret_os[n * 2 + 1] = s_ao + bb;
  ret_os_a[n * 2 + 0] = s_aa + bb;
  ret_os_a[n * 2 + 1] = s_oa + bb;
}

__global__ void k_dec1(const float* __restrict__ x2o, const int* __restrict__ idx0,
                       const int* __restrict__ idx1, const float* __restrict__ w,
                       const float* __restrict__ b1, float* __restrict__ hh) {
  int t = blockIdx.x * blockDim.x + threadIdx.x;
  if (t >= NB * 512) return;
  int bb = t >> 9, n = t & 511;
  const float* r0 = x2o + (size_t)idx0[bb] * 32;
  const float* r1 = x2o + (size_t)idx1[bb] * 32;
  float acc = b1[n];
#pragma unroll
  for (int i = 0; i < 32; ++i) acc = fmaf(r0[i], w[i * 512 + n], acc);
#pragma unroll
  for (int i = 0; i < 32; ++i) acc = fmaf(r1[i], w[(32 + i) * 512 + n], acc);
  hh[t] = fmaxf(acc, 0.0f);
}

__global__ void k_dec2(const float* __restrict__ hh, const float* __restrict__ w2,
                       const float* __restrict__ b2, const float* __restrict__ w3,
                       const float* __restrict__ b3, float* __restrict__ logo,
                       float* __restrict__ log1, int Bn) {
  int t = blockIdx.x * blockDim.x + threadIdx.x;
  if (t >= Bn * 4) return;
  int bb = t >> 2, j = t & 3;
  const float* h = hh + (size_t)bb * 512;
  if (j < 2) {
    float acc = b2[j];
    for (int k = 0; k < 512; ++k) acc = fmaf(h[k], w2[k * 2 + j], acc);
    logo[bb * 2 + j] = acc;
  } else {
    int jj = j - 2;
    float acc = b3[jj];
    for (int k = 0; k < 512; ++k) acc = fmaf(h[k], w3[k * 2 + jj], acc);
    log1[bb * 2 + jj] = acc;
  }
}

__global__ void k_advprep(const float* __restrict__ w, const float* __restrict__ b,
                          float* __restrict__ out) {
  int i = threadIdx.x;
  if (i < 32) {
    float s = 0.0f;
    for (int j = 0; j < 32; ++j) s += w[i * 32 + j];
    out[i] = s;
  } else if (i == 32) {
    float s = 0.0f;
    for (int j = 0; j < 32; ++j) s += b[j];
    out[32] = s;
  }
}

__global__ void k_adv(const float* __restrict__ x2o, const float* __restrict__ x2a,
                      const float* __restrict__ advr, float* __restrict__ logits) {
  int n = blockIdx.x * blockDim.x + threadIdx.x;
  if (n >= 2 * NN) return;
  const float* row = (n < NN) ? (x2o + (size_t)n * 32) : (x2a + (size_t)(n - NN) * 32);
  float acc = advr[32];
#pragma unroll
  for (int i = 0; i < 32; ++i) acc = fmaf(row[i], advr[i], acc);
  logits[n] = acc;
}

// ------------------------------------------------ host

extern "C" void kernel_launch(void* const* d_in, const int* in_sizes, int n_in,
                              void* d_out, int out_size, void* d_ws, size_t ws_size,
                              hipStream_t stream) {
  const float* x_o = (const float*)d_in[0];
  const float* x_a = (const float*)d_in[1];
  const float* gat1_w = (const float*)d_in[2];
  const float* gat1_asrc = (const float*)d_in[3];
  const float* gat1_adst = (const float*)d_in[4];
  const float* gat1_b = (const float*)d_in[5];
  const float* gat2_w = (const float*)d_in[6];
  const float* gat2_asrc = (const float*)d_in[7];
  const float* gat2_adst = (const float*)d_in[8];
  const float* gat2_b = (const float*)d_in[9];
  const float* pg1 = (const float*)d_in[10];
  const float* pg2 = (const float*)d_in[11];
  const float* gt1_wq = (const float*)d_in[12];
  const float* gt1_bq = (const float*)d_in[13];
  const float* gt1_wk = (const float*)d_in[14];
  const float* gt1_bk = (const float*)d_in[15];
  const float* gt1_wv = (const float*)d_in[16];
  const float* gt1_bv = (const float*)d_in[17];
  const float* gt1_ws = (const float*)d_in[18];
  const float* gt1_bs = (const float*)d_in[19];
  const float* gt2_wq = (const float*)d_in[20];
  const float* gt2_bq = (const float*)d_in[21];
  const float* gt2_wk = (const float*)d_in[22];
  const float* gt2_bk = (const float*)d_in[23];
  const float* gt2_wv = (const float*)d_in[24];
  const float* gt2_bv = (const float*)d_in[25];
  const float* gt2_ws = (const float*)d_in[26];
  const float* gt2_bs = (const float*)d_in[27];
  const float* pt1 = (const float*)d_in[28];
  const float* pt2 = (const float*)d_in[29];
  const float* fuse_w = (const float*)d_in[30];
  const float* fuse_b = (const float*)d_in[31];
  const float* mlp1_w = (const float*)d_in[32];
  const float* mlp1_b = (const float*)d_in[33];
  const float* disc_w = (const float*)d_in[34];
  const float* disc_b = (const float*)d_in[35];
  const float* fus_w1 = (const float*)d_in[36];
  const float* fus_b1 = (const float*)d_in[37];
  const float* fus_w2 = (const float*)d_in[38];
  const float* fus_b2 = (const float*)d_in[39];
  const float* fus_w3 = (const float*)d_in[40];
  const float* fus_b3 = (const float*)d_in[41];
  const float* adv_w = (const float*)d_in[42];
  const float* adv_b = (const float*)d_in[43];
  const int* ei = (const int*)d_in[44];
  const int* idxp = (const int*)d_in[45];
  const int* esrc = ei;
  const int* edst = ei + NE;
  const int* idx0 = idxp;
  const int* idx1 = idxp + NB;

  // ---- workspace carve (float units; u16 buffers counted /2) ----
  float* w = (float*)d_ws;
  size_t o = 0;
  u16* C1 = (u16*)(w + o); o += 12800000;            // 20000*1280 bf16
  u16* C2 = (u16*)(w + o); o += 1600000;             // 20000*160 bf16
  u16* bufB = (u16*)(w + o); o += 2560000;           // 20000*256 bf16
  u16* bufE = (u16*)(w + o); o += 2560000;           // 20000*256 bf16
  u16* xb_o = (u16*)(w + o); o += 1280000;           // 20000*128 bf16
  u16* xb_a = (u16*)(w + o); o += 1280000;
  u16* Wt1 = (u16*)(w + o); o += 81920;              // 1280*128 bf16
  u16* Wt2 = (u16*)(w + o); o += 20480;              // 160*256 bf16
  float* bp1 = w + o; o += 1280;
  float* bp2 = w + o; o += 160;
  float* als = w + o; o += NN * 4;
  float* ald = w + o; o += NN * 4;
  float* xg = w + o; o += NN * 32;
  float* xt = w + o; o += NN * 32;
  float* x2a = w + o; o += NN * 32;
  float* t_o = w + o; o += NN * 32;
  float* t_a = w + o; o += NN * 32;
  float* hh = w + o; o += NB * 512;
  int* deg = (int*)(w + o); o += NN;
  int* offs = (int*)(w + o); o += NN + 8;
  int* cur = (int*)(w + o); o += NN;
  int* esrcs = (int*)(w + o); o += NE;
  float* sml = w + o; o += 256;
  float* sig_o = sml;
  float* sig_a = sml + 32;
  float* h_os = sml + 64;
  float* h_osa = sml + 96;
  float* advr = sml + 128;

  float* out = (float*)d_out;
  float* out_log = out;               // [B,2]
  float* out_ret = out + 8192;        // [N,2]
  float* out_reta = out + 48192;      // [N,2]
  float* out_x2o = out + 88192;       // [N,32]
  float* out_logit = out + 728192;    // [1,2N]
  float* out_log1 = out + 768192;     // [B,2]

  // ---- weight packing + input conversion ----
  k_pack1<<<(1280 * 128 + 255) / 256, 256, 0, stream>>>(gat1_w, gt1_wq, gt1_wk, gt1_wv,
                                                        gt1_ws, gt1_bq, gt1_bk, gt1_bv,
                                                        gt1_bs, Wt1, bp1);
  k_pack2<<<(160 * 256 + 255) / 256, 256, 0, stream>>>(gt2_wq, gt2_wk, gt2_wv, gt2_ws,
                                                       gat2_w, gt2_bq, gt2_bk, gt2_bv,
                                                       gt2_bs, Wt2, bp2);
  k_tobf16<<<(NN * 128 + 255) / 256, 256, 0, stream>>>(x_o, xb_o, NN * 128);
  k_tobf16<<<(NN * 128 + 255) / 256, 256, 0, stream>>>(x_a, xb_a, NN * 128);
  // ---- CSR build ----
  hipMemsetAsync(deg, 0, NN * sizeof(int), stream);
  k_hist<<<(NE + 255) / 256, 256, 0, stream>>>(edst, deg);
  k_scan20000<<<1, 1024, 0, stream>>>(deg, offs);
  k_copyoffs<<<(NN + 255) / 256, 256, 0, stream>>>(offs, cur);
  k_scatter<<<(NE + 255) / 256, 256, 0, stream>>>(esrc, edst, cur, esrcs);

  auto branch = [&](const u16* xb, float* x2out) {
    // layer 1: MFMA GEMM -> C1 = [gat_h | q | k | v | skip] bf16, M=NN K=128 Nc=1280
    {
      dim3 g(10, (NN + 127) / 128);
      k_mfma_gemm<<<g, 256, 0, stream>>>(xb, xb, 999, Wt1, bp1, C1, NN, 128, 1280);
    }
    k_gat_al<<<(NN * 4 + 255) / 256, 256, 0, stream>>>(C1, 1280, 0, gat1_asrc, gat1_adst,
                                                       als, ald, NN * 4, 4, 64);
    k_agg256_gat<<<(NN + 3) / 4, 256, 0, stream>>>(offs, esrcs, als, ald, C1, gat1_b,
                                                   pg1, bufB);
    k_agg256_gt<<<(NN + 3) / 4, 256, 0, stream>>>(offs, esrcs, C1, pt1, bufE);
    // layer 2: MFMA GEMM, n-block 0 = bufE (gt2 cols 0..127), block 1 = bufB (gat2 128..159)
    {
      dim3 g(2, (NN + 127) / 128);
      k_mfma_gemm<<<g, 256, 0, stream>>>(bufE, bufB, 1, Wt2, bp2, C2, NN, 256, 160);
    }
    k_gat_al<<<(NN + 255) / 256, 256, 0, stream>>>(C2, 160, 128, gat2_asrc, gat2_adst,
                                                   als, ald, NN, 1, 32);
    k_agg32_gat<<<(NN + 7) / 8, 256, 0, stream>>>(offs, esrcs, als, ald, C2, gat2_b,
                                                  pg2, xg);
    k_agg32_gt<<<(NN + 7) / 8, 256, 0, stream>>>(offs, esrcs, C2, pt2, xt);
    k_fuse<<<(NN * 32 + 255) / 256, 256, 0, stream>>>(xg, xt, fuse_w, fuse_b, x2out, NN);
  };

  branch(xb_o, out_x2o);
  branch(xb_a, x2a);

  // ---- summary + discriminator ----
  k_colmean_sig<<<32, 256, 0, stream>>>(out_x2o, sig_o, NN);
  k_colmean_sig<<<32, 256, 0, stream>>>(x2a, sig_a, NN);
  k_summary2<<<1, 32, 0, stream>>>(sig_o, mlp1_w, mlp1_b, h_os);
  k_summary2<<<1, 32, 0, stream>>>(sig_a, mlp1_w, mlp1_b, h_osa);
  {
    dim3 g(1, (NN + 7) / 8);
    k_gemm_bias<<<g, 256, 0, stream>>>(out_x2o, disc_w, nullptr, t_o, NN, 32, 32, 5);
    k_gemm_bias<<<g, 256, 0, stream>>>(x2a, disc_w, nullptr, t_a, NN, 32, 32, 5);
  }
  k_disc<<<(NN + 255) / 256, 256, 0, stream>>>(t_o, t_a, h_os, h_osa, disc_b,
                                               out_ret, out_reta, NN);
  // ---- decoder ----
  k_dec1<<<(NB * 512 + 255) / 256, 256, 0, stream>>>(out_x2o, idx0, idx1, fus_w1,
                                                     fus_b1, hh);
  k_dec2<<<(NB * 4 + 255) / 256, 256, 0, stream>>>(hh, fus_w2, fus_b2, fus_w3, fus_b3,
                                                   out_log, out_log1, NB);
  // ---- adversarial logits ----
  k_advprep<<<1, 64, 0, stream>>>(adv_w, adv_b, advr);
  k_adv<<<(2 * NN + 255) / 256, 256, 0, stream>>>(out_x2o, x2a, advr, out_logit);
}

// Round 5
// 651.778 us; speedup vs baseline: 5.9734x; 1.1962x over previous
//
#include <hip/hip_runtime.h>
#include <math.h>

#define NN 20000
#define NE 320000
#define NB 4096

typedef unsigned short u16;
typedef __attribute__((ext_vector_type(8))) short short8;
typedef __attribute__((ext_vector_type(4))) float f32x4;

__device__ __forceinline__ float b2f(u16 u) {
  unsigned int x = ((unsigned int)u) << 16;
  return __uint_as_float(x);
}
__device__ __forceinline__ u16 f2b(float f) {
  unsigned int x = __float_as_uint(f);
  return (u16)((x + 0x7fffu + ((x >> 16) & 1u)) >> 16);
}

// ------------------------------------------------ packing (transposed bf16 weights)

__global__ void k_pack1(const float* __restrict__ w0, const float* __restrict__ w1,
                        const float* __restrict__ w2, const float* __restrict__ w3,
                        const float* __restrict__ w4, const float* __restrict__ b1,
                        const float* __restrict__ b2, const float* __restrict__ b3,
                        const float* __restrict__ b4, u16* __restrict__ Wt,
                        float* __restrict__ bp) {
  int t = blockIdx.x * blockDim.x + threadIdx.x;
  if (t < 1280 * 128) {
    int j = t >> 7, k = t & 127;
    int seg = j >> 8, jj = j & 255;
    const float* s = (seg == 0) ? w0 : (seg == 1) ? w1 : (seg == 2) ? w2 : (seg == 3) ? w3 : w4;
    Wt[t] = f2b(s[k * 256 + jj]);
  }
  if (t < 1280) {
    int seg = t >> 8, jj = t & 255;
    bp[t] = (seg == 0) ? 0.0f : (seg == 1) ? b1[jj] : (seg == 2) ? b2[jj] : (seg == 3) ? b3[jj] : b4[jj];
  }
}

// cols: [wq2|wk2|wv2|ws2|gat2_w]; Wt2[j][k] (j<160, k<256)
__global__ void k_pack2(const float* __restrict__ wq, const float* __restrict__ wk,
                        const float* __restrict__ wv, const float* __restrict__ ws,
                        const float* __restrict__ wg, const float* __restrict__ bq,
                        const float* __restrict__ bk, const float* __restrict__ bv,
                        const float* __restrict__ bs, u16* __restrict__ Wt,
                        float* __restrict__ bp) {
  int t = blockIdx.x * blockDim.x + threadIdx.x;
  if (t < 160 * 256) {
    int j = t >> 8, k = t & 255;
    int seg = j >> 5, jj = j & 31;
    const float* s = (seg == 0) ? wq : (seg == 1) ? wk : (seg == 2) ? wv : (seg == 3) ? ws : wg;
    Wt[t] = f2b(s[k * 32 + jj]);
  }
  if (t < 160) {
    int seg = t >> 5, jj = t & 31;
    bp[t] = (seg == 0) ? bq[jj] : (seg == 1) ? bk[jj] : (seg == 2) ? bv[jj] : (seg == 3) ? bs[jj] : 0.0f;
  }
}

__global__ void k_tobf16(const float* __restrict__ x, u16* __restrict__ xb, int total) {
  int t = blockIdx.x * blockDim.x + threadIdx.x;
  if (t < total) xb[t] = f2b(x[t]);
}

// ------------------------------------------------ CSR build

__global__ void k_hist(const int* __restrict__ dst, int* __restrict__ deg) {
  int t = blockIdx.x * blockDim.x + threadIdx.x;
  if (t < NE) atomicAdd(&deg[dst[t]], 1);
}

__global__ void k_scan20000(const int* __restrict__ deg, int* __restrict__ offs) {
  __shared__ int part[1024];
  int t = threadIdx.x;
  int loc[20];
  int s = 0;
#pragma unroll
  for (int i = 0; i < 20; ++i) {
    int idx = t * 20 + i;
    int v = (idx < NN) ? deg[idx] : 0;
    loc[i] = s;
    s += v;
  }
  part[t] = s;
  __syncthreads();
  for (int off = 1; off < 1024; off <<= 1) {
    int v = (t >= off) ? part[t - off] : 0;
    __syncthreads();
    part[t] += v;
    __syncthreads();
  }
  int base = (t > 0) ? part[t - 1] : 0;
#pragma unroll
  for (int i = 0; i < 20; ++i) {
    int idx = t * 20 + i;
    if (idx < NN) offs[idx] = base + loc[i];
  }
  if (t == 1023) offs[NN] = part[1023];
}

__global__ void k_copyoffs(const int* __restrict__ offs, int* __restrict__ cur) {
  int t = blockIdx.x * blockDim.x + threadIdx.x;
  if (t < NN) cur[t] = offs[t];
}

__global__ void k_scatter(const int* __restrict__ src, const int* __restrict__ dst,
                          int* __restrict__ cur, int* __restrict__ esrcs) {
  int t = blockIdx.x * blockDim.x + threadIdx.x;
  if (t >= NE) return;
  int d = dst[t];
  int pos = atomicAdd(&cur[d], 1);
  esrcs[pos] = src[t];
}

// ------------------------------------------------ MFMA GEMM (proven round 4)

__global__ void k_mfma_gemm(const u16* __restrict__ A0, const u16* __restrict__ A1,
                            int asel, const u16* __restrict__ Bt,
                            const float* __restrict__ bias, u16* __restrict__ C,
                            int M, int K, int Nc) {
  const u16* A = (blockIdx.x >= (unsigned)asel) ? A1 : A0;
  int m0 = blockIdx.y * 128, n0 = blockIdx.x * 128;
  int wid = threadIdx.x >> 6, lane = threadIdx.x & 63;
  int mw = m0 + (wid & 1) * 64, nw = n0 + (wid >> 1) * 64;
  int arow = mw + (lane & 15);
  int bcol = nw + (lane & 15);
  int kblk = (lane >> 4) * 8;
  f32x4 acc[4][4] = {};
  const short8 zero8 = {0, 0, 0, 0, 0, 0, 0, 0};
  for (int k0 = 0; k0 < K; k0 += 32) {
    short8 af[4], bf[4];
#pragma unroll
    for (int mf = 0; mf < 4; ++mf) {
      int r = arow + mf * 16;
      if (r > M - 1) r = M - 1;
      af[mf] = *reinterpret_cast<const short8*>(&A[(size_t)r * K + k0 + kblk]);
    }
#pragma unroll
    for (int nf = 0; nf < 4; ++nf) {
      int c = bcol + nf * 16;
      bf[nf] = (c < Nc) ? *reinterpret_cast<const short8*>(&Bt[(size_t)c * K + k0 + kblk])
                        : zero8;
    }
#pragma unroll
    for (int mf = 0; mf < 4; ++mf)
#pragma unroll
      for (int nf = 0; nf < 4; ++nf)
        acc[mf][nf] = __builtin_amdgcn_mfma_f32_16x16x32_bf16(af[mf], bf[nf],
                                                              acc[mf][nf], 0, 0, 0);
  }
#pragma unroll
  for (int nf = 0; nf < 4; ++nf) {
    int col = nw + nf * 16 + (lane & 15);
    if (col >= Nc) continue;
    float bs = bias ? bias[col] : 0.0f;
#pragma unroll
    for (int mf = 0; mf < 4; ++mf) {
      int rbase = mw + mf * 16 + (lane >> 4) * 4;
#pragma unroll
      for (int r = 0; r < 4; ++r) {
        int row = rbase + r;
        if (row < M) C[(size_t)row * Nc + col] = f2b(acc[mf][nf][r] + bs);
      }
    }
  }
}

// ------------------------------------------------ attention pieces

__global__ void k_gat_al(const u16* __restrict__ h, int stride, int coff,
                         const float* __restrict__ asrc, const float* __restrict__ adst,
                         float* __restrict__ als, float* __restrict__ ald, int total,
                         int heads, int c) {
  int i = blockIdx.x * blockDim.x + threadIdx.x;
  if (i >= total) return;
  int node = i / heads, hd = i - node * heads;
  const u16* hp = h + (size_t)node * stride + coff + hd * c;
  const float* as = asrc + hd * c;
  const float* ad = adst + hd * c;
  float s1 = 0.0f, s2 = 0.0f;
  for (int k = 0; k < c; k += 4) {
    ushort4 f4 = *reinterpret_cast<const ushort4*>(&hp[k]);
    s1 = fmaf(b2f(f4.x), as[k], s1);
    s2 = fmaf(b2f(f4.x), ad[k], s2);
    s1 = fmaf(b2f(f4.y), as[k + 1], s1);
    s2 = fmaf(b2f(f4.y), ad[k + 1], s2);
    s1 = fmaf(b2f(f4.z), as[k + 2], s1);
    s2 = fmaf(b2f(f4.z), ad[k + 2], s2);
    s1 = fmaf(b2f(f4.w), as[k + 3], s1);
    s2 = fmaf(b2f(f4.w), ad[k + 3], s2);
  }
  als[i] = s1;
  ald[i] = s2;
}

// Layer-1 FUSED aggregate (GAT1 + GT1): one wave per dst, 2-stage pipelined.
// C1 cols: gat_h@0 q@256 k@512 v@768 skip@1024
__global__ void k_agg256_fused(const int* __restrict__ offs, const int* __restrict__ esrcs,
                               const float* __restrict__ als, const float* __restrict__ ald,
                               const u16* __restrict__ C1, const float* __restrict__ gbias,
                               const float* __restrict__ pg, const float* __restrict__ pt,
                               u16* __restrict__ outG, u16* __restrict__ outT) {
  int d = blockIdx.x * 4 + (threadIdx.x >> 6);
  if (d >= NN) return;
  int lane = threadIdx.x & 63;
  int head = lane >> 4, c4 = lane << 2;
  ushort4 q4 = *reinterpret_cast<const ushort4*>(&C1[(size_t)d * 1280 + 256 + c4]);
  float q0 = b2f(q4.x), q1 = b2f(q4.y), q2 = b2f(q4.z), q3 = b2f(q4.w);
  float aldd = ald[d * 4 + head];
  float ga0 = 0, ga1 = 0, ga2 = 0, ga3 = 0, gden = 0.0f;
  float ta0 = 0, ta1 = 0, ta2 = 0, ta3 = 0, tden = 1e-16f;
  int b0 = offs[d], b1 = offs[d + 1];
  int sc = 0;
  ushort4 fc = {0, 0, 0, 0}, kc = {0, 0, 0, 0}, vc = {0, 0, 0, 0};
  float alc = 0.0f;
  if (b0 < b1) {
    sc = esrcs[b0];
    const u16* row = &C1[(size_t)sc * 1280];
    fc = *reinterpret_cast<const ushort4*>(&row[c4]);
    kc = *reinterpret_cast<const ushort4*>(&row[512 + c4]);
    vc = *reinterpret_cast<const ushort4*>(&row[768 + c4]);
    alc = als[sc * 4 + head];
  }
  for (int i = b0; i < b1; ++i) {
    int sn = sc;
    ushort4 fn = fc, kn = kc, vn = vc;
    float aln = alc;
    if (i + 1 < b1) {  // prefetch next edge (independent of compute below)
      sn = esrcs[i + 1];
      const u16* row = &C1[(size_t)sn * 1280];
      fn = *reinterpret_cast<const ushort4*>(&row[c4]);
      kn = *reinterpret_cast<const ushort4*>(&row[512 + c4]);
      vn = *reinterpret_cast<const ushort4*>(&row[768 + c4]);
      aln = als[sn * 4 + head];
    }
    // GT chain
    float pp = q0 * b2f(kc.x);
    pp = fmaf(q1, b2f(kc.y), pp);
    pp = fmaf(q2, b2f(kc.z), pp);
    pp = fmaf(q3, b2f(kc.w), pp);
    pp += __shfl_xor(pp, 1, 16);
    pp += __shfl_xor(pp, 2, 16);
    pp += __shfl_xor(pp, 4, 16);
    pp += __shfl_xor(pp, 8, 16);
    float pet = expf(pp * 0.125f);
    // GAT chain (independent)
    float v = alc + aldd;
    float peg = expf(v >= 0.0f ? v : 0.2f * v);
    ga0 = fmaf(peg, b2f(fc.x), ga0);
    ga1 = fmaf(peg, b2f(fc.y), ga1);
    ga2 = fmaf(peg, b2f(fc.z), ga2);
    ga3 = fmaf(peg, b2f(fc.w), ga3);
    gden += peg;
    ta0 = fmaf(pet, b2f(vc.x), ta0);
    ta1 = fmaf(pet, b2f(vc.y), ta1);
    ta2 = fmaf(pet, b2f(vc.z), ta2);
    ta3 = fmaf(pet, b2f(vc.w), ta3);
    tden += pet;
    sc = sn; fc = fn; kc = kn; vc = vn; alc = aln;
  }
  { // GAT self loop
    float v = als[d * 4 + head] + aldd;
    float pe = expf(v >= 0.0f ? v : 0.2f * v);
    ushort4 f = *reinterpret_cast<const ushort4*>(&C1[(size_t)d * 1280 + c4]);
    ga0 = fmaf(pe, b2f(f.x), ga0);
    ga1 = fmaf(pe, b2f(f.y), ga1);
    ga2 = fmaf(pe, b2f(f.z), ga2);
    ga3 = fmaf(pe, b2f(f.w), ga3);
    gden += pe;
  }
  float ig = 1.0f / gden, it = 1.0f / tden;
  float o0 = ga0 * ig + gbias[c4 + 0];
  float o1 = ga1 * ig + gbias[c4 + 1];
  float o2 = ga2 * ig + gbias[c4 + 2];
  float o3 = ga3 * ig + gbias[c4 + 3];
  o0 = o0 >= 0.0f ? o0 : pg[c4 + 0] * o0;
  o1 = o1 >= 0.0f ? o1 : pg[c4 + 1] * o1;
  o2 = o2 >= 0.0f ? o2 : pg[c4 + 2] * o2;
  o3 = o3 >= 0.0f ? o3 : pg[c4 + 3] * o3;
  ushort4 wg4;
  wg4.x = f2b(o0); wg4.y = f2b(o1); wg4.z = f2b(o2); wg4.w = f2b(o3);
  *reinterpret_cast<ushort4*>(&outG[(size_t)d * 256 + c4]) = wg4;
  ushort4 sk = *reinterpret_cast<const ushort4*>(&C1[(size_t)d * 1280 + 1024 + c4]);
  float u0 = ta0 * it + b2f(sk.x);
  float u1 = ta1 * it + b2f(sk.y);
  float u2 = ta2 * it + b2f(sk.z);
  float u3 = ta3 * it + b2f(sk.w);
  u0 = u0 >= 0.0f ? u0 : pt[c4 + 0] * u0;
  u1 = u1 >= 0.0f ? u1 : pt[c4 + 1] * u1;
  u2 = u2 >= 0.0f ? u2 : pt[c4 + 2] * u2;
  u3 = u3 >= 0.0f ? u3 : pt[c4 + 3] * u3;
  ushort4 wt4;
  wt4.x = f2b(u0); wt4.y = f2b(u1); wt4.z = f2b(u2); wt4.w = f2b(u3);
  *reinterpret_cast<ushort4*>(&outT[(size_t)d * 256 + c4]) = wt4;
}

// Layer-2 FUSED aggregate (GAT2 + GT2): 32 lanes per dst, 2-stage pipelined.
// C2 cols: q2@0 k2@32 v2@64 s2@96 gat2h@128
__global__ void k_agg32_fused(const int* __restrict__ offs, const int* __restrict__ esrcs,
                              const float* __restrict__ als, const float* __restrict__ ald,
                              const u16* __restrict__ C2, const float* __restrict__ gbias,
                              const float* __restrict__ pg, const float* __restrict__ pt,
                              float* __restrict__ outG, float* __restrict__ outT) {
  int d = blockIdx.x * 8 + (threadIdx.x >> 5);
  if (d >= NN) return;
  int l = threadIdx.x & 31;
  float qv = b2f(C2[(size_t)d * 160 + l]);
  float aldd = ald[d];
  float ga = 0.0f, gden = 0.0f;
  float ta = 0.0f, tden = 1e-16f;
  int b0 = offs[d], b1 = offs[d + 1];
  int sc = 0;
  float kc = 0, vc = 0, hc = 0, alc = 0;
  if (b0 < b1) {
    sc = esrcs[b0];
    const u16* row = &C2[(size_t)sc * 160];
    kc = b2f(row[32 + l]);
    vc = b2f(row[64 + l]);
    hc = b2f(row[128 + l]);
    alc = als[sc];
  }
  for (int i = b0; i < b1; ++i) {
    int sn = sc;
    float kn = kc, vn = vc, hn = hc, aln = alc;
    if (i + 1 < b1) {
      sn = esrcs[i + 1];
      const u16* row = &C2[(size_t)sn * 160];
      kn = b2f(row[32 + l]);
      vn = b2f(row[64 + l]);
      hn = b2f(row[128 + l]);
      aln = als[sn];
    }
    // GT chain
    float pp = qv * kc;
    pp += __shfl_xor(pp, 1, 32);
    pp += __shfl_xor(pp, 2, 32);
    pp += __shfl_xor(pp, 4, 32);
    pp += __shfl_xor(pp, 8, 32);
    pp += __shfl_xor(pp, 16, 32);
    float pet = expf(pp * 0.17677669529663687f);
    // GAT chain
    float v = alc + aldd;
    float peg = expf(v >= 0.0f ? v : 0.2f * v);
    ga = fmaf(peg, hc, ga);
    gden += peg;
    ta = fmaf(pet, vc, ta);
    tden += pet;
    sc = sn; kc = kn; vc = vn; hc = hn; alc = aln;
  }
  { // GAT self loop
    float v = als[d] + aldd;
    float pe = expf(v >= 0.0f ? v : 0.2f * v);
    ga = fmaf(pe, b2f(C2[(size_t)d * 160 + 128 + l]), ga);
    gden += pe;
  }
  float og = ga / gden + gbias[l];
  og = og >= 0.0f ? og : pg[l] * og;
  outG[(size_t)d * 32 + l] = og;
  float ot = ta / tden + b2f(C2[(size_t)d * 160 + 96 + l]);
  ot = ot >= 0.0f ? ot : pt[l] * ot;
  outT[(size_t)d * 32 + l] = ot;
}

// ------------------------------------------------ epilogue (proven)

__global__ void k_fuse(const float* __restrict__ xg, const float* __restrict__ xt,
                       const float* __restrict__ w, const float* __restrict__ b,
                       float* __restrict__ out, int M) {
  int t = blockIdx.x * blockDim.x + threadIdx.x;
  if (t >= M * 32) return;
  int m = t >> 5, j = t & 31;
  const float* xgp = xg + (size_t)m * 32;
  const float* xtp = xt + (size_t)m * 32;
  float acc = b[j];
#pragma unroll
  for (int i = 0; i < 32; ++i) acc = fmaf(xgp[i], w[i * 32 + j], acc);
#pragma unroll
  for (int i = 0; i < 32; ++i) acc = fmaf(xtp[i], w[(32 + i) * 32 + j], acc);
  out[t] = acc;
}

__global__ void k_gemm_bias(const float* __restrict__ A, const float* __restrict__ W,
                            const float* __restrict__ bias, float* __restrict__ C,
                            int M, int K, int Nc, int lgw) {
  int wmask = (1 << lgw) - 1;
  int n = blockIdx.x * (1 << lgw) + (threadIdx.x & wmask);
  int m = blockIdx.y * (256 >> lgw) + (threadIdx.x >> lgw);
  if (m >= M || n >= Nc) return;
  const float* a = A + (size_t)m * K;
  float acc = bias ? bias[n] : 0.0f;
#pragma unroll 4
  for (int k = 0; k < K; ++k) acc = fmaf(a[k], W[(size_t)k * Nc + n], acc);
  C[(size_t)m * Nc + n] = acc;
}

__global__ void k_colmean_sig(const float* __restrict__ x, float* __restrict__ sig, int M) {
  __shared__ float red[256];
  int j = blockIdx.x;
  float s = 0.0f;
  for (int m = threadIdx.x; m < M; m += 256) s += x[(size_t)m * 32 + j];
  red[threadIdx.x] = s;
  __syncthreads();
  for (int w = 128; w > 0; w >>= 1) {
    if (threadIdx.x < w) red[threadIdx.x] += red[threadIdx.x + w];
    __syncthreads();
  }
  if (threadIdx.x == 0) sig[j] = 1.0f / (1.0f + expf(-red[0] / (float)M));
}

__global__ void k_summary2(const float* __restrict__ sig, const float* __restrict__ w,
                           const float* __restrict__ b, float* __restrict__ out) {
  int j = threadIdx.x;
  float acc = b[j];
#pragma unroll
  for (int i = 0; i < 32; ++i) acc = fmaf(sig[i], w[i * 32 + j], acc);
  out[j] = acc;
}

__global__ void k_disc(const float* __restrict__ to, const float* __restrict__ ta,
                       const float* __restrict__ hos, const float* __restrict__ hosa,
                       const float* __restrict__ db, float* __restrict__ ret_os,
                       float* __restrict__ ret_os_a, int M) {
  int n = blockIdx.x * blockDim.x + threadIdx.x;
  if (n >= M) return;
  const float* a = to + (size_t)n * 32;
  const float* b = ta + (size_t)n * 32;
  float s_oo = 0, s_ao = 0, s_aa = 0, s_oa = 0;
#pragma unroll
  for (int i = 0; i < 32; ++i) {
    float ho = hos[i], ha = hosa[i];
    s_oo = fmaf(a[i], ho, s_oo);
    s_ao = fmaf(b[i], ho, s_ao);
    s_aa = fmaf(b[i], ha, s_aa);
    s_oa = fmaf(a[i], ha, s_oa);
  }
  float bb = db[0];
  ret_os[n * 2 + 0] = s_oo + bb;
  ret_os[n * 2 + 1] = s_ao + bb;
  ret_os_a[n * 2 + 0] = s_aa + bb;
  ret_os_a[n * 2 + 1] = s_oa + bb;
}

__global__ void k_dec1(const float* __restrict__ x2o, const int* __restrict__ idx0,
                       const int* __restrict__ idx1, const float* __restrict__ w,
                       const float* __restrict__ b1, float* __restrict__ hh) {
  int t = blockIdx.x * blockDim.x + threadIdx.x;
  if (t >= NB * 512) return;
  int bb = t >> 9, n = t & 511;
  const float* r0 = x2o + (size_t)idx0[bb] * 32;
  const float* r1 = x2o + (size_t)idx1[bb] * 32;
  float acc = b1[n];
#pragma unroll
  for (int i = 0; i < 32; ++i) acc = fmaf(r0[i], w[i * 512 + n], acc);
#pragma unroll
  for (int i = 0; i < 32; ++i) acc = fmaf(r1[i], w[(32 + i) * 512 + n], acc);
  hh[t] = fmaxf(acc, 0.0f);
}

__global__ void k_dec2(const float* __restrict__ hh, const float* __restrict__ w2,
                       const float* __restrict__ b2, const float* __restrict__ w3,
                       const float* __restrict__ b3, float* __restrict__ logo,
                       float* __restrict__ log1, int Bn) {
  int t = blockIdx.x * blockDim.x + threadIdx.x;
  if (t >= Bn * 4) return;
  int bb = t >> 2, j = t & 3;
  const float* h = hh + (size_t)bb * 512;
  if (j < 2) {
    float acc = b2[j];
    for (int k = 0; k < 512; ++k) acc = fmaf(h[k], w2[k * 2 + j], acc);
    logo[bb * 2 + j] = acc;
  } else {
    int jj = j - 2;
    float acc = b3[jj];
    for (int k = 0; k < 512; ++k) acc = fmaf(h[k], w3[k * 2 + jj], acc);
    log1[bb * 2 + jj] = acc;
  }
}

__global__ void k_advprep(const float* __restrict__ w, const float* __restrict__ b,
                          float* __restrict__ out) {
  int i = threadIdx.x;
  if (i < 32) {
    float s = 0.0f;
    for (int j = 0; j < 32; ++j) s += w[i * 32 + j];
    out[i] = s;
  } else if (i == 32) {
    float s = 0.0f;
    for (int j = 0; j < 32; ++j) s += b[j];
    out[32] = s;
  }
}

__global__ void k_adv(const float* __restrict__ x2o, const float* __restrict__ x2a,
                      const float* __restrict__ advr, float* __restrict__ logits) {
  int n = blockIdx.x * blockDim.x + threadIdx.x;
  if (n >= 2 * NN) return;
  const float* row = (n < NN) ? (x2o + (size_t)n * 32) : (x2a + (size_t)(n - NN) * 32);
  float acc = advr[32];
#pragma unroll
  for (int i = 0; i < 32; ++i) acc = fmaf(row[i], advr[i], acc);
  logits[n] = acc;
}

// ------------------------------------------------ host

extern "C" void kernel_launch(void* const* d_in, const int* in_sizes, int n_in,
                              void* d_out, int out_size, void* d_ws, size_t ws_size,
                              hipStream_t stream) {
  const float* x_o = (const float*)d_in[0];
  const float* x_a = (const float*)d_in[1];
  const float* gat1_w = (const float*)d_in[2];
  const float* gat1_asrc = (const float*)d_in[3];
  const float* gat1_adst = (const float*)d_in[4];
  const float* gat1_b = (const float*)d_in[5];
  const float* gat2_w = (const float*)d_in[6];
  const float* gat2_asrc = (const float*)d_in[7];
  const float* gat2_adst = (const float*)d_in[8];
  const float* gat2_b = (const float*)d_in[9];
  const float* pg1 = (const float*)d_in[10];
  const float* pg2 = (const float*)d_in[11];
  const float* gt1_wq = (const float*)d_in[12];
  const float* gt1_bq = (const float*)d_in[13];
  const float* gt1_wk = (const float*)d_in[14];
  const float* gt1_bk = (const float*)d_in[15];
  const float* gt1_wv = (const float*)d_in[16];
  const float* gt1_bv = (const float*)d_in[17];
  const float* gt1_ws = (const float*)d_in[18];
  const float* gt1_bs = (const float*)d_in[19];
  const float* gt2_wq = (const float*)d_in[20];
  const float* gt2_bq = (const float*)d_in[21];
  const float* gt2_wk = (const float*)d_in[22];
  const float* gt2_bk = (const float*)d_in[23];
  const float* gt2_wv = (const float*)d_in[24];
  const float* gt2_bv = (const float*)d_in[25];
  const float* gt2_ws = (const float*)d_in[26];
  const float* gt2_bs = (const float*)d_in[27];
  const float* pt1 = (const float*)d_in[28];
  const float* pt2 = (const float*)d_in[29];
  const float* fuse_w = (const float*)d_in[30];
  const float* fuse_b = (const float*)d_in[31];
  const float* mlp1_w = (const float*)d_in[32];
  const float* mlp1_b = (const float*)d_in[33];
  const float* disc_w = (const float*)d_in[34];
  const float* disc_b = (const float*)d_in[35];
  const float* fus_w1 = (const float*)d_in[36];
  const float* fus_b1 = (const float*)d_in[37];
  const float* fus_w2 = (const float*)d_in[38];
  const float* fus_b2 = (const float*)d_in[39];
  const float* fus_w3 = (const float*)d_in[40];
  const float* fus_b3 = (const float*)d_in[41];
  const float* adv_w = (const float*)d_in[42];
  const float* adv_b = (const float*)d_in[43];
  const int* ei = (const int*)d_in[44];
  const int* idxp = (const int*)d_in[45];
  const int* esrc = ei;
  const int* edst = ei + NE;
  const int* idx0 = idxp;
  const int* idx1 = idxp + NB;

  // ---- workspace carve (float units; u16 buffers counted /2) ----
  float* w = (float*)d_ws;
  size_t o = 0;
  u16* C1 = (u16*)(w + o); o += 12800000;            // 20000*1280 bf16
  u16* C2 = (u16*)(w + o); o += 1600000;             // 20000*160 bf16
  u16* bufB = (u16*)(w + o); o += 2560000;           // 20000*256 bf16
  u16* bufE = (u16*)(w + o); o += 2560000;           // 20000*256 bf16
  u16* xb_o = (u16*)(w + o); o += 1280000;           // 20000*128 bf16
  u16* xb_a = (u16*)(w + o); o += 1280000;
  u16* Wt1 = (u16*)(w + o); o += 81920;              // 1280*128 bf16
  u16* Wt2 = (u16*)(w + o); o += 20480;              // 160*256 bf16
  float* bp1 = w + o; o += 1280;
  float* bp2 = w + o; o += 160;
  float* als = w + o; o += NN * 4;
  float* ald = w + o; o += NN * 4;
  float* xg = w + o; o += NN * 32;
  float* xt = w + o; o += NN * 32;
  float* x2a = w + o; o += NN * 32;
  float* t_o = w + o; o += NN * 32;
  float* t_a = w + o; o += NN * 32;
  float* hh = w + o; o += NB * 512;
  int* deg = (int*)(w + o); o += NN;
  int* offs = (int*)(w + o); o += NN + 8;
  int* cur = (int*)(w + o); o += NN;
  int* esrcs = (int*)(w + o); o += NE;
  float* sml = w + o; o += 256;
  float* sig_o = sml;
  float* sig_a = sml + 32;
  float* h_os = sml + 64;
  float* h_osa = sml + 96;
  float* advr = sml + 128;

  float* out = (float*)d_out;
  float* out_log = out;               // [B,2]
  float* out_ret = out + 8192;        // [N,2]
  float* out_reta = out + 48192;      // [N,2]
  float* out_x2o = out + 88192;       // [N,32]
  float* out_logit = out + 728192;    // [1,2N]
  float* out_log1 = out + 768192;     // [B,2]

  // ---- weight packing + input conversion ----
  k_pack1<<<(1280 * 128 + 255) / 256, 256, 0, stream>>>(gat1_w, gt1_wq, gt1_wk, gt1_wv,
                                                        gt1_ws, gt1_bq, gt1_bk, gt1_bv,
                                                        gt1_bs, Wt1, bp1);
  k_pack2<<<(160 * 256 + 255) / 256, 256, 0, stream>>>(gt2_wq, gt2_wk, gt2_wv, gt2_ws,
                                                       gat2_w, gt2_bq, gt2_bk, gt2_bv,
                                                       gt2_bs, Wt2, bp2);
  k_tobf16<<<(NN * 128 + 255) / 256, 256, 0, stream>>>(x_o, xb_o, NN * 128);
  k_tobf16<<<(NN * 128 + 255) / 256, 256, 0, stream>>>(x_a, xb_a, NN * 128);
  // ---- CSR build ----
  hipMemsetAsync(deg, 0, NN * sizeof(int), stream);
  k_hist<<<(NE + 255) / 256, 256, 0, stream>>>(edst, deg);
  k_scan20000<<<1, 1024, 0, stream>>>(deg, offs);
  k_copyoffs<<<(NN + 255) / 256, 256, 0, stream>>>(offs, cur);
  k_scatter<<<(NE + 255) / 256, 256, 0, stream>>>(esrc, edst, cur, esrcs);

  auto branch = [&](const u16* xb, float* x2out) {
    // layer 1: MFMA GEMM -> C1 = [gat_h | q | k | v | skip] bf16
    {
      dim3 g(10, (NN + 127) / 128);
      k_mfma_gemm<<<g, 256, 0, stream>>>(xb, xb, 999, Wt1, bp1, C1, NN, 128, 1280);
    }
    k_gat_al<<<(NN * 4 + 255) / 256, 256, 0, stream>>>(C1, 1280, 0, gat1_asrc, gat1_adst,
                                                       als, ald, NN * 4, 4, 64);
    k_agg256_fused<<<(NN + 3) / 4, 256, 0, stream>>>(offs, esrcs, als, ald, C1, gat1_b,
                                                     pg1, pt1, bufB, bufE);
    // layer 2: MFMA GEMM, n-block 0 = bufE (gt2 cols 0..127), block 1 = bufB (gat2 128..159)
    {
      dim3 g(2, (NN + 127) / 128);
      k_mfma_gemm<<<g, 256, 0, stream>>>(bufE, bufB, 1, Wt2, bp2, C2, NN, 256, 160);
    }
    k_gat_al<<<(NN + 255) / 256, 256, 0, stream>>>(C2, 160, 128, gat2_asrc, gat2_adst,
                                                   als, ald, NN, 1, 32);
    k_agg32_fused<<<(NN + 7) / 8, 256, 0, stream>>>(offs, esrcs, als, ald, C2, gat2_b,
                                                    pg2, pt2, xg, xt);
    k_fuse<<<(NN * 32 + 255) / 256, 256, 0, stream>>>(xg, xt, fuse_w, fuse_b, x2out, NN);
  };

  branch(xb_o, out_x2o);
  branch(xb_a, x2a);

  // ---- summary + discriminator ----
  k_colmean_sig<<<32, 256, 0, stream>>>(out_x2o, sig_o, NN);
  k_colmean_sig<<<32, 256, 0, stream>>>(x2a, sig_a, NN);
  k_summary2<<<1, 32, 0, stream>>>(sig_o, mlp1_w, mlp1_b, h_os);
  k_summary2<<<1, 32, 0, stream>>>(sig_a, mlp1_w, mlp1_b, h_osa);
  {
    dim3 g(1, (NN + 7) / 8);
    k_gemm_bias<<<g, 256, 0, stream>>>(out_x2o, disc_w, nullptr, t_o, NN, 32, 32, 5);
    k_gemm_bias<<<g, 256, 0, stream>>>(x2a, disc_w, nullptr, t_a, NN, 32, 32, 5);
  }
  k_disc<<<(NN + 255) / 256, 256, 0, stream>>>(t_o, t_a, h_os, h_osa, disc_b,
                                               out_ret, out_reta, NN);
  // ---- decoder ----
  k_dec1<<<(NB * 512 + 255) / 256, 256, 0, stream>>>(out_x2o, idx0, idx1, fus_w1,
                                                     fus_b1, hh);
  k_dec2<<<(NB * 4 + 255) / 256, 256, 0, stream>>>(hh, fus_w2, fus_b2, fus_w3, fus_b3,
                                                   out_log, out_log1, NB);
  // ---- adversarial logits ----
  k_advprep<<<1, 64, 0, stream>>>(adv_w, adv_b, advr);
  k_adv<<<(2 * NN + 255) / 256, 256, 0, stream>>>(out_x2o, x2a, advr, out_logit);
}

// Round 6
// 556.708 us; speedup vs baseline: 6.9935x; 1.1708x over previous
//
#include <hip/hip_runtime.h>
#include <math.h>

#define NN 20000
#define NE 320000
#define NB 4096

typedef unsigned short u16;
typedef unsigned char u8;
typedef __attribute__((ext_vector_type(8))) short short8;
typedef __attribute__((ext_vector_type(4))) float f32x4;
typedef __attribute__((ext_vector_type(2))) float f32x2;

#define FP8_SCALE 16.0f
#define FP8_INV 0.0625f

__device__ __forceinline__ float b2f(u16 u) {
  unsigned int x = ((unsigned int)u) << 16;
  return __uint_as_float(x);
}
__device__ __forceinline__ u16 f2b(float f) {
  unsigned int x = __float_as_uint(f);
  return (u16)((x + 0x7fffu + ((x >> 16) & 1u)) >> 16);
}
__device__ __forceinline__ u8 f2q(float f) {  // f32 -> fp8 e4m3 (RNE, sat)
  return (u8)(__builtin_amdgcn_cvt_pk_fp8_f32(f, f, 0, false) & 0xff);
}
__device__ __forceinline__ float q2f(u8 b) {
  f32x2 v = __builtin_amdgcn_cvt_pk_f32_fp8((int)b, false);
  return v[0];
}
__device__ __forceinline__ void q4(unsigned int u, float* f) {
  f32x2 lo = __builtin_amdgcn_cvt_pk_f32_fp8((int)u, false);
  f32x2 hi = __builtin_amdgcn_cvt_pk_f32_fp8((int)u, true);
  f[0] = lo[0]; f[1] = lo[1]; f[2] = hi[0]; f[3] = hi[1];
}

// ------------------------------------------------ packing (transposed bf16 weights)

__global__ void k_pack1(const float* __restrict__ w0, const float* __restrict__ w1,
                        const float* __restrict__ w2, const float* __restrict__ w3,
                        const float* __restrict__ w4, const float* __restrict__ b1,
                        const float* __restrict__ b2, const float* __restrict__ b3,
                        const float* __restrict__ b4, u16* __restrict__ Wt,
                        float* __restrict__ bp) {
  int t = blockIdx.x * blockDim.x + threadIdx.x;
  if (t < 1280 * 128) {
    int j = t >> 7, k = t & 127;
    int seg = j >> 8, jj = j & 255;
    const float* s = (seg == 0) ? w0 : (seg == 1) ? w1 : (seg == 2) ? w2 : (seg == 3) ? w3 : w4;
    Wt[t] = f2b(s[k * 256 + jj]);
  }
  if (t < 1280) {
    int seg = t >> 8, jj = t & 255;
    bp[t] = (seg == 0) ? 0.0f : (seg == 1) ? b1[jj] : (seg == 2) ? b2[jj] : (seg == 3) ? b3[jj] : b4[jj];
  }
}

// cols: [wq2|wk2|wv2|ws2|gat2_w]; Wt2[j][k] (j<160, k<256)
__global__ void k_pack2(const float* __restrict__ wq, const float* __restrict__ wk,
                        const float* __restrict__ wv, const float* __restrict__ ws,
                        const float* __restrict__ wg, const float* __restrict__ bq,
                        const float* __restrict__ bk, const float* __restrict__ bv,
                        const float* __restrict__ bs, u16* __restrict__ Wt,
                        float* __restrict__ bp) {
  int t = blockIdx.x * blockDim.x + threadIdx.x;
  if (t < 160 * 256) {
    int j = t >> 8, k = t & 255;
    int seg = j >> 5, jj = j & 31;
    const float* s = (seg == 0) ? wq : (seg == 1) ? wk : (seg == 2) ? wv : (seg == 3) ? ws : wg;
    Wt[t] = f2b(s[k * 32 + jj]);
  }
  if (t < 160) {
    int seg = t >> 5, jj = t & 31;
    bp[t] = (seg == 0) ? bq[jj] : (seg == 1) ? bk[jj] : (seg == 2) ? bv[jj] : (seg == 3) ? bs[jj] : 0.0f;
  }
}

__global__ void k_tobf16(const float* __restrict__ x, u16* __restrict__ xb, int total) {
  int t = blockIdx.x * blockDim.x + threadIdx.x;
  if (t < total) xb[t] = f2b(x[t]);
}

// ------------------------------------------------ CSR build

__global__ void k_hist(const int* __restrict__ dst, int* __restrict__ deg) {
  int t = blockIdx.x * blockDim.x + threadIdx.x;
  if (t < NE) atomicAdd(&deg[dst[t]], 1);
}

__global__ void k_scan20000(const int* __restrict__ deg, int* __restrict__ offs,
                            int* __restrict__ cur) {
  __shared__ int part[1024];
  int t = threadIdx.x;
  int loc[20];
  int s = 0;
#pragma unroll
  for (int i = 0; i < 20; ++i) {
    int idx = t * 20 + i;
    int v = (idx < NN) ? deg[idx] : 0;
    loc[i] = s;
    s += v;
  }
  part[t] = s;
  __syncthreads();
  for (int off = 1; off < 1024; off <<= 1) {
    int v = (t >= off) ? part[t - off] : 0;
    __syncthreads();
    part[t] += v;
    __syncthreads();
  }
  int base = (t > 0) ? part[t - 1] : 0;
#pragma unroll
  for (int i = 0; i < 20; ++i) {
    int idx = t * 20 + i;
    if (idx < NN) {
      offs[idx] = base + loc[i];
      cur[idx] = base + loc[i];
    }
  }
  if (t == 1023) offs[NN] = part[1023];
}

__global__ void k_scatter(const int* __restrict__ src, const int* __restrict__ dst,
                          int* __restrict__ cur, int* __restrict__ esrcs) {
  int t = blockIdx.x * blockDim.x + threadIdx.x;
  if (t >= NE) return;
  int d = dst[t];
  int pos = atomicAdd(&cur[d], 1);
  esrcs[pos] = src[t];
}

// ------------------------------------------------ MFMA GEMM with split fp8/bf16 epilogue
// LAYER=1: Nc=1280, seg=col>>8: 0->G8 f(col), 2->G8 k(col-256), 3->G8 v(col-256),
//          1->Cb q(col-256), 4->Cb skip(col-768). G8 stride 768B, Cb stride 512.
// LAYER=2: Nc=160, seg=col>>5: 1->G k2(col-32), 2->G v2(col-32), 4->G h2(col-64),
//          0->Cb q2(col), 3->Cb s2(col-64). G stride 96B, Cb stride 64.
template <int LAYER>
__global__ void k_mfma_gemm_s(const u16* __restrict__ A0, const u16* __restrict__ A1,
                              int asel, const u16* __restrict__ Bt,
                              const float* __restrict__ bias, int M, int K, int Nc,
                              u8* __restrict__ G, u16* __restrict__ Cb) {
  const u16* A = (blockIdx.x >= (unsigned)asel) ? A1 : A0;
  int m0 = blockIdx.y * 128, n0 = blockIdx.x * 128;
  int wid = threadIdx.x >> 6, lane = threadIdx.x & 63;
  int mw = m0 + (wid & 1) * 64, nw = n0 + (wid >> 1) * 64;
  int arow = mw + (lane & 15);
  int bcol = nw + (lane & 15);
  int kblk = (lane >> 4) * 8;
  f32x4 acc[4][4] = {};
  const short8 zero8 = {0, 0, 0, 0, 0, 0, 0, 0};
  for (int k0 = 0; k0 < K; k0 += 32) {
    short8 af[4], bf[4];
#pragma unroll
    for (int mf = 0; mf < 4; ++mf) {
      int r = arow + mf * 16;
      if (r > M - 1) r = M - 1;
      af[mf] = *reinterpret_cast<const short8*>(&A[(size_t)r * K + k0 + kblk]);
    }
#pragma unroll
    for (int nf = 0; nf < 4; ++nf) {
      int c = bcol + nf * 16;
      bf[nf] = (c < Nc) ? *reinterpret_cast<const short8*>(&Bt[(size_t)c * K + k0 + kblk])
                        : zero8;
    }
#pragma unroll
    for (int mf = 0; mf < 4; ++mf)
#pragma unroll
      for (int nf = 0; nf < 4; ++nf)
        acc[mf][nf] = __builtin_amdgcn_mfma_f32_16x16x32_bf16(af[mf], bf[nf],
                                                              acc[mf][nf], 0, 0, 0);
  }
#pragma unroll
  for (int nf = 0; nf < 4; ++nf) {
    int col = nw + nf * 16 + (lane & 15);
    if (col >= Nc) continue;
    float bs = bias[col];
    int seg = (LAYER == 1) ? (col >> 8) : (col >> 5);
    bool tobf = (LAYER == 1) ? (seg == 1 || seg == 4) : (seg == 0 || seg == 3);
    int ccol, gcol;
    if (LAYER == 1) {
      ccol = (seg == 1) ? (col - 256) : (col - 768);
      gcol = (seg == 0) ? col : (col - 256);
    } else {
      ccol = (seg == 0) ? col : (col - 64);
      gcol = (seg == 4) ? (col - 64) : (col - 32);
    }
    const int CSTR = (LAYER == 1) ? 512 : 64;
    const int GSTR = (LAYER == 1) ? 768 : 96;
#pragma unroll
    for (int mf = 0; mf < 4; ++mf) {
      int rbase = mw + mf * 16 + (lane >> 4) * 4;
#pragma unroll
      for (int r = 0; r < 4; ++r) {
        int row = rbase + r;
        if (row >= M) continue;
        float val = acc[mf][nf][r] + bs;
        if (tobf) Cb[(size_t)row * CSTR + ccol] = f2b(val);
        else G[(size_t)row * GSTR + gcol] = f2q(val * FP8_SCALE);
      }
    }
  }
}

// ------------------------------------------------ attention pieces

// als/ald from fp8 features (scaled by FP8_SCALE): stride/coff in bytes
__global__ void k_gat_al8(const u8* __restrict__ h, int stride, int coff,
                          const float* __restrict__ asrc, const float* __restrict__ adst,
                          float* __restrict__ als, float* __restrict__ ald, int total,
                          int heads, int c) {
  int i = blockIdx.x * blockDim.x + threadIdx.x;
  if (i >= total) return;
  int node = i / heads, hd = i - node * heads;
  const u8* hp = h + (size_t)node * stride + coff + hd * c;
  const float* as = asrc + hd * c;
  const float* ad = adst + hd * c;
  float s1 = 0.0f, s2 = 0.0f;
  for (int k = 0; k < c; k += 4) {
    float f[4];
    q4(*reinterpret_cast<const unsigned int*>(&hp[k]), f);
#pragma unroll
    for (int j = 0; j < 4; ++j) {
      s1 = fmaf(f[j], as[k + j], s1);
      s2 = fmaf(f[j], ad[k + j], s2);
    }
  }
  als[i] = s1 * FP8_INV;
  ald[i] = s2 * FP8_INV;
}

// Layer-1 FUSED aggregate (GAT1 + GT1): one wave per dst, 2-stage pipelined.
// G8 row: f@0 k@256 v@512 (fp8, x16). C1b row: q@0 skip@256 (bf16).
__global__ void k_agg256_fused(const int* __restrict__ offs, const int* __restrict__ esrcs,
                               const float* __restrict__ als, const float* __restrict__ ald,
                               const u8* __restrict__ G8, const u16* __restrict__ C1b,
                               const float* __restrict__ gbias,
                               const float* __restrict__ pg, const float* __restrict__ pt,
                               u16* __restrict__ outG, u16* __restrict__ outT) {
  int d = blockIdx.x * 4 + (threadIdx.x >> 6);
  if (d >= NN) return;
  int lane = threadIdx.x & 63;
  int head = lane >> 4, c4 = lane << 2;
  ushort4 q4v = *reinterpret_cast<const ushort4*>(&C1b[(size_t)d * 512 + c4]);
  float q0 = b2f(q4v.x), q1 = b2f(q4v.y), q2 = b2f(q4v.z), q3 = b2f(q4v.w);
  float aldd = ald[d * 4 + head];
  float ga0 = 0, ga1 = 0, ga2 = 0, ga3 = 0, gden = 0.0f;
  float ta0 = 0, ta1 = 0, ta2 = 0, ta3 = 0, tden = 1e-16f;
  int b0 = offs[d], b1 = offs[d + 1];
  unsigned int fc = 0, kc = 0, vc = 0;
  float alc = 0.0f;
  if (b0 < b1) {
    int sc = esrcs[b0];
    const u8* row = &G8[(size_t)sc * 768];
    fc = *reinterpret_cast<const unsigned int*>(&row[c4]);
    kc = *reinterpret_cast<const unsigned int*>(&row[256 + c4]);
    vc = *reinterpret_cast<const unsigned int*>(&row[512 + c4]);
    alc = als[sc * 4 + head];
  }
  for (int i = b0; i < b1; ++i) {
    unsigned int fn = fc, kn = kc, vn = vc;
    float aln = alc;
    if (i + 1 < b1) {  // prefetch next edge
      int sn = esrcs[i + 1];
      const u8* row = &G8[(size_t)sn * 768];
      fn = *reinterpret_cast<const unsigned int*>(&row[c4]);
      kn = *reinterpret_cast<const unsigned int*>(&row[256 + c4]);
      vn = *reinterpret_cast<const unsigned int*>(&row[512 + c4]);
      aln = als[sn * 4 + head];
    }
    // GT chain
    float kf[4];
    q4(kc, kf);
    float pp = q0 * kf[0];
    pp = fmaf(q1, kf[1], pp);
    pp = fmaf(q2, kf[2], pp);
    pp = fmaf(q3, kf[3], pp);
    pp += __shfl_xor(pp, 1, 16);
    pp += __shfl_xor(pp, 2, 16);
    pp += __shfl_xor(pp, 4, 16);
    pp += __shfl_xor(pp, 8, 16);
    float pet = expf(pp * (0.125f * FP8_INV));
    // GAT chain
    float v = alc + aldd;
    float peg = expf(v >= 0.0f ? v : 0.2f * v);
    float ff[4], vf[4];
    q4(fc, ff);
    q4(vc, vf);
    ga0 = fmaf(peg, ff[0], ga0);
    ga1 = fmaf(peg, ff[1], ga1);
    ga2 = fmaf(peg, ff[2], ga2);
    ga3 = fmaf(peg, ff[3], ga3);
    gden += peg;
    ta0 = fmaf(pet, vf[0], ta0);
    ta1 = fmaf(pet, vf[1], ta1);
    ta2 = fmaf(pet, vf[2], ta2);
    ta3 = fmaf(pet, vf[3], ta3);
    tden += pet;
    fc = fn; kc = kn; vc = vn; alc = aln;
  }
  { // GAT self loop
    float v = als[d * 4 + head] + aldd;
    float pe = expf(v >= 0.0f ? v : 0.2f * v);
    float ff[4];
    q4(*reinterpret_cast<const unsigned int*>(&G8[(size_t)d * 768 + c4]), ff);
    ga0 = fmaf(pe, ff[0], ga0);
    ga1 = fmaf(pe, ff[1], ga1);
    ga2 = fmaf(pe, ff[2], ga2);
    ga3 = fmaf(pe, ff[3], ga3);
    gden += pe;
  }
  float ig = FP8_INV / gden, it = FP8_INV / tden;
  float o0 = ga0 * ig + gbias[c4 + 0];
  float o1 = ga1 * ig + gbias[c4 + 1];
  float o2 = ga2 * ig + gbias[c4 + 2];
  float o3 = ga3 * ig + gbias[c4 + 3];
  o0 = o0 >= 0.0f ? o0 : pg[c4 + 0] * o0;
  o1 = o1 >= 0.0f ? o1 : pg[c4 + 1] * o1;
  o2 = o2 >= 0.0f ? o2 : pg[c4 + 2] * o2;
  o3 = o3 >= 0.0f ? o3 : pg[c4 + 3] * o3;
  ushort4 wg4;
  wg4.x = f2b(o0); wg4.y = f2b(o1); wg4.z = f2b(o2); wg4.w = f2b(o3);
  *reinterpret_cast<ushort4*>(&outG[(size_t)d * 256 + c4]) = wg4;
  ushort4 sk = *reinterpret_cast<const ushort4*>(&C1b[(size_t)d * 512 + 256 + c4]);
  float u0 = ta0 * it + b2f(sk.x);
  float u1 = ta1 * it + b2f(sk.y);
  float u2 = ta2 * it + b2f(sk.z);
  float u3 = ta3 * it + b2f(sk.w);
  u0 = u0 >= 0.0f ? u0 : pt[c4 + 0] * u0;
  u1 = u1 >= 0.0f ? u1 : pt[c4 + 1] * u1;
  u2 = u2 >= 0.0f ? u2 : pt[c4 + 2] * u2;
  u3 = u3 >= 0.0f ? u3 : pt[c4 + 3] * u3;
  ushort4 wt4;
  wt4.x = f2b(u0); wt4.y = f2b(u1); wt4.z = f2b(u2); wt4.w = f2b(u3);
  *reinterpret_cast<ushort4*>(&outT[(size_t)d * 256 + c4]) = wt4;
}

// Layer-2 FUSED aggregate: 32 lanes per dst, 2-stage pipelined.
// G28 row: k2@0 v2@32 h2@64 (fp8 x16). C2b row: q2@0 s2@32 (bf16).
__global__ void k_agg32_fused(const int* __restrict__ offs, const int* __restrict__ esrcs,
                              const float* __restrict__ als, const float* __restrict__ ald,
                              const u8* __restrict__ G28, const u16* __restrict__ C2b,
                              const float* __restrict__ gbias,
                              const float* __restrict__ pg, const float* __restrict__ pt,
                              float* __restrict__ outG, float* __restrict__ outT) {
  int d = blockIdx.x * 8 + (threadIdx.x >> 5);
  if (d >= NN) return;
  int l = threadIdx.x & 31;
  float qv = b2f(C2b[(size_t)d * 64 + l]);
  float aldd = ald[d];
  float ga = 0.0f, gden = 0.0f;
  float ta = 0.0f, tden = 1e-16f;
  int b0 = offs[d], b1 = offs[d + 1];
  u8 kc = 0, vc = 0, hc = 0;
  float alc = 0;
  if (b0 < b1) {
    int sc = esrcs[b0];
    const u8* row = &G28[(size_t)sc * 96];
    kc = row[l]; vc = row[32 + l]; hc = row[64 + l];
    alc = als[sc];
  }
  for (int i = b0; i < b1; ++i) {
    u8 kn = kc, vn = vc, hn = hc;
    float aln = alc;
    if (i + 1 < b1) {
      int sn = esrcs[i + 1];
      const u8* row = &G28[(size_t)sn * 96];
      kn = row[l]; vn = row[32 + l]; hn = row[64 + l];
      aln = als[sn];
    }
    float pp = qv * q2f(kc);
    pp += __shfl_xor(pp, 1, 32);
    pp += __shfl_xor(pp, 2, 32);
    pp += __shfl_xor(pp, 4, 32);
    pp += __shfl_xor(pp, 8, 32);
    pp += __shfl_xor(pp, 16, 32);
    float pet = expf(pp * (0.17677669529663687f * FP8_INV));
    float v = alc + aldd;
    float peg = expf(v >= 0.0f ? v : 0.2f * v);
    ga = fmaf(peg, q2f(hc), ga);
    gden += peg;
    ta = fmaf(pet, q2f(vc), ta);
    tden += pet;
    kc = kn; vc = vn; hc = hn; alc = aln;
  }
  { // GAT self loop
    float v = als[d] + aldd;
    float pe = expf(v >= 0.0f ? v : 0.2f * v);
    ga = fmaf(pe, q2f(G28[(size_t)d * 96 + 64 + l]), ga);
    gden += pe;
  }
  float og = ga * FP8_INV / gden + gbias[l];
  og = og >= 0.0f ? og : pg[l] * og;
  outG[(size_t)d * 32 + l] = og;
  float ot = ta * FP8_INV / tden + b2f(C2b[(size_t)d * 64 + 32 + l]);
  ot = ot >= 0.0f ? ot : pt[l] * ot;
  outT[(size_t)d * 32 + l] = ot;
}

// ------------------------------------------------ epilogue

__global__ void k_fuse(const float* __restrict__ xg, const float* __restrict__ xt,
                       const float* __restrict__ w, const float* __restrict__ b,
                       float* __restrict__ out, int M) {
  int t = blockIdx.x * blockDim.x + threadIdx.x;
  if (t >= M * 32) return;
  int m = t >> 5, j = t & 31;
  const float* xgp = xg + (size_t)m * 32;
  const float* xtp = xt + (size_t)m * 32;
  float acc = b[j];
#pragma unroll
  for (int i = 0; i < 32; ++i) acc = fmaf(xgp[i], w[i * 32 + j], acc);
#pragma unroll
  for (int i = 0; i < 32; ++i) acc = fmaf(xtp[i], w[(32 + i) * 32 + j], acc);
  out[t] = acc;
}

__global__ void k_colmean_sig(const float* __restrict__ x, float* __restrict__ sig, int M) {
  __shared__ float red[256];
  int j = blockIdx.x;
  float s = 0.0f;
  for (int m = threadIdx.x; m < M; m += 256) s += x[(size_t)m * 32 + j];
  red[threadIdx.x] = s;
  __syncthreads();
  for (int w = 128; w > 0; w >>= 1) {
    if (threadIdx.x < w) red[threadIdx.x] += red[threadIdx.x + w];
    __syncthreads();
  }
  if (threadIdx.x == 0) sig[j] = 1.0f / (1.0f + expf(-red[0] / (float)M));
}

// summary2 + bilinear folded: m1 = disc_w @ (sig_o@mlp+b), m2 = disc_w @ (sig_a@mlp+b)
// ret_os[n] = [x2o[n].m1, x2a[n].m1]+db ; ret_os_a[n] = [x2a[n].m2, x2o[n].m2]+db
__global__ void k_disc_all(const float* __restrict__ x2o, const float* __restrict__ x2a_,
                           const float* __restrict__ sig_o, const float* __restrict__ sig_a,
                           const float* __restrict__ mlp_w, const float* __restrict__ mlp_b,
                           const float* __restrict__ disc_w, const float* __restrict__ db,
                           float* __restrict__ ret_os, float* __restrict__ ret_os_a) {
  __shared__ float h1s[32], h2s[32], m1[32], m2[32];
  int t = threadIdx.x;
  if (t < 64) {
    int j = t & 31;
    const float* sg = (t < 32) ? sig_o : sig_a;
    float acc = mlp_b[j];
#pragma unroll
    for (int i = 0; i < 32; ++i) acc = fmaf(sg[i], mlp_w[i * 32 + j], acc);
    (t < 32 ? h1s : h2s)[j] = acc;
  }
  __syncthreads();
  if (t < 64) {
    int k = t & 31;
    const float* hv = (t < 32) ? h1s : h2s;
    float acc = 0.0f;
#pragma unroll
    for (int i = 0; i < 32; ++i) acc = fmaf(disc_w[k * 32 + i], hv[i], acc);
    (t < 32 ? m1 : m2)[k] = acc;
  }
  __syncthreads();
  int n = blockIdx.x * blockDim.x + t;
  if (n >= NN) return;
  const float* a = x2o + (size_t)n * 32;
  const float* b = x2a_ + (size_t)n * 32;
  float s_oo = 0, s_ao = 0, s_aa = 0, s_oa = 0;
#pragma unroll
  for (int i = 0; i < 32; ++i) {
    float v1 = m1[i], v2 = m2[i];
    s_oo = fmaf(a[i], v1, s_oo);
    s_ao = fmaf(b[i], v1, s_ao);
    s_aa = fmaf(b[i], v2, s_aa);
    s_oa = fmaf(a[i], v2, s_oa);
  }
  float bb = db[0];
  ret_os[n * 2 + 0] = s_oo + bb;
  ret_os[n * 2 + 1] = s_ao + bb;
  ret_os_a[n * 2 + 0] = s_aa + bb;
  ret_os_a[n * 2 + 1] = s_oa + bb;
}

__global__ void k_dec1(const float* __restrict__ x2o, const int* __restrict__ idx0,
                       const int* __restrict__ idx1, const float* __restrict__ w,
                       const float* __restrict__ b1, float* __restrict__ hh) {
  int t = blockIdx.x * blockDim.x + threadIdx.x;
  if (t >= NB * 512) return;
  int bb = t >> 9, n = t & 511;
  const float* r0 = x2o + (size_t)idx0[bb] * 32;
  const float* r1 = x2o + (size_t)idx1[bb] * 32;
  float acc = b1[n];
#pragma unroll
  for (int i = 0; i < 32; ++i) acc = fmaf(r0[i], w[i * 512 + n], acc);
#pragma unroll
  for (int i = 0; i < 32; ++i) acc = fmaf(r1[i], w[(32 + i) * 512 + n], acc);
  hh[t] = fmaxf(acc, 0.0f);
}

// wave-parallel: one wave per output scalar (NB*4 waves)
__global__ void k_dec2w(const float* __restrict__ hh, const float* __restrict__ w2,
                        const float* __restrict__ b2, const float* __restrict__ w3,
                        const float* __restrict__ b3, float* __restrict__ logo,
                        float* __restrict__ log1) {
  int wv = (blockIdx.x * blockDim.x + threadIdx.x) >> 6;
  int lane = threadIdx.x & 63;
  if (wv >= NB * 4) return;
  int bb = wv >> 2, j = wv & 3;
  const float* h = hh + (size_t)bb * 512;
  const float* ws = (j < 2) ? w2 : w3;
  int jj = j & 1;
  float acc = 0.0f;
#pragma unroll
  for (int k = 0; k < 8; ++k) acc = fmaf(h[lane + k * 64], ws[(lane + k * 64) * 2 + jj], acc);
  acc += __shfl_xor(acc, 32);
  acc += __shfl_xor(acc, 16);
  acc += __shfl_xor(acc, 8);
  acc += __shfl_xor(acc, 4);
  acc += __shfl_xor(acc, 2);
  acc += __shfl_xor(acc, 1);
  if (lane == 0) {
    float b = (j < 2) ? b2[jj] : b3[jj];
    ((j < 2) ? logo : log1)[bb * 2 + jj] = acc + b;
  }
}

// adv logits with inline advprep
__global__ void k_adv(const float* __restrict__ x2o, const float* __restrict__ x2a,
                      const float* __restrict__ aw, const float* __restrict__ ab,
                      float* __restrict__ logits) {
  __shared__ float sadv[33];
  int t = threadIdx.x;
  if (t < 32) {
    float s = 0.0f;
#pragma unroll
    for (int j = 0; j < 32; ++j) s += aw[t * 32 + j];
    sadv[t] = s;
  } else if (t == 32) {
    float s = 0.0f;
#pragma unroll
    for (int j = 0; j < 32; ++j) s += ab[j];
    sadv[32] = s;
  }
  __syncthreads();
  int n = blockIdx.x * blockDim.x + t;
  if (n >= 2 * NN) return;
  const float* row = (n < NN) ? (x2o + (size_t)n * 32) : (x2a + (size_t)(n - NN) * 32);
  float acc = sadv[32];
#pragma unroll
  for (int i = 0; i < 32; ++i) acc = fmaf(row[i], sadv[i], acc);
  logits[n] = acc;
}

// ------------------------------------------------ host

extern "C" void kernel_launch(void* const* d_in, const int* in_sizes, int n_in,
                              void* d_out, int out_size, void* d_ws, size_t ws_size,
                              hipStream_t stream) {
  const float* x_o = (const float*)d_in[0];
  const float* x_a = (const float*)d_in[1];
  const float* gat1_w = (const float*)d_in[2];
  const float* gat1_asrc = (const float*)d_in[3];
  const float* gat1_adst = (const float*)d_in[4];
  const float* gat1_b = (const float*)d_in[5];
  const float* gat2_w = (const float*)d_in[6];
  const float* gat2_asrc = (const float*)d_in[7];
  const float* gat2_adst = (const float*)d_in[8];
  const float* gat2_b = (const float*)d_in[9];
  const float* pg1 = (const float*)d_in[10];
  const float* pg2 = (const float*)d_in[11];
  const float* gt1_wq = (const float*)d_in[12];
  const float* gt1_bq = (const float*)d_in[13];
  const float* gt1_wk = (const float*)d_in[14];
  const float* gt1_bk = (const float*)d_in[15];
  const float* gt1_wv = (const float*)d_in[16];
  const float* gt1_bv = (const float*)d_in[17];
  const float* gt1_ws = (const float*)d_in[18];
  const float* gt1_bs = (const float*)d_in[19];
  const float* gt2_wq = (const float*)d_in[20];
  const float* gt2_bq = (const float*)d_in[21];
  const float* gt2_wk = (const float*)d_in[22];
  const float* gt2_bk = (const float*)d_in[23];
  const float* gt2_wv = (const float*)d_in[24];
  const float* gt2_bv = (const float*)d_in[25];
  const float* gt2_ws = (const float*)d_in[26];
  const float* gt2_bs = (const float*)d_in[27];
  const float* pt1 = (const float*)d_in[28];
  const float* pt2 = (const float*)d_in[29];
  const float* fuse_w = (const float*)d_in[30];
  const float* fuse_b = (const float*)d_in[31];
  const float* mlp1_w = (const float*)d_in[32];
  const float* mlp1_b = (const float*)d_in[33];
  const float* disc_w = (const float*)d_in[34];
  const float* disc_b = (const float*)d_in[35];
  const float* fus_w1 = (const float*)d_in[36];
  const float* fus_b1 = (const float*)d_in[37];
  const float* fus_w2 = (const float*)d_in[38];
  const float* fus_b2 = (const float*)d_in[39];
  const float* fus_w3 = (const float*)d_in[40];
  const float* fus_b3 = (const float*)d_in[41];
  const float* adv_w = (const float*)d_in[42];
  const float* adv_b = (const float*)d_in[43];
  const int* ei = (const int*)d_in[44];
  const int* idxp = (const int*)d_in[45];
  const int* esrc = ei;
  const int* edst = ei + NE;
  const int* idx0 = idxp;
  const int* idx1 = idxp + NB;

  // ---- workspace carve (float units) ----
  float* w = (float*)d_ws;
  size_t o = 0;
  u8* G8 = (u8*)(w + o); o += 3840000;               // 20000*768 fp8
  u16* C1b = (u16*)(w + o); o += 5120000;            // 20000*512 bf16
  u8* G28 = (u8*)(w + o); o += 480000;               // 20000*96 fp8
  u16* C2b = (u16*)(w + o); o += 640000;             // 20000*64 bf16
  u16* bufB = (u16*)(w + o); o += 2560000;           // 20000*256 bf16
  u16* bufE = (u16*)(w + o); o += 2560000;           // 20000*256 bf16
  u16* xb_o = (u16*)(w + o); o += 1280000;           // 20000*128 bf16
  u16* xb_a = (u16*)(w + o); o += 1280000;
  u16* Wt1 = (u16*)(w + o); o += 81920;              // 1280*128 bf16
  u16* Wt2 = (u16*)(w + o); o += 20480;              // 160*256 bf16
  float* bp1 = w + o; o += 1280;
  float* bp2 = w + o; o += 160;
  float* als = w + o; o += NN * 4;
  float* ald = w + o; o += NN * 4;
  float* xg = w + o; o += NN * 32;
  float* xt = w + o; o += NN * 32;
  float* x2a = w + o; o += NN * 32;
  float* hh = w + o; o += NB * 512;
  int* deg = (int*)(w + o); o += NN;
  int* offs = (int*)(w + o); o += NN + 8;
  int* cur = (int*)(w + o); o += NN;
  int* esrcs = (int*)(w + o); o += NE;
  float* sml = w + o; o += 256;
  float* sig_o = sml;
  float* sig_a = sml + 32;

  float* out = (float*)d_out;
  float* out_log = out;               // [B,2]
  float* out_ret = out + 8192;        // [N,2]
  float* out_reta = out + 48192;      // [N,2]
  float* out_x2o = out + 88192;       // [N,32]
  float* out_logit = out + 728192;    // [1,2N]
  float* out_log1 = out + 768192;     // [B,2]

  // ---- weight packing + input conversion ----
  k_pack1<<<(1280 * 128 + 255) / 256, 256, 0, stream>>>(gat1_w, gt1_wq, gt1_wk, gt1_wv,
                                                        gt1_ws, gt1_bq, gt1_bk, gt1_bv,
                                                        gt1_bs, Wt1, bp1);
  k_pack2<<<(160 * 256 + 255) / 256, 256, 0, stream>>>(gt2_wq, gt2_wk, gt2_wv, gt2_ws,
                                                       gat2_w, gt2_bq, gt2_bk, gt2_bv,
                                                       gt2_bs, Wt2, bp2);
  k_tobf16<<<(NN * 128 + 255) / 256, 256, 0, stream>>>(x_o, xb_o, NN * 128);
  k_tobf16<<<(NN * 128 + 255) / 256, 256, 0, stream>>>(x_a, xb_a, NN * 128);
  // ---- CSR build ----
  hipMemsetAsync(deg, 0, NN * sizeof(int), stream);
  k_hist<<<(NE + 255) / 256, 256, 0, stream>>>(edst, deg);
  k_scan20000<<<1, 1024, 0, stream>>>(deg, offs, cur);
  k_scatter<<<(NE + 255) / 256, 256, 0, stream>>>(esrc, edst, cur, esrcs);

  auto branch = [&](const u16* xb, float* x2out) {
    // layer 1: MFMA GEMM -> G8 fp8 [f|k|v] + C1b bf16 [q|skip]
    {
      dim3 g(10, (NN + 127) / 128);
      k_mfma_gemm_s<1><<<g, 256, 0, stream>>>(xb, xb, 999, Wt1, bp1, NN, 128, 1280,
                                              G8, C1b);
    }
    k_gat_al8<<<(NN * 4 + 255) / 256, 256, 0, stream>>>(G8, 768, 0, gat1_asrc, gat1_adst,
                                                        als, ald, NN * 4, 4, 64);
    k_agg256_fused<<<(NN + 3) / 4, 256, 0, stream>>>(offs, esrcs, als, ald, G8, C1b,
                                                     gat1_b, pg1, pt1, bufB, bufE);
    // layer 2: MFMA GEMM -> G28 fp8 [k2|v2|h2] + C2b bf16 [q2|s2]
    {
      dim3 g(2, (NN + 127) / 128);
      k_mfma_gemm_s<2><<<g, 256, 0, stream>>>(bufE, bufB, 1, Wt2, bp2, NN, 256, 160,
                                              G28, C2b);
    }
    k_gat_al8<<<(NN + 255) / 256, 256, 0, stream>>>(G28, 96, 64, gat2_asrc, gat2_adst,
                                                    als, ald, NN, 1, 32);
    k_agg32_fused<<<(NN + 7) / 8, 256, 0, stream>>>(offs, esrcs, als, ald, G28, C2b,
                                                    gat2_b, pg2, pt2, xg, xt);
    k_fuse<<<(NN * 32 + 255) / 256, 256, 0, stream>>>(xg, xt, fuse_w, fuse_b, x2out, NN);
  };

  branch(xb_o, out_x2o);
  branch(xb_a, x2a);

  // ---- summary + discriminator ----
  k_colmean_sig<<<32, 256, 0, stream>>>(out_x2o, sig_o, NN);
  k_colmean_sig<<<32, 256, 0, stream>>>(x2a, sig_a, NN);
  k_disc_all<<<(NN + 255) / 256, 256, 0, stream>>>(out_x2o, x2a, sig_o, sig_a, mlp1_w,
                                                   mlp1_b, disc_w, disc_b, out_ret,
                                                   out_reta);
  // ---- decoder ----
  k_dec1<<<(NB * 512 + 255) / 256, 256, 0, stream>>>(out_x2o, idx0, idx1, fus_w1,
                                                     fus_b1, hh);
  k_dec2w<<<(NB * 4 * 64 + 255) / 256, 256, 0, stream>>>(hh, fus_w2, fus_b2, fus_w3,
                                                         fus_b3, out_log, out_log1);
  // ---- adversarial logits ----
  k_adv<<<(2 * NN + 255) / 256, 256, 0, stream>>>(out_x2o, x2a, adv_w, adv_b, out_logit);
}

// Round 7
// 529.245 us; speedup vs baseline: 7.3564x; 1.0519x over previous
//
#include <hip/hip_runtime.h>
#include <math.h>

#define NN 20000
#define NE 320000
#define NB 4096

typedef unsigned short u16;
typedef unsigned char u8;
typedef __attribute__((ext_vector_type(8))) short short8;
typedef __attribute__((ext_vector_type(4))) float f32x4;
typedef __attribute__((ext_vector_type(2))) float f32x2;

#define FP8_SCALE 16.0f
#define FP8_INV 0.0625f
#define LOG2E 1.44269504088896341f

__device__ __forceinline__ float b2f(u16 u) {
  unsigned int x = ((unsigned int)u) << 16;
  return __uint_as_float(x);
}
__device__ __forceinline__ u16 f2b(float f) {
  unsigned int x = __float_as_uint(f);
  return (u16)((x + 0x7fffu + ((x >> 16) & 1u)) >> 16);
}
__device__ __forceinline__ u8 f2q(float f) {  // f32 -> fp8 e4m3 (RNE, sat)
  return (u8)(__builtin_amdgcn_cvt_pk_fp8_f32(f, f, 0, false) & 0xff);
}
__device__ __forceinline__ float q2f(u8 b) {
  f32x2 v = __builtin_amdgcn_cvt_pk_f32_fp8((int)b, false);
  return v[0];
}
__device__ __forceinline__ void q4(unsigned int u, float* f) {
  f32x2 lo = __builtin_amdgcn_cvt_pk_f32_fp8((int)u, false);
  f32x2 hi = __builtin_amdgcn_cvt_pk_f32_fp8((int)u, true);
  f[0] = lo[0]; f[1] = lo[1]; f[2] = hi[0]; f[3] = hi[1];
}

// ------------------------------------------------ packing (transposed bf16 weights)

__global__ void k_pack1(const float* __restrict__ w0, const float* __restrict__ w1,
                        const float* __restrict__ w2, const float* __restrict__ w3,
                        const float* __restrict__ w4, const float* __restrict__ b1,
                        const float* __restrict__ b2, const float* __restrict__ b3,
                        const float* __restrict__ b4, u16* __restrict__ Wt,
                        float* __restrict__ bp) {
  int t = blockIdx.x * blockDim.x + threadIdx.x;
  if (t < 1280 * 128) {
    int j = t >> 7, k = t & 127;
    int seg = j >> 8, jj = j & 255;
    const float* s = (seg == 0) ? w0 : (seg == 1) ? w1 : (seg == 2) ? w2 : (seg == 3) ? w3 : w4;
    Wt[t] = f2b(s[k * 256 + jj]);
  }
  if (t < 1280) {
    int seg = t >> 8, jj = t & 255;
    bp[t] = (seg == 0) ? 0.0f : (seg == 1) ? b1[jj] : (seg == 2) ? b2[jj] : (seg == 3) ? b3[jj] : b4[jj];
  }
}

// cols: [wq2|wk2|wv2|ws2|gat2_w]; Wt2[j][k] (j<160, k<256)
__global__ void k_pack2(const float* __restrict__ wq, const float* __restrict__ wk,
                        const float* __restrict__ wv, const float* __restrict__ ws,
                        const float* __restrict__ wg, const float* __restrict__ bq,
                        const float* __restrict__ bk, const float* __restrict__ bv,
                        const float* __restrict__ bs, u16* __restrict__ Wt,
                        float* __restrict__ bp) {
  int t = blockIdx.x * blockDim.x + threadIdx.x;
  if (t < 160 * 256) {
    int j = t >> 8, k = t & 255;
    int seg = j >> 5, jj = j & 31;
    const float* s = (seg == 0) ? wq : (seg == 1) ? wk : (seg == 2) ? wv : (seg == 3) ? ws : wg;
    Wt[t] = f2b(s[k * 32 + jj]);
  }
  if (t < 160) {
    int seg = t >> 5, jj = t & 31;
    bp[t] = (seg == 0) ? bq[jj] : (seg == 1) ? bk[jj] : (seg == 2) ? bv[jj] : (seg == 3) ? bs[jj] : 0.0f;
  }
}

__global__ void k_tobf16(const float* __restrict__ x, u16* __restrict__ xb, int total) {
  int t = blockIdx.x * blockDim.x + threadIdx.x;
  if (t < total) xb[t] = f2b(x[t]);
}

// ------------------------------------------------ CSR build

__global__ void k_hist(const int* __restrict__ dst, int* __restrict__ deg) {
  int t = blockIdx.x * blockDim.x + threadIdx.x;
  if (t < NE) atomicAdd(&deg[dst[t]], 1);
}

__global__ void k_scan20000(const int* __restrict__ deg, int* __restrict__ offs,
                            int* __restrict__ cur) {
  __shared__ int part[1024];
  int t = threadIdx.x;
  int loc[20];
  int s = 0;
#pragma unroll
  for (int i = 0; i < 20; ++i) {
    int idx = t * 20 + i;
    int v = (idx < NN) ? deg[idx] : 0;
    loc[i] = s;
    s += v;
  }
  part[t] = s;
  __syncthreads();
  for (int off = 1; off < 1024; off <<= 1) {
    int v = (t >= off) ? part[t - off] : 0;
    __syncthreads();
    part[t] += v;
    __syncthreads();
  }
  int base = (t > 0) ? part[t - 1] : 0;
#pragma unroll
  for (int i = 0; i < 20; ++i) {
    int idx = t * 20 + i;
    if (idx < NN) {
      offs[idx] = base + loc[i];
      cur[idx] = base + loc[i];
    }
  }
  if (t == 1023) offs[NN] = part[1023];
}

__global__ void k_scatter(const int* __restrict__ src, const int* __restrict__ dst,
                          int* __restrict__ cur, int* __restrict__ esrcs) {
  int t = blockIdx.x * blockDim.x + threadIdx.x;
  if (t >= NE) return;
  int d = dst[t];
  int pos = atomicAdd(&cur[d], 1);
  esrcs[pos] = src[t];
}

// ------------------------------------------------ MFMA GEMM with split fp8/bf16 epilogue
// TRANSPOSED accumulate: acc = mfma(bf, af) = D^T, so per lane reg 0..3 are 4
// CONSECUTIVE COLUMNS at a fixed row -> packed 4B (fp8) / 8B (bf16) stores.
// LAYER=1: Nc=1280, seg=col>>8: 0->G8 f(col), 2->G8 k(col-256), 3->G8 v(col-256),
//          1->Cb q(col-256), 4->Cb skip(col-768). G8 stride 768B, Cb stride 512.
// LAYER=2: Nc=160, seg=col>>5: 1->G k2(col-32), 2->G v2(col-32), 4->G h2(col-64),
//          0->Cb q2(col), 3->Cb s2(col-64). G stride 96B, Cb stride 64.
template <int LAYER>
__global__ void k_mfma_gemm_s(const u16* __restrict__ A0, const u16* __restrict__ A1,
                              int asel, const u16* __restrict__ Bt,
                              const float* __restrict__ bias, int M, int K, int Nc,
                              u8* __restrict__ G, u16* __restrict__ Cb) {
  const u16* A = (blockIdx.x >= (unsigned)asel) ? A1 : A0;
  int m0 = blockIdx.y * 128, n0 = blockIdx.x * 128;
  int wid = threadIdx.x >> 6, lane = threadIdx.x & 63;
  int mw = m0 + (wid & 1) * 64, nw = n0 + (wid >> 1) * 64;
  int arow = mw + (lane & 15);
  int bcol = nw + (lane & 15);
  int kblk = (lane >> 4) * 8;
  f32x4 acc[4][4] = {};
  const short8 zero8 = {0, 0, 0, 0, 0, 0, 0, 0};
  for (int k0 = 0; k0 < K; k0 += 32) {
    short8 af[4], bf[4];
#pragma unroll
    for (int mf = 0; mf < 4; ++mf) {
      int r = arow + mf * 16;
      if (r > M - 1) r = M - 1;
      af[mf] = *reinterpret_cast<const short8*>(&A[(size_t)r * K + k0 + kblk]);
    }
#pragma unroll
    for (int nf = 0; nf < 4; ++nf) {
      int c = bcol + nf * 16;
      bf[nf] = (c < Nc) ? *reinterpret_cast<const short8*>(&Bt[(size_t)c * K + k0 + kblk])
                        : zero8;
    }
#pragma unroll
    for (int mf = 0; mf < 4; ++mf)
#pragma unroll
      for (int nf = 0; nf < 4; ++nf)
        acc[mf][nf] = __builtin_amdgcn_mfma_f32_16x16x32_bf16(bf[nf], af[mf],
                                                              acc[mf][nf], 0, 0, 0);
  }
  const int CSTR = (LAYER == 1) ? 512 : 64;
  const int GSTR = (LAYER == 1) ? 768 : 96;
#pragma unroll
  for (int mf = 0; mf < 4; ++mf) {
    int row = mw + mf * 16 + (lane & 15);
    if (row >= M) continue;
#pragma unroll
    for (int nf = 0; nf < 4; ++nf) {
      int col0 = nw + nf * 16 + ((lane >> 4) << 2);
      if (col0 >= Nc) continue;
      float4 bs4 = *reinterpret_cast<const float4*>(&bias[col0]);
      float v0 = acc[mf][nf][0] + bs4.x;
      float v1 = acc[mf][nf][1] + bs4.y;
      float v2 = acc[mf][nf][2] + bs4.z;
      float v3 = acc[mf][nf][3] + bs4.w;
      int seg = (LAYER == 1) ? (col0 >> 8) : (col0 >> 5);
      bool tobf = (LAYER == 1) ? (seg == 1 || seg == 4) : (seg == 0 || seg == 3);
      if (tobf) {
        int ccol = (LAYER == 1) ? ((seg == 1) ? col0 - 256 : col0 - 768)
                                : ((seg == 0) ? col0 : col0 - 64);
        ushort4 w4;
        w4.x = f2b(v0); w4.y = f2b(v1); w4.z = f2b(v2); w4.w = f2b(v3);
        *reinterpret_cast<ushort4*>(&Cb[(size_t)row * CSTR + ccol]) = w4;
      } else {
        int gcol = (LAYER == 1) ? ((seg == 0) ? col0 : col0 - 256)
                                : ((seg == 4) ? col0 - 64 : col0 - 32);
        unsigned int p = (unsigned int)__builtin_amdgcn_cvt_pk_fp8_f32(
            v0 * FP8_SCALE, v1 * FP8_SCALE, 0, false);
        p = (unsigned int)__builtin_amdgcn_cvt_pk_fp8_f32(
            v2 * FP8_SCALE, v3 * FP8_SCALE, (int)p, true);
        *reinterpret_cast<unsigned int*>(&G[(size_t)row * GSTR + gcol]) = p;
      }
    }
  }
}

// ------------------------------------------------ attention pieces

// als/ald from fp8 features (scaled by FP8_SCALE): stride/coff in bytes
__global__ void k_gat_al8(const u8* __restrict__ h, int stride, int coff,
                          const float* __restrict__ asrc, const float* __restrict__ adst,
                          float* __restrict__ als, float* __restrict__ ald, int total,
                          int heads, int c) {
  int i = blockIdx.x * blockDim.x + threadIdx.x;
  if (i >= total) return;
  int node = i / heads, hd = i - node * heads;
  const u8* hp = h + (size_t)node * stride + coff + hd * c;
  const float* as = asrc + hd * c;
  const float* ad = adst + hd * c;
  float s1 = 0.0f, s2 = 0.0f;
  for (int k = 0; k < c; k += 4) {
    float f[4];
    q4(*reinterpret_cast<const unsigned int*>(&hp[k]), f);
#pragma unroll
    for (int j = 0; j < 4; ++j) {
      s1 = fmaf(f[j], as[k + j], s1);
      s2 = fmaf(f[j], ad[k + j], s2);
    }
  }
  als[i] = s1 * FP8_INV;
  ald[i] = s2 * FP8_INV;
}

// Layer-1 FUSED aggregate (GAT1 + GT1): one wave per dst, 3-stage pipelined.
// G8 row: f@0 k@256 v@512 (fp8, x16). C1b row: q@0 skip@256 (bf16).
__global__ void k_agg256_fused(const int* __restrict__ offs, const int* __restrict__ esrcs,
                               const float* __restrict__ als, const float* __restrict__ ald,
                               const u8* __restrict__ G8, const u16* __restrict__ C1b,
                               const float* __restrict__ gbias,
                               const float* __restrict__ pg, const float* __restrict__ pt,
                               u16* __restrict__ outG, u16* __restrict__ outT) {
  int d = blockIdx.x * 4 + (threadIdx.x >> 6);
  if (d >= NN) return;
  int lane = threadIdx.x & 63;
  int head = lane >> 4, c4 = lane << 2;
  ushort4 q4v = *reinterpret_cast<const ushort4*>(&C1b[(size_t)d * 512 + c4]);
  float q0 = b2f(q4v.x), q1 = b2f(q4v.y), q2 = b2f(q4v.z), q3 = b2f(q4v.w);
  float aldd = ald[d * 4 + head];
  float ga0 = 0, ga1 = 0, ga2 = 0, ga3 = 0, gden = 0.0f;
  float ta0 = 0, ta1 = 0, ta2 = 0, ta3 = 0, tden = 1e-16f;
  int b0 = offs[d], b1 = offs[d + 1];
  const float GTC = 0.125f * FP8_INV * LOG2E;
  unsigned int f0 = 0, k0 = 0, v0 = 0, f1 = 0, k1 = 0, v1 = 0;
  float al0 = 0.0f, al1 = 0.0f;
  if (b0 < b1) {
    int s = esrcs[b0];
    const u8* row = &G8[(size_t)s * 768];
    f0 = *reinterpret_cast<const unsigned int*>(&row[c4]);
    k0 = *reinterpret_cast<const unsigned int*>(&row[256 + c4]);
    v0 = *reinterpret_cast<const unsigned int*>(&row[512 + c4]);
    al0 = als[s * 4 + head];
  }
  if (b0 + 1 < b1) {
    int s = esrcs[b0 + 1];
    const u8* row = &G8[(size_t)s * 768];
    f1 = *reinterpret_cast<const unsigned int*>(&row[c4]);
    k1 = *reinterpret_cast<const unsigned int*>(&row[256 + c4]);
    v1 = *reinterpret_cast<const unsigned int*>(&row[512 + c4]);
    al1 = als[s * 4 + head];
  }
  for (int i = b0; i < b1; ++i) {
    unsigned int f2_ = 0, k2_ = 0, v2_ = 0;
    float al2_ = 0.0f;
    if (i + 2 < b1) {  // prefetch 2 ahead
      int s = esrcs[i + 2];
      const u8* row = &G8[(size_t)s * 768];
      f2_ = *reinterpret_cast<const unsigned int*>(&row[c4]);
      k2_ = *reinterpret_cast<const unsigned int*>(&row[256 + c4]);
      v2_ = *reinterpret_cast<const unsigned int*>(&row[512 + c4]);
      al2_ = als[s * 4 + head];
    }
    // GT chain
    float kf[4];
    q4(k0, kf);
    float pp = q0 * kf[0];
    pp = fmaf(q1, kf[1], pp);
    pp = fmaf(q2, kf[2], pp);
    pp = fmaf(q3, kf[3], pp);
    pp += __shfl_xor(pp, 1, 16);
    pp += __shfl_xor(pp, 2, 16);
    pp += __shfl_xor(pp, 4, 16);
    pp += __shfl_xor(pp, 8, 16);
    float pet = exp2f(pp * GTC);
    // GAT chain (independent)
    float v = al0 + aldd;
    float peg = expf(v >= 0.0f ? v : 0.2f * v);
    float ff[4], vf[4];
    q4(f0, ff);
    q4(v0, vf);
    ga0 = fmaf(peg, ff[0], ga0);
    ga1 = fmaf(peg, ff[1], ga1);
    ga2 = fmaf(peg, ff[2], ga2);
    ga3 = fmaf(peg, ff[3], ga3);
    gden += peg;
    ta0 = fmaf(pet, vf[0], ta0);
    ta1 = fmaf(pet, vf[1], ta1);
    ta2 = fmaf(pet, vf[2], ta2);
    ta3 = fmaf(pet, vf[3], ta3);
    tden += pet;
    f0 = f1; k0 = k1; v0 = v1; al0 = al1;
    f1 = f2_; k1 = k2_; v1 = v2_; al1 = al2_;
  }
  { // GAT self loop
    float v = als[d * 4 + head] + aldd;
    float pe = expf(v >= 0.0f ? v : 0.2f * v);
    float ff[4];
    q4(*reinterpret_cast<const unsigned int*>(&G8[(size_t)d * 768 + c4]), ff);
    ga0 = fmaf(pe, ff[0], ga0);
    ga1 = fmaf(pe, ff[1], ga1);
    ga2 = fmaf(pe, ff[2], ga2);
    ga3 = fmaf(pe, ff[3], ga3);
    gden += pe;
  }
  float ig = FP8_INV / gden, it = FP8_INV / tden;
  float o0 = ga0 * ig + gbias[c4 + 0];
  float o1 = ga1 * ig + gbias[c4 + 1];
  float o2 = ga2 * ig + gbias[c4 + 2];
  float o3 = ga3 * ig + gbias[c4 + 3];
  o0 = o0 >= 0.0f ? o0 : pg[c4 + 0] * o0;
  o1 = o1 >= 0.0f ? o1 : pg[c4 + 1] * o1;
  o2 = o2 >= 0.0f ? o2 : pg[c4 + 2] * o2;
  o3 = o3 >= 0.0f ? o3 : pg[c4 + 3] * o3;
  ushort4 wg4;
  wg4.x = f2b(o0); wg4.y = f2b(o1); wg4.z = f2b(o2); wg4.w = f2b(o3);
  *reinterpret_cast<ushort4*>(&outG[(size_t)d * 256 + c4]) = wg4;
  ushort4 sk = *reinterpret_cast<const ushort4*>(&C1b[(size_t)d * 512 + 256 + c4]);
  float u0 = ta0 * it + b2f(sk.x);
  float u1 = ta1 * it + b2f(sk.y);
  float u2 = ta2 * it + b2f(sk.z);
  float u3 = ta3 * it + b2f(sk.w);
  u0 = u0 >= 0.0f ? u0 : pt[c4 + 0] * u0;
  u1 = u1 >= 0.0f ? u1 : pt[c4 + 1] * u1;
  u2 = u2 >= 0.0f ? u2 : pt[c4 + 2] * u2;
  u3 = u3 >= 0.0f ? u3 : pt[c4 + 3] * u3;
  ushort4 wt4;
  wt4.x = f2b(u0); wt4.y = f2b(u1); wt4.z = f2b(u2); wt4.w = f2b(u3);
  *reinterpret_cast<ushort4*>(&outT[(size_t)d * 256 + c4]) = wt4;
}

// Layer-2 FUSED aggregate: 32 lanes per dst, 2-stage pipelined.
// G28 row: k2@0 v2@32 h2@64 (fp8 x16). C2b row: q2@0 s2@32 (bf16).
__global__ void k_agg32_fused(const int* __restrict__ offs, const int* __restrict__ esrcs,
                              const float* __restrict__ als, const float* __restrict__ ald,
                              const u8* __restrict__ G28, const u16* __restrict__ C2b,
                              const float* __restrict__ gbias,
                              const float* __restrict__ pg, const float* __restrict__ pt,
                              float* __restrict__ outG, float* __restrict__ outT) {
  int d = blockIdx.x * 8 + (threadIdx.x >> 5);
  if (d >= NN) return;
  int l = threadIdx.x & 31;
  float qv = b2f(C2b[(size_t)d * 64 + l]);
  float aldd = ald[d];
  float ga = 0.0f, gden = 0.0f;
  float ta = 0.0f, tden = 1e-16f;
  int b0 = offs[d], b1 = offs[d + 1];
  const float GTC2 = 0.17677669529663687f * FP8_INV * LOG2E;
  u8 kc = 0, vc = 0, hc = 0;
  float alc = 0;
  if (b0 < b1) {
    int sc = esrcs[b0];
    const u8* row = &G28[(size_t)sc * 96];
    kc = row[l]; vc = row[32 + l]; hc = row[64 + l];
    alc = als[sc];
  }
  for (int i = b0; i < b1; ++i) {
    u8 kn = kc, vn = vc, hn = hc;
    float aln = alc;
    if (i + 1 < b1) {
      int sn = esrcs[i + 1];
      const u8* row = &G28[(size_t)sn * 96];
      kn = row[l]; vn = row[32 + l]; hn = row[64 + l];
      aln = als[sn];
    }
    float pp = qv * q2f(kc);
    pp += __shfl_xor(pp, 1, 32);
    pp += __shfl_xor(pp, 2, 32);
    pp += __shfl_xor(pp, 4, 32);
    pp += __shfl_xor(pp, 8, 32);
    pp += __shfl_xor(pp, 16, 32);
    float pet = exp2f(pp * GTC2);
    float v = alc + aldd;
    float peg = expf(v >= 0.0f ? v : 0.2f * v);
    ga = fmaf(peg, q2f(hc), ga);
    gden += peg;
    ta = fmaf(pet, q2f(vc), ta);
    tden += pet;
    kc = kn; vc = vn; hc = hn; alc = aln;
  }
  { // GAT self loop
    float v = als[d] + aldd;
    float pe = expf(v >= 0.0f ? v : 0.2f * v);
    ga = fmaf(pe, q2f(G28[(size_t)d * 96 + 64 + l]), ga);
    gden += pe;
  }
  float og = ga * FP8_INV / gden + gbias[l];
  og = og >= 0.0f ? og : pg[l] * og;
  outG[(size_t)d * 32 + l] = og;
  float ot = ta * FP8_INV / tden + b2f(C2b[(size_t)d * 64 + 32 + l]);
  ot = ot >= 0.0f ? ot : pt[l] * ot;
  outT[(size_t)d * 32 + l] = ot;
}

// ------------------------------------------------ epilogue

__global__ void k_fuse(const float* __restrict__ xg, const float* __restrict__ xt,
                       const float* __restrict__ w, const float* __restrict__ b,
                       float* __restrict__ out, int M) {
  int t = blockIdx.x * blockDim.x + threadIdx.x;
  if (t >= M * 32) return;
  int m = t >> 5, j = t & 31;
  const float* xgp = xg + (size_t)m * 32;
  const float* xtp = xt + (size_t)m * 32;
  float acc = b[j];
#pragma unroll
  for (int i = 0; i < 32; ++i) acc = fmaf(xgp[i], w[i * 32 + j], acc);
#pragma unroll
  for (int i = 0; i < 32; ++i) acc = fmaf(xtp[i], w[(32 + i) * 32 + j], acc);
  out[t] = acc;
}

__global__ void k_colmean_sig(const float* __restrict__ x, float* __restrict__ sig, int M) {
  __shared__ float red[256];
  int j = blockIdx.x;
  float s = 0.0f;
  for (int m = threadIdx.x; m < M; m += 256) s += x[(size_t)m * 32 + j];
  red[threadIdx.x] = s;
  __syncthreads();
  for (int w = 128; w > 0; w >>= 1) {
    if (threadIdx.x < w) red[threadIdx.x] += red[threadIdx.x + w];
    __syncthreads();
  }
  if (threadIdx.x == 0) sig[j] = 1.0f / (1.0f + expf(-red[0] / (float)M));
}

// summary2 + bilinear folded
__global__ void k_disc_all(const float* __restrict__ x2o, const float* __restrict__ x2a_,
                           const float* __restrict__ sig_o, const float* __restrict__ sig_a,
                           const float* __restrict__ mlp_w, const float* __restrict__ mlp_b,
                           const float* __restrict__ disc_w, const float* __restrict__ db,
                           float* __restrict__ ret_os, float* __restrict__ ret_os_a) {
  __shared__ float h1s[32], h2s[32], m1[32], m2[32];
  int t = threadIdx.x;
  if (t < 64) {
    int j = t & 31;
    const float* sg = (t < 32) ? sig_o : sig_a;
    float acc = mlp_b[j];
#pragma unroll
    for (int i = 0; i < 32; ++i) acc = fmaf(sg[i], mlp_w[i * 32 + j], acc);
    (t < 32 ? h1s : h2s)[j] = acc;
  }
  __syncthreads();
  if (t < 64) {
    int k = t & 31;
    const float* hv = (t < 32) ? h1s : h2s;
    float acc = 0.0f;
#pragma unroll
    for (int i = 0; i < 32; ++i) acc = fmaf(disc_w[k * 32 + i], hv[i], acc);
    (t < 32 ? m1 : m2)[k] = acc;
  }
  __syncthreads();
  int n = blockIdx.x * blockDim.x + t;
  if (n >= NN) return;
  const float* a = x2o + (size_t)n * 32;
  const float* b = x2a_ + (size_t)n * 32;
  float s_oo = 0, s_ao = 0, s_aa = 0, s_oa = 0;
#pragma unroll
  for (int i = 0; i < 32; ++i) {
    float v1 = m1[i], v2 = m2[i];
    s_oo = fmaf(a[i], v1, s_oo);
    s_ao = fmaf(b[i], v1, s_ao);
    s_aa = fmaf(b[i], v2, s_aa);
    s_oa = fmaf(a[i], v2, s_oa);
  }
  float bb = db[0];
  ret_os[n * 2 + 0] = s_oo + bb;
  ret_os[n * 2 + 1] = s_ao + bb;
  ret_os_a[n * 2 + 0] = s_aa + bb;
  ret_os_a[n * 2 + 1] = s_oa + bb;
}

__global__ void k_dec1(const float* __restrict__ x2o, const int* __restrict__ idx0,
                       const int* __restrict__ idx1, const float* __restrict__ w,
                       const float* __restrict__ b1, float* __restrict__ hh) {
  int t = blockIdx.x * blockDim.x + threadIdx.x;
  if (t >= NB * 512) return;
  int bb = t >> 9, n = t & 511;
  const float* r0 = x2o + (size_t)idx0[bb] * 32;
  const float* r1 = x2o + (size_t)idx1[bb] * 32;
  float acc = b1[n];
#pragma unroll
  for (int i = 0; i < 32; ++i) acc = fmaf(r0[i], w[i * 512 + n], acc);
#pragma unroll
  for (int i = 0; i < 32; ++i) acc = fmaf(r1[i], w[(32 + i) * 512 + n], acc);
  hh[t] = fmaxf(acc, 0.0f);
}

// wave-parallel: one wave per output scalar (NB*4 waves)
__global__ void k_dec2w(const float* __restrict__ hh, const float* __restrict__ w2,
                        const float* __restrict__ b2, const float* __restrict__ w3,
                        const float* __restrict__ b3, float* __restrict__ logo,
                        float* __restrict__ log1) {
  int wv = (blockIdx.x * blockDim.x + threadIdx.x) >> 6;
  int lane = threadIdx.x & 63;
  if (wv >= NB * 4) return;
  int bb = wv >> 2, j = wv & 3;
  const float* h = hh + (size_t)bb * 512;
  const float* ws = (j < 2) ? w2 : w3;
  int jj = j & 1;
  float acc = 0.0f;
#pragma unroll
  for (int k = 0; k < 8; ++k) acc = fmaf(h[lane + k * 64], ws[(lane + k * 64) * 2 + jj], acc);
  acc += __shfl_xor(acc, 32);
  acc += __shfl_xor(acc, 16);
  acc += __shfl_xor(acc, 8);
  acc += __shfl_xor(acc, 4);
  acc += __shfl_xor(acc, 2);
  acc += __shfl_xor(acc, 1);
  if (lane == 0) {
    float b = (j < 2) ? b2[jj] : b3[jj];
    ((j < 2) ? logo : log1)[bb * 2 + jj] = acc + b;
  }
}

// adv logits with inline advprep
__global__ void k_adv(const float* __restrict__ x2o, const float* __restrict__ x2a,
                      const float* __restrict__ aw, const float* __restrict__ ab,
                      float* __restrict__ logits) {
  __shared__ float sadv[33];
  int t = threadIdx.x;
  if (t < 32) {
    float s = 0.0f;
#pragma unroll
    for (int j = 0; j < 32; ++j) s += aw[t * 32 + j];
    sadv[t] = s;
  } else if (t == 32) {
    float s = 0.0f;
#pragma unroll
    for (int j = 0; j < 32; ++j) s += ab[j];
    sadv[32] = s;
  }
  __syncthreads();
  int n = blockIdx.x * blockDim.x + t;
  if (n >= 2 * NN) return;
  const float* row = (n < NN) ? (x2o + (size_t)n * 32) : (x2a + (size_t)(n - NN) * 32);
  float acc = sadv[32];
#pragma unroll
  for (int i = 0; i < 32; ++i) acc = fmaf(row[i], sadv[i], acc);
  logits[n] = acc;
}

// ------------------------------------------------ host

extern "C" void kernel_launch(void* const* d_in, const int* in_sizes, int n_in,
                              void* d_out, int out_size, void* d_ws, size_t ws_size,
                              hipStream_t stream) {
  const float* x_o = (const float*)d_in[0];
  const float* x_a = (const float*)d_in[1];
  const float* gat1_w = (const float*)d_in[2];
  const float* gat1_asrc = (const float*)d_in[3];
  const float* gat1_adst = (const float*)d_in[4];
  const float* gat1_b = (const float*)d_in[5];
  const float* gat2_w = (const float*)d_in[6];
  const float* gat2_asrc = (const float*)d_in[7];
  const float* gat2_adst = (const float*)d_in[8];
  const float* gat2_b = (const float*)d_in[9];
  const float* pg1 = (const float*)d_in[10];
  const float* pg2 = (const float*)d_in[11];
  const float* gt1_wq = (const float*)d_in[12];
  const float* gt1_bq = (const float*)d_in[13];
  const float* gt1_wk = (const float*)d_in[14];
  const float* gt1_bk = (const float*)d_in[15];
  const float* gt1_wv = (const float*)d_in[16];
  const float* gt1_bv = (const float*)d_in[17];
  const float* gt1_ws = (const float*)d_in[18];
  const float* gt1_bs = (const float*)d_in[19];
  const float* gt2_wq = (const float*)d_in[20];
  const float* gt2_bq = (const float*)d_in[21];
  const float* gt2_wk = (const float*)d_in[22];
  const float* gt2_bk = (const float*)d_in[23];
  const float* gt2_wv = (const float*)d_in[24];
  const float* gt2_bv = (const float*)d_in[25];
  const float* gt2_ws = (const float*)d_in[26];
  const float* gt2_bs = (const float*)d_in[27];
  const float* pt1 = (const float*)d_in[28];
  const float* pt2 = (const float*)d_in[29];
  const float* fuse_w = (const float*)d_in[30];
  const float* fuse_b = (const float*)d_in[31];
  const float* mlp1_w = (const float*)d_in[32];
  const float* mlp1_b = (const float*)d_in[33];
  const float* disc_w = (const float*)d_in[34];
  const float* disc_b = (const float*)d_in[35];
  const float* fus_w1 = (const float*)d_in[36];
  const float* fus_b1 = (const float*)d_in[37];
  const float* fus_w2 = (const float*)d_in[38];
  const float* fus_b2 = (const float*)d_in[39];
  const float* fus_w3 = (const float*)d_in[40];
  const float* fus_b3 = (const float*)d_in[41];
  const float* adv_w = (const float*)d_in[42];
  const float* adv_b = (const float*)d_in[43];
  const int* ei = (const int*)d_in[44];
  const int* idxp = (const int*)d_in[45];
  const int* esrc = ei;
  const int* edst = ei + NE;
  const int* idx0 = idxp;
  const int* idx1 = idxp + NB;

  // ---- workspace carve (float units) ----
  float* w = (float*)d_ws;
  size_t o = 0;
  u8* G8 = (u8*)(w + o); o += 3840000;               // 20000*768 fp8
  u16* C1b = (u16*)(w + o); o += 5120000;            // 20000*512 bf16
  u8* G28 = (u8*)(w + o); o += 480000;               // 20000*96 fp8
  u16* C2b = (u16*)(w + o); o += 640000;             // 20000*64 bf16
  u16* bufB = (u16*)(w + o); o += 2560000;           // 20000*256 bf16
  u16* bufE = (u16*)(w + o); o += 2560000;           // 20000*256 bf16
  u16* xb_o = (u16*)(w + o); o += 1280000;           // 20000*128 bf16
  u16* xb_a = (u16*)(w + o); o += 1280000;
  u16* Wt1 = (u16*)(w + o); o += 81920;              // 1280*128 bf16
  u16* Wt2 = (u16*)(w + o); o += 20480;              // 160*256 bf16
  float* bp1 = w + o; o += 1280;
  float* bp2 = w + o; o += 160;
  float* als = w + o; o += NN * 4;
  float* ald = w + o; o += NN * 4;
  float* xg = w + o; o += NN * 32;
  float* xt = w + o; o += NN * 32;
  float* x2a = w + o; o += NN * 32;
  float* hh = w + o; o += NB * 512;
  int* deg = (int*)(w + o); o += NN;
  int* offs = (int*)(w + o); o += NN + 8;
  int* cur = (int*)(w + o); o += NN;
  int* esrcs = (int*)(w + o); o += NE;
  float* sml = w + o; o += 256;
  float* sig_o = sml;
  float* sig_a = sml + 32;

  float* out = (float*)d_out;
  float* out_log = out;               // [B,2]
  float* out_ret = out + 8192;        // [N,2]
  float* out_reta = out + 48192;      // [N,2]
  float* out_x2o = out + 88192;       // [N,32]
  float* out_logit = out + 728192;    // [1,2N]
  float* out_log1 = out + 768192;     // [B,2]

  // ---- weight packing + input conversion ----
  k_pack1<<<(1280 * 128 + 255) / 256, 256, 0, stream>>>(gat1_w, gt1_wq, gt1_wk, gt1_wv,
                                                        gt1_ws, gt1_bq, gt1_bk, gt1_bv,
                                                        gt1_bs, Wt1, bp1);
  k_pack2<<<(160 * 256 + 255) / 256, 256, 0, stream>>>(gt2_wq, gt2_wk, gt2_wv, gt2_ws,
                                                       gat2_w, gt2_bq, gt2_bk, gt2_bv,
                                                       gt2_bs, Wt2, bp2);
  k_tobf16<<<(NN * 128 + 255) / 256, 256, 0, stream>>>(x_o, xb_o, NN * 128);
  k_tobf16<<<(NN * 128 + 255) / 256, 256, 0, stream>>>(x_a, xb_a, NN * 128);
  // ---- CSR build ----
  hipMemsetAsync(deg, 0, NN * sizeof(int), stream);
  k_hist<<<(NE + 255) / 256, 256, 0, stream>>>(edst, deg);
  k_scan20000<<<1, 1024, 0, stream>>>(deg, offs, cur);
  k_scatter<<<(NE + 255) / 256, 256, 0, stream>>>(esrc, edst, cur, esrcs);

  auto branch = [&](const u16* xb, float* x2out) {
    // layer 1: MFMA GEMM -> G8 fp8 [f|k|v] + C1b bf16 [q|skip]
    {
      dim3 g(10, (NN + 127) / 128);
      k_mfma_gemm_s<1><<<g, 256, 0, stream>>>(xb, xb, 999, Wt1, bp1, NN, 128, 1280,
                                              G8, C1b);
    }
    k_gat_al8<<<(NN * 4 + 255) / 256, 256, 0, stream>>>(G8, 768, 0, gat1_asrc, gat1_adst,
                                                        als, ald, NN * 4, 4, 64);
    k_agg256_fused<<<(NN + 3) / 4, 256, 0, stream>>>(offs, esrcs, als, ald, G8, C1b,
                                                     gat1_b, pg1, pt1, bufB, bufE);
    // layer 2: MFMA GEMM -> G28 fp8 [k2|v2|h2] + C2b bf16 [q2|s2]
    {
      dim3 g(2, (NN + 127) / 128);
      k_mfma_gemm_s<2><<<g, 256, 0, stream>>>(bufE, bufB, 1, Wt2, bp2, NN, 256, 160,
                                              G28, C2b);
    }
    k_gat_al8<<<(NN + 255) / 256, 256, 0, stream>>>(G28, 96, 64, gat2_asrc, gat2_adst,
                                                    als, ald, NN, 1, 32);
    k_agg32_fused<<<(NN + 7) / 8, 256, 0, stream>>>(offs, esrcs, als, ald, G28, C2b,
                                                    gat2_b, pg2, pt2, xg, xt);
    k_fuse<<<(NN * 32 + 255) / 256, 256, 0, stream>>>(xg, xt, fuse_w, fuse_b, x2out, NN);
  };

  branch(xb_o, out_x2o);
  branch(xb_a, x2a);

  // ---- summary + discriminator ----
  k_colmean_sig<<<32, 256, 0, stream>>>(out_x2o, sig_o, NN);
  k_colmean_sig<<<32, 256, 0, stream>>>(x2a, sig_a, NN);
  k_disc_all<<<(NN + 255) / 256, 256, 0, stream>>>(out_x2o, x2a, sig_o, sig_a, mlp1_w,
                                                   mlp1_b, disc_w, disc_b, out_ret,
                                                   out_reta);
  // ---- decoder ----
  k_dec1<<<(NB * 512 + 255) / 256, 256, 0, stream>>>(out_x2o, idx0, idx1, fus_w1,
                                                     fus_b1, hh);
  k_dec2w<<<(NB * 4 * 64 + 255) / 256, 256, 0, stream>>>(hh, fus_w2, fus_b2, fus_w3,
                                                         fus_b3, out_log, out_log1);
  // ---- adversarial logits ----
  k_adv<<<(2 * NN + 255) / 256, 256, 0, stream>>>(out_x2o, x2a, adv_w, adv_b, out_logit);
}

// Round 9
// 464.398 us; speedup vs baseline: 8.3837x; 1.1396x over previous
//
#include <hip/hip_runtime.h>
#include <math.h>

#define NN 20000
#define NE 320000
#define NB 4096

typedef unsigned short u16;
typedef unsigned char u8;
typedef __attribute__((ext_vector_type(8))) short short8;
typedef __attribute__((ext_vector_type(4))) float f32x4;
typedef __attribute__((ext_vector_type(2))) float f32x2;

#define FP8_SCALE 16.0f
#define FP8_INV 0.0625f
#define LOG2E 1.44269504088896341f

__device__ __forceinline__ float b2f(u16 u) {
  unsigned int x = ((unsigned int)u) << 16;
  return __uint_as_float(x);
}
__device__ __forceinline__ u16 f2b(float f) {
  unsigned int x = __float_as_uint(f);
  return (u16)((x + 0x7fffu + ((x >> 16) & 1u)) >> 16);
}
__device__ __forceinline__ float q2f(u8 b) {
  f32x2 v = __builtin_amdgcn_cvt_pk_f32_fp8((int)b, false);
  return v[0];
}
__device__ __forceinline__ void q4(unsigned int u, float* f) {
  f32x2 lo = __builtin_amdgcn_cvt_pk_f32_fp8((int)u, false);
  f32x2 hi = __builtin_amdgcn_cvt_pk_f32_fp8((int)u, true);
  f[0] = lo[0]; f[1] = lo[1]; f[2] = hi[0]; f[3] = hi[1];
}
// DPP butterfly add (VALU, no LDS). CTRL must be a compile-time constant.
template <int CTRL>
__device__ __forceinline__ float dppadd(float x) {
  int y = __builtin_amdgcn_update_dpp(0, __float_as_int(x), CTRL, 0xf, 0xf, true);
  return x + __int_as_float(y);
}
// sum over 16-lane group: xor1, xor2, row_ror:4, row_ror:8
__device__ __forceinline__ float red16(float x) {
  x = dppadd<0xB1>(x);
  x = dppadd<0x4E>(x);
  x = dppadd<0x124>(x);
  x = dppadd<0x128>(x);
  return x;
}

// ------------------------------------------------ packing (transposed bf16 weights)

__global__ void k_pack1(const float* __restrict__ w0, const float* __restrict__ w1,
                        const float* __restrict__ w2, const float* __restrict__ w3,
                        const float* __restrict__ w4, const float* __restrict__ b1,
                        const float* __restrict__ b2, const float* __restrict__ b3,
                        const float* __restrict__ b4, u16* __restrict__ Wt,
                        float* __restrict__ bp) {
  int t = blockIdx.x * blockDim.x + threadIdx.x;
  if (t < 1280 * 128) {
    int j = t >> 7, k = t & 127;
    int seg = j >> 8, jj = j & 255;
    const float* s = (seg == 0) ? w0 : (seg == 1) ? w1 : (seg == 2) ? w2 : (seg == 3) ? w3 : w4;
    Wt[t] = f2b(s[k * 256 + jj]);
  }
  if (t < 1280) {
    int seg = t >> 8, jj = t & 255;
    bp[t] = (seg == 0) ? 0.0f : (seg == 1) ? b1[jj] : (seg == 2) ? b2[jj] : (seg == 3) ? b3[jj] : b4[jj];
  }
}

__global__ void k_pack2(const float* __restrict__ wq, const float* __restrict__ wk,
                        const float* __restrict__ wv, const float* __restrict__ ws,
                        const float* __restrict__ wg, const float* __restrict__ bq,
                        const float* __restrict__ bk, const float* __restrict__ bv,
                        const float* __restrict__ bs, u16* __restrict__ Wt,
                        float* __restrict__ bp) {
  int t = blockIdx.x * blockDim.x + threadIdx.x;
  if (t < 160 * 256) {
    int j = t >> 8, k = t & 255;
    int seg = j >> 5, jj = j & 31;
    const float* s = (seg == 0) ? wq : (seg == 1) ? wk : (seg == 2) ? wv : (seg == 3) ? ws : wg;
    Wt[t] = f2b(s[k * 32 + jj]);
  }
  if (t < 160) {
    int seg = t >> 5, jj = t & 31;
    bp[t] = (seg == 0) ? bq[jj] : (seg == 1) ? bk[jj] : (seg == 2) ? bv[jj] : (seg == 3) ? bs[jj] : 0.0f;
  }
}

// both inputs in one launch
__global__ void k_tobf16x2(const float* __restrict__ xo, const float* __restrict__ xa,
                           u16* __restrict__ bo, u16* __restrict__ ba) {
  int t = blockIdx.x * blockDim.x + threadIdx.x;
  if (t >= 2 * NN * 128) return;
  if (t < NN * 128) bo[t] = f2b(xo[t]);
  else ba[t - NN * 128] = f2b(xa[t - NN * 128]);
}

// ------------------------------------------------ CSR build

__global__ void k_hist(const int* __restrict__ dst, int* __restrict__ deg) {
  int t = blockIdx.x * blockDim.x + threadIdx.x;
  if (t < NE) atomicAdd(&deg[dst[t]], 1);
}

__global__ void k_scan20000(const int* __restrict__ deg, int* __restrict__ offs,
                            int* __restrict__ cur) {
  __shared__ int part[1024];
  int t = threadIdx.x;
  int loc[20];
  int s = 0;
#pragma unroll
  for (int i = 0; i < 20; ++i) {
    int idx = t * 20 + i;
    int v = (idx < NN) ? deg[idx] : 0;
    loc[i] = s;
    s += v;
  }
  part[t] = s;
  __syncthreads();
  for (int off = 1; off < 1024; off <<= 1) {
    int v = (t >= off) ? part[t - off] : 0;
    __syncthreads();
    part[t] += v;
    __syncthreads();
  }
  int base = (t > 0) ? part[t - 1] : 0;
#pragma unroll
  for (int i = 0; i < 20; ++i) {
    int idx = t * 20 + i;
    if (idx < NN) {
      offs[idx] = base + loc[i];
      cur[idx] = base + loc[i];
    }
  }
  if (t == 1023) offs[NN] = part[1023];
}

__global__ void k_scatter(const int* __restrict__ src, const int* __restrict__ dst,
                          int* __restrict__ cur, int* __restrict__ esrcs) {
  int t = blockIdx.x * blockDim.x + threadIdx.x;
  if (t >= NE) return;
  int d = dst[t];
  int pos = atomicAdd(&cur[d], 1);
  esrcs[pos] = src[t];
}

// ------------------------------------------------ MFMA GEMM, transposed epilogue (proven r7)

template <int LAYER>
__global__ void k_mfma_gemm_s(const u16* __restrict__ A0, const u16* __restrict__ A1,
                              int asel, const u16* __restrict__ Bt,
                              const float* __restrict__ bias, int M, int K, int Nc,
                              u8* __restrict__ G, u16* __restrict__ Cb) {
  const u16* A = (blockIdx.x >= (unsigned)asel) ? A1 : A0;
  int m0 = blockIdx.y * 128, n0 = blockIdx.x * 128;
  int wid = threadIdx.x >> 6, lane = threadIdx.x & 63;
  int mw = m0 + (wid & 1) * 64, nw = n0 + (wid >> 1) * 64;
  int arow = mw + (lane & 15);
  int bcol = nw + (lane & 15);
  int kblk = (lane >> 4) * 8;
  f32x4 acc[4][4] = {};
  const short8 zero8 = {0, 0, 0, 0, 0, 0, 0, 0};
  for (int k0 = 0; k0 < K; k0 += 32) {
    short8 af[4], bf[4];
#pragma unroll
    for (int mf = 0; mf < 4; ++mf) {
      int r = arow + mf * 16;
      if (r > M - 1) r = M - 1;
      af[mf] = *reinterpret_cast<const short8*>(&A[(size_t)r * K + k0 + kblk]);
    }
#pragma unroll
    for (int nf = 0; nf < 4; ++nf) {
      int c = bcol + nf * 16;
      bf[nf] = (c < Nc) ? *reinterpret_cast<const short8*>(&Bt[(size_t)c * K + k0 + kblk])
                        : zero8;
    }
#pragma unroll
    for (int mf = 0; mf < 4; ++mf)
#pragma unroll
      for (int nf = 0; nf < 4; ++nf)
        acc[mf][nf] = __builtin_amdgcn_mfma_f32_16x16x32_bf16(bf[nf], af[mf],
                                                              acc[mf][nf], 0, 0, 0);
  }
  const int CSTR = (LAYER == 1) ? 512 : 64;
  const int GSTR = (LAYER == 1) ? 768 : 96;
#pragma unroll
  for (int mf = 0; mf < 4; ++mf) {
    int row = mw + mf * 16 + (lane & 15);
    if (row >= M) continue;
#pragma unroll
    for (int nf = 0; nf < 4; ++nf) {
      int col0 = nw + nf * 16 + ((lane >> 4) << 2);
      if (col0 >= Nc) continue;
      float4 bs4 = *reinterpret_cast<const float4*>(&bias[col0]);
      float v0 = acc[mf][nf][0] + bs4.x;
      float v1 = acc[mf][nf][1] + bs4.y;
      float v2 = acc[mf][nf][2] + bs4.z;
      float v3 = acc[mf][nf][3] + bs4.w;
      int seg = (LAYER == 1) ? (col0 >> 8) : (col0 >> 5);
      bool tobf = (LAYER == 1) ? (seg == 1 || seg == 4) : (seg == 0 || seg == 3);
      if (tobf) {
        int ccol = (LAYER == 1) ? ((seg == 1) ? col0 - 256 : col0 - 768)
                                : ((seg == 0) ? col0 : col0 - 64);
        ushort4 w4;
        w4.x = f2b(v0); w4.y = f2b(v1); w4.z = f2b(v2); w4.w = f2b(v3);
        *reinterpret_cast<ushort4*>(&Cb[(size_t)row * CSTR + ccol]) = w4;
      } else {
        int gcol = (LAYER == 1) ? ((seg == 0) ? col0 : col0 - 256)
                                : ((seg == 4) ? col0 - 64 : col0 - 32);
        unsigned int p = (unsigned int)__builtin_amdgcn_cvt_pk_fp8_f32(
            v0 * FP8_SCALE, v1 * FP8_SCALE, 0, false);
        p = (unsigned int)__builtin_amdgcn_cvt_pk_fp8_f32(
            v2 * FP8_SCALE, v3 * FP8_SCALE, (int)p, true);
        *reinterpret_cast<unsigned int*>(&G[(size_t)row * GSTR + gcol]) = p;
      }
    }
  }
}

// ------------------------------------------------ attention pieces

// als/ald from fp8, PRE-SCALED by LOG2E (consumers use exp2)
__global__ void k_gat_al8(const u8* __restrict__ h, int stride, int coff,
                          const float* __restrict__ asrc, const float* __restrict__ adst,
                          float* __restrict__ als, float* __restrict__ ald, int total,
                          int heads, int c) {
  int i = blockIdx.x * blockDim.x + threadIdx.x;
  if (i >= total) return;
  int node = i / heads, hd = i - node * heads;
  const u8* hp = h + (size_t)node * stride + coff + hd * c;
  const float* as = asrc + hd * c;
  const float* ad = adst + hd * c;
  float s1 = 0.0f, s2 = 0.0f;
  for (int k = 0; k < c; k += 4) {
    float f[4];
    q4(*reinterpret_cast<const unsigned int*>(&hp[k]), f);
#pragma unroll
    for (int j = 0; j < 4; ++j) {
      s1 = fmaf(f[j], as[k + j], s1);
      s2 = fmaf(f[j], ad[k + j], s2);
    }
  }
  als[i] = s1 * (FP8_INV * LOG2E);
  ald[i] = s2 * (FP8_INV * LOG2E);
}

// Layer-1 FUSED aggregate (GAT1 + GT1): one wave per dst, 3-stage pipelined, DPP reduce.
__global__ void k_agg256_fused(const int* __restrict__ offs, const int* __restrict__ esrcs,
                               const float* __restrict__ als, const float* __restrict__ ald,
                               const u8* __restrict__ G8, const u16* __restrict__ C1b,
                               const float* __restrict__ gbias,
                               const float* __restrict__ pg, const float* __restrict__ pt,
                               u16* __restrict__ outG, u16* __restrict__ outT) {
  int d = blockIdx.x * 4 + (threadIdx.x >> 6);
  if (d >= NN) return;
  int lane = threadIdx.x & 63;
  int head = lane >> 4, c4 = lane << 2;
  ushort4 q4v = *reinterpret_cast<const ushort4*>(&C1b[(size_t)d * 512 + c4]);
  float q0 = b2f(q4v.x), q1 = b2f(q4v.y), q2 = b2f(q4v.z), q3 = b2f(q4v.w);
  float aldd = ald[d * 4 + head];
  float ga0 = 0, ga1 = 0, ga2 = 0, ga3 = 0, gden = 0.0f;
  float ta0 = 0, ta1 = 0, ta2 = 0, ta3 = 0, tden = 1e-16f;
  int b0 = offs[d], b1 = offs[d + 1];
  const float GTC = 0.125f * FP8_INV * LOG2E;
  unsigned int f0 = 0, k0 = 0, v0 = 0, f1 = 0, k1 = 0, v1 = 0;
  float al0 = 0.0f, al1 = 0.0f;
  if (b0 < b1) {
    int s = esrcs[b0];
    const u8* row = &G8[(size_t)s * 768];
    f0 = *reinterpret_cast<const unsigned int*>(&row[c4]);
    k0 = *reinterpret_cast<const unsigned int*>(&row[256 + c4]);
    v0 = *reinterpret_cast<const unsigned int*>(&row[512 + c4]);
    al0 = als[s * 4 + head];
  }
  if (b0 + 1 < b1) {
    int s = esrcs[b0 + 1];
    const u8* row = &G8[(size_t)s * 768];
    f1 = *reinterpret_cast<const unsigned int*>(&row[c4]);
    k1 = *reinterpret_cast<const unsigned int*>(&row[256 + c4]);
    v1 = *reinterpret_cast<const unsigned int*>(&row[512 + c4]);
    al1 = als[s * 4 + head];
  }
  for (int i = b0; i < b1; ++i) {
    unsigned int f2_ = 0, k2_ = 0, v2_ = 0;
    float al2_ = 0.0f;
    if (i + 2 < b1) {  // prefetch 2 ahead
      int s = esrcs[i + 2];
      const u8* row = &G8[(size_t)s * 768];
      f2_ = *reinterpret_cast<const unsigned int*>(&row[c4]);
      k2_ = *reinterpret_cast<const unsigned int*>(&row[256 + c4]);
      v2_ = *reinterpret_cast<const unsigned int*>(&row[512 + c4]);
      al2_ = als[s * 4 + head];
    }
    // GT chain (DPP reduce over 16-lane head group)
    float kf[4];
    q4(k0, kf);
    float pp = q0 * kf[0];
    pp = fmaf(q1, kf[1], pp);
    pp = fmaf(q2, kf[2], pp);
    pp = fmaf(q3, kf[3], pp);
    pp = red16(pp);
    float pet = exp2f(pp * GTC);
    // GAT chain (als pre-scaled by log2e -> exp2)
    float v = al0 + aldd;
    float peg = exp2f(v >= 0.0f ? v : 0.2f * v);
    float ff[4], vf[4];
    q4(f0, ff);
    q4(v0, vf);
    ga0 = fmaf(peg, ff[0], ga0);
    ga1 = fmaf(peg, ff[1], ga1);
    ga2 = fmaf(peg, ff[2], ga2);
    ga3 = fmaf(peg, ff[3], ga3);
    gden += peg;
    ta0 = fmaf(pet, vf[0], ta0);
    ta1 = fmaf(pet, vf[1], ta1);
    ta2 = fmaf(pet, vf[2], ta2);
    ta3 = fmaf(pet, vf[3], ta3);
    tden += pet;
    f0 = f1; k0 = k1; v0 = v1; al0 = al1;
    f1 = f2_; k1 = k2_; v1 = v2_; al1 = al2_;
  }
  { // GAT self loop
    float v = als[d * 4 + head] + aldd;
    float pe = exp2f(v >= 0.0f ? v : 0.2f * v);
    float ff[4];
    q4(*reinterpret_cast<const unsigned int*>(&G8[(size_t)d * 768 + c4]), ff);
    ga0 = fmaf(pe, ff[0], ga0);
    ga1 = fmaf(pe, ff[1], ga1);
    ga2 = fmaf(pe, ff[2], ga2);
    ga3 = fmaf(pe, ff[3], ga3);
    gden += pe;
  }
  float ig = FP8_INV / gden, it = FP8_INV / tden;
  float o0 = ga0 * ig + gbias[c4 + 0];
  float o1 = ga1 * ig + gbias[c4 + 1];
  float o2 = ga2 * ig + gbias[c4 + 2];
  float o3 = ga3 * ig + gbias[c4 + 3];
  o0 = o0 >= 0.0f ? o0 : pg[c4 + 0] * o0;
  o1 = o1 >= 0.0f ? o1 : pg[c4 + 1] * o1;
  o2 = o2 >= 0.0f ? o2 : pg[c4 + 2] * o2;
  o3 = o3 >= 0.0f ? o3 : pg[c4 + 3] * o3;
  ushort4 wg4;
  wg4.x = f2b(o0); wg4.y = f2b(o1); wg4.z = f2b(o2); wg4.w = f2b(o3);
  *reinterpret_cast<ushort4*>(&outG[(size_t)d * 256 + c4]) = wg4;
  ushort4 sk = *reinterpret_cast<const ushort4*>(&C1b[(size_t)d * 512 + 256 + c4]);
  float u0 = ta0 * it + b2f(sk.x);
  float u1 = ta1 * it + b2f(sk.y);
  float u2 = ta2 * it + b2f(sk.z);
  float u3 = ta3 * it + b2f(sk.w);
  u0 = u0 >= 0.0f ? u0 : pt[c4 + 0] * u0;
  u1 = u1 >= 0.0f ? u1 : pt[c4 + 1] * u1;
  u2 = u2 >= 0.0f ? u2 : pt[c4 + 2] * u2;
  u3 = u3 >= 0.0f ? u3 : pt[c4 + 3] * u3;
  ushort4 wt4;
  wt4.x = f2b(u0); wt4.y = f2b(u1); wt4.z = f2b(u2); wt4.w = f2b(u3);
  *reinterpret_cast<ushort4*>(&outT[(size_t)d * 256 + c4]) = wt4;
}

// Layer-2 FUSED aggregate + fuse_w matmul + column-sum accumulation.
// 8 dst/block (exactly NN/8 blocks). G28 row: k2@0 v2@32 h2@64. C2b row: q2@0 s2@32.
__global__ void k_agg32_fuse(const int* __restrict__ offs, const int* __restrict__ esrcs,
                             const float* __restrict__ als, const float* __restrict__ ald,
                             const u8* __restrict__ G28, const u16* __restrict__ C2b,
                             const float* __restrict__ gbias,
                             const float* __restrict__ pg, const float* __restrict__ pt,
                             const float* __restrict__ fw, const float* __restrict__ fb,
                             float* __restrict__ x2out, float* __restrict__ colsum) {
  __shared__ float xgv[8][32], xtv[8][32];
  int g = threadIdx.x >> 5, l = threadIdx.x & 31;
  int d = blockIdx.x * 8 + g;
  float qv = b2f(C2b[(size_t)d * 64 + l]);
  float aldd = ald[d];
  float ga = 0.0f, gden = 0.0f;
  float ta = 0.0f, tden = 1e-16f;
  int b0 = offs[d], b1 = offs[d + 1];
  const float GTC2 = 0.17677669529663687f * FP8_INV * LOG2E;
  u8 kc = 0, vc = 0, hc = 0;
  float alc = 0;
  if (b0 < b1) {
    int sc = esrcs[b0];
    const u8* row = &G28[(size_t)sc * 96];
    kc = row[l]; vc = row[32 + l]; hc = row[64 + l];
    alc = als[sc];
  }
  for (int i = b0; i < b1; ++i) {
    u8 kn = kc, vn = vc, hn = hc;
    float aln = alc;
    if (i + 1 < b1) {
      int sn = esrcs[i + 1];
      const u8* row = &G28[(size_t)sn * 96];
      kn = row[l]; vn = row[32 + l]; hn = row[64 + l];
      aln = als[sn];
    }
    float pp = qv * q2f(kc);
    pp = red16(pp);
    pp += __shfl_xor(pp, 16, 32);
    float pet = exp2f(pp * GTC2);
    float v = alc + aldd;
    float peg = exp2f(v >= 0.0f ? v : 0.2f * v);
    ga = fmaf(peg, q2f(hc), ga);
    gden += peg;
    ta = fmaf(pet, q2f(vc), ta);
    tden += pet;
    kc = kn; vc = vn; hc = hn; alc = aln;
  }
  { // GAT self loop
    float v = als[d] + aldd;
    float pe = exp2f(v >= 0.0f ? v : 0.2f * v);
    ga = fmaf(pe, q2f(G28[(size_t)d * 96 + 64 + l]), ga);
    gden += pe;
  }
  float og = ga * FP8_INV / gden + gbias[l];
  og = og >= 0.0f ? og : pg[l] * og;
  float ot = ta * FP8_INV / tden + b2f(C2b[(size_t)d * 64 + 32 + l]);
  ot = ot >= 0.0f ? ot : pt[l] * ot;
  xgv[g][l] = og;
  xtv[g][l] = ot;
  __syncthreads();
  // fuse: x2[d][l] = fb[l] + sum_i xg[i]*fw[i][l] + xt[i]*fw[32+i][l]
  float acc = fb[l];
#pragma unroll
  for (int i = 0; i < 32; ++i) {
    acc = fmaf(xgv[g][i], fw[i * 32 + l], acc);
    acc = fmaf(xtv[g][i], fw[(32 + i) * 32 + l], acc);
  }
  x2out[(size_t)d * 32 + l] = acc;
  __syncthreads();
  xgv[g][l] = acc;
  __syncthreads();
  if (g == 0) {
    float s = acc;
#pragma unroll
    for (int i = 1; i < 8; ++i) s += xgv[i][l];
    atomicAdd(&colsum[(blockIdx.x & 7) * 32 + l], s);  // 8 shadows kill contention
  }
}

// ------------------------------------------------ epilogue

// sigmoid(colsum/NN) -> mlp -> disc_w -> bilinear rows (all fused)
__global__ void k_disc_all(const float* __restrict__ x2o, const float* __restrict__ x2a_,
                           const float* __restrict__ cso, const float* __restrict__ csa,
                           const float* __restrict__ mlp_w, const float* __restrict__ mlp_b,
                           const float* __restrict__ disc_w, const float* __restrict__ db,
                           float* __restrict__ ret_os, float* __restrict__ ret_os_a) {
  __shared__ float sgv[64], h1s[32], h2s[32], m1[32], m2[32];
  int t = threadIdx.x;
  if (t < 64) {
    int j = t & 31;
    const float* cs = (t < 32) ? cso : csa;
    float m = 0.0f;
#pragma unroll
    for (int i = 0; i < 8; ++i) m += cs[i * 32 + j];
    sgv[t] = 1.0f / (1.0f + expf(-m / (float)NN));
  }
  __syncthreads();
  if (t < 64) {
    int j = t & 31;
    const float* sg = (t < 32) ? sgv : sgv + 32;
    float acc = mlp_b[j];
#pragma unroll
    for (int i = 0; i < 32; ++i) acc = fmaf(sg[i], mlp_w[i * 32 + j], acc);
    (t < 32 ? h1s : h2s)[j] = acc;
  }
  __syncthreads();
  if (t < 64) {
    int k = t & 31;
    const float* hv = (t < 32) ? h1s : h2s;
    float acc = 0.0f;
#pragma unroll
    for (int i = 0; i < 32; ++i) acc = fmaf(disc_w[k * 32 + i], hv[i], acc);
    (t < 32 ? m1 : m2)[k] = acc;
  }
  __syncthreads();
  int n = blockIdx.x * blockDim.x + t;
  if (n >= NN) return;
  const float* a = x2o + (size_t)n * 32;
  const float* b = x2a_ + (size_t)n * 32;
  float s_oo = 0, s_ao = 0, s_aa = 0, s_oa = 0;
#pragma unroll
  for (int i = 0; i < 32; ++i) {
    float v1 = m1[i], v2 = m2[i];
    s_oo = fmaf(a[i], v1, s_oo);
    s_ao = fmaf(b[i], v1, s_ao);
    s_aa = fmaf(b[i], v2, s_aa);
    s_oa = fmaf(a[i], v2, s_oa);
  }
  float bb = db[0];
  ret_os[n * 2 + 0] = s_oo + bb;
  ret_os[n * 2 + 1] = s_ao + bb;
  ret_os_a[n * 2 + 0] = s_aa + bb;
  ret_os_a[n * 2 + 1] = s_oa + bb;
}

__global__ void k_dec1(const float* __restrict__ x2o, const int* __restrict__ idx0,
                       const int* __restrict__ idx1, const float* __restrict__ w,
                       const float* __restrict__ b1, float* __restrict__ hh) {
  int t = blockIdx.x * blockDim.x + threadIdx.x;
  if (t >= NB * 512) return;
  int bb = t >> 9, n = t & 511;
  const float* r0 = x2o + (size_t)idx0[bb] * 32;
  const float* r1 = x2o + (size_t)idx1[bb] * 32;
  float acc = b1[n];
#pragma unroll
  for (int i = 0; i < 32; ++i) acc = fmaf(r0[i], w[i * 512 + n], acc);
#pragma unroll
  for (int i = 0; i < 32; ++i) acc = fmaf(r1[i], w[(32 + i) * 512 + n], acc);
  hh[t] = fmaxf(acc, 0.0f);
}

__global__ void k_dec2w(const float* __restrict__ hh, const float* __restrict__ w2,
                        const float* __restrict__ b2, const float* __restrict__ w3,
                        const float* __restrict__ b3, float* __restrict__ logo,
                        float* __restrict__ log1) {
  int wv = (blockIdx.x * blockDim.x + threadIdx.x) >> 6;
  int lane = threadIdx.x & 63;
  if (wv >= NB * 4) return;
  int bb = wv >> 2, j = wv & 3;
  const float* h = hh + (size_t)bb * 512;
  const float* ws = (j < 2) ? w2 : w3;
  int jj = j & 1;
  float acc = 0.0f;
#pragma unroll
  for (int k = 0; k < 8; ++k) acc = fmaf(h[lane + k * 64], ws[(lane + k * 64) * 2 + jj], acc);
  acc += __shfl_xor(acc, 32);
  acc += __shfl_xor(acc, 16);
  acc += __shfl_xor(acc, 8);
  acc += __shfl_xor(acc, 4);
  acc += __shfl_xor(acc, 2);
  acc += __shfl_xor(acc, 1);
  if (lane == 0) {
    float b = (j < 2) ? b2[jj] : b3[jj];
    ((j < 2) ? logo : log1)[bb * 2 + jj] = acc + b;
  }
}

__global__ void k_adv(const float* __restrict__ x2o, const float* __restrict__ x2a,
                      const float* __restrict__ aw, const float* __restrict__ ab,
                      float* __restrict__ logits) {
  __shared__ float sadv[33];
  int t = threadIdx.x;
  if (t < 32) {
    float s = 0.0f;
#pragma unroll
    for (int j = 0; j < 32; ++j) s += aw[t * 32 + j];
    sadv[t] = s;
  } else if (t == 32) {
    float s = 0.0f;
#pragma unroll
    for (int j = 0; j < 32; ++j) s += ab[j];
    sadv[32] = s;
  }
  __syncthreads();
  int n = blockIdx.x * blockDim.x + t;
  if (n >= 2 * NN) return;
  const float* row = (n < NN) ? (x2o + (size_t)n * 32) : (x2a + (size_t)(n - NN) * 32);
  float acc = sadv[32];
#pragma unroll
  for (int i = 0; i < 32; ++i) acc = fmaf(row[i], sadv[i], acc);
  logits[n] = acc;
}

// ------------------------------------------------ host

extern "C" void kernel_launch(void* const* d_in, const int* in_sizes, int n_in,
                              void* d_out, int out_size, void* d_ws, size_t ws_size,
                              hipStream_t stream) {
  const float* x_o = (const float*)d_in[0];
  const float* x_a = (const float*)d_in[1];
  const float* gat1_w = (const float*)d_in[2];
  const float* gat1_asrc = (const float*)d_in[3];
  const float* gat1_adst = (const float*)d_in[4];
  const float* gat1_b = (const float*)d_in[5];
  const float* gat2_w = (const float*)d_in[6];
  const float* gat2_asrc = (const float*)d_in[7];
  const float* gat2_adst = (const float*)d_in[8];
  const float* gat2_b = (const float*)d_in[9];
  const float* pg1 = (const float*)d_in[10];
  const float* pg2 = (const float*)d_in[11];
  const float* gt1_wq = (const float*)d_in[12];
  const float* gt1_bq = (const float*)d_in[13];
  const float* gt1_wk = (const float*)d_in[14];
  const float* gt1_bk = (const float*)d_in[15];
  const float* gt1_wv = (const float*)d_in[16];
  const float* gt1_bv = (const float*)d_in[17];
  const float* gt1_ws = (const float*)d_in[18];
  const float* gt1_bs = (const float*)d_in[19];
  const float* gt2_wq = (const float*)d_in[20];
  const float* gt2_bq = (const float*)d_in[21];
  const float* gt2_wk = (const float*)d_in[22];
  const float* gt2_bk = (const float*)d_in[23];
  const float* gt2_wv = (const float*)d_in[24];
  const float* gt2_bv = (const float*)d_in[25];
  const float* gt2_ws = (const float*)d_in[26];
  const float* gt2_bs = (const float*)d_in[27];
  const float* pt1 = (const float*)d_in[28];
  const float* pt2 = (const float*)d_in[29];
  const float* fuse_w = (const float*)d_in[30];
  const float* fuse_b = (const float*)d_in[31];
  const float* mlp1_w = (const float*)d_in[32];
  const float* mlp1_b = (const float*)d_in[33];
  const float* disc_w = (const float*)d_in[34];
  const float* disc_b = (const float*)d_in[35];
  const float* fus_w1 = (const float*)d_in[36];
  const float* fus_b1 = (const float*)d_in[37];
  const float* fus_w2 = (const float*)d_in[38];
  const float* fus_b2 = (const float*)d_in[39];
  const float* fus_w3 = (const float*)d_in[40];
  const float* fus_b3 = (const float*)d_in[41];
  const float* adv_w = (const float*)d_in[42];
  const float* adv_b = (const float*)d_in[43];
  const int* ei = (const int*)d_in[44];
  const int* idxp = (const int*)d_in[45];
  const int* esrc = ei;
  const int* edst = ei + NE;
  const int* idx0 = idxp;
  const int* idx1 = idxp + NB;

  // ---- workspace carve (float units) ----
  float* w = (float*)d_ws;
  size_t o = 0;
  u8* G8 = (u8*)(w + o); o += 3840000;               // 20000*768 fp8
  u16* C1b = (u16*)(w + o); o += 5120000;            // 20000*512 bf16
  u8* G28 = (u8*)(w + o); o += 480000;               // 20000*96 fp8
  u16* C2b = (u16*)(w + o); o += 640000;             // 20000*64 bf16
  u16* bufB = (u16*)(w + o); o += 2560000;           // 20000*256 bf16
  u16* bufE = (u16*)(w + o); o += 2560000;           // 20000*256 bf16
  u16* xb_o = (u16*)(w + o); o += 1280000;           // 20000*128 bf16
  u16* xb_a = (u16*)(w + o); o += 1280000;
  u16* Wt1 = (u16*)(w + o); o += 81920;              // 1280*128 bf16
  u16* Wt2 = (u16*)(w + o); o += 20480;              // 160*256 bf16
  float* bp1 = w + o; o += 1280;
  float* bp2 = w + o; o += 160;
  float* als = w + o; o += NN * 4;
  float* ald = w + o; o += NN * 4;
  float* x2a = w + o; o += NN * 32;
  float* hh = w + o; o += NB * 512;
  int* deg = (int*)(w + o); o += NN;
  int* offs = (int*)(w + o); o += NN + 8;
  int* cur = (int*)(w + o); o += NN;
  int* esrcs = (int*)(w + o); o += NE;
  float* colsum_o = w + o; o += 256;   // 8 shadows x 32
  float* colsum_a = w + o; o += 256;

  float* out = (float*)d_out;
  float* out_log = out;               // [B,2]
  float* out_ret = out + 8192;        // [N,2]
  float* out_reta = out + 48192;      // [N,2]
  float* out_x2o = out + 88192;       // [N,32]
  float* out_logit = out + 728192;    // [1,2N]
  float* out_log1 = out + 768192;     // [B,2]

  // ---- weight packing + input conversion ----
  k_pack1<<<(1280 * 128 + 255) / 256, 256, 0, stream>>>(gat1_w, gt1_wq, gt1_wk, gt1_wv,
                                                        gt1_ws, gt1_bq, gt1_bk, gt1_bv,
                                                        gt1_bs, Wt1, bp1);
  k_pack2<<<(160 * 256 + 255) / 256, 256, 0, stream>>>(gt2_wq, gt2_wk, gt2_wv, gt2_ws,
                                                       gat2_w, gt2_bq, gt2_bk, gt2_bv,
                                                       gt2_bs, Wt2, bp2);
  k_tobf16x2<<<(2 * NN * 128 + 255) / 256, 256, 0, stream>>>(x_o, x_a, xb_o, xb_a);
  // ---- CSR build + colsum zero ----
  hipMemsetAsync(deg, 0, NN * sizeof(int), stream);
  hipMemsetAsync(colsum_o, 0, 512 * sizeof(float), stream);
  k_hist<<<(NE + 255) / 256, 256, 0, stream>>>(edst, deg);
  k_scan20000<<<1, 1024, 0, stream>>>(deg, offs, cur);
  k_scatter<<<(NE + 255) / 256, 256, 0, stream>>>(esrc, edst, cur, esrcs);

  auto branch = [&](const u16* xb, float* x2out, float* colsum) {
    {
      dim3 g(10, (NN + 127) / 128);
      k_mfma_gemm_s<1><<<g, 256, 0, stream>>>(xb, xb, 999, Wt1, bp1, NN, 128, 1280,
                                              G8, C1b);
    }
    k_gat_al8<<<(NN * 4 + 255) / 256, 256, 0, stream>>>(G8, 768, 0, gat1_asrc, gat1_adst,
                                                        als, ald, NN * 4, 4, 64);
    k_agg256_fused<<<NN / 4, 256, 0, stream>>>(offs, esrcs, als, ald, G8, C1b,
                                               gat1_b, pg1, pt1, bufB, bufE);
    {
      dim3 g(2, (NN + 127) / 128);
      k_mfma_gemm_s<2><<<g, 256, 0, stream>>>(bufE, bufB, 1, Wt2, bp2, NN, 256, 160,
                                              G28, C2b);
    }
    k_gat_al8<<<(NN + 255) / 256, 256, 0, stream>>>(G28, 96, 64, gat2_asrc, gat2_adst,
                                                    als, ald, NN, 1, 32);
    k_agg32_fuse<<<NN / 8, 256, 0, stream>>>(offs, esrcs, als, ald, G28, C2b,
                                             gat2_b, pg2, pt2, fuse_w, fuse_b,
                                             x2out, colsum);
  };

  branch(xb_o, out_x2o, colsum_o);
  branch(xb_a, x2a, colsum_a);

  // ---- summary + discriminator (fused) ----
  k_disc_all<<<(NN + 255) / 256, 256, 0, stream>>>(out_x2o, x2a, colsum_o, colsum_a,
                                                   mlp1_w, mlp1_b, disc_w, disc_b,
                                                   out_ret, out_reta);
  // ---- decoder ----
  k_dec1<<<(NB * 512 + 255) / 256, 256, 0, stream>>>(out_x2o, idx0, idx1, fus_w1,
                                                     fus_b1, hh);
  k_dec2w<<<(NB * 4 * 64 + 255) / 256, 256, 0, stream>>>(hh, fus_w2, fus_b2, fus_w3,
                                                         fus_b3, out_log, out_log1);
  // ---- adversarial logits ----
  k_adv<<<(2 * NN + 255) / 256, 256, 0, stream>>>(out_x2o, x2a, adv_w, adv_b, out_logit);
}

// Round 10
// 446.806 us; speedup vs baseline: 8.7138x; 1.0394x over previous
//
#include <hip/hip_runtime.h>
#include <math.h>

#define NN 20000
#define NE 320000
#define NB 4096

typedef unsigned short u16;
typedef unsigned char u8;
typedef __attribute__((ext_vector_type(8))) short short8;
typedef __attribute__((ext_vector_type(4))) float f32x4;
typedef __attribute__((ext_vector_type(2))) float f32x2;

#define FP8_SCALE 16.0f
#define FP8_INV 0.0625f
#define LOG2E 1.44269504088896341f

__device__ __forceinline__ float b2f(u16 u) {
  unsigned int x = ((unsigned int)u) << 16;
  return __uint_as_float(x);
}
__device__ __forceinline__ u16 f2b(float f) {
  unsigned int x = __float_as_uint(f);
  return (u16)((x + 0x7fffu + ((x >> 16) & 1u)) >> 16);
}
__device__ __forceinline__ float q2f(u8 b) {
  f32x2 v = __builtin_amdgcn_cvt_pk_f32_fp8((int)b, false);
  return v[0];
}
__device__ __forceinline__ void q4(unsigned int u, float* f) {
  f32x2 lo = __builtin_amdgcn_cvt_pk_f32_fp8((int)u, false);
  f32x2 hi = __builtin_amdgcn_cvt_pk_f32_fp8((int)u, true);
  f[0] = lo[0]; f[1] = lo[1]; f[2] = hi[0]; f[3] = hi[1];
}
template <int CTRL>
__device__ __forceinline__ float dppadd(float x) {
  int y = __builtin_amdgcn_update_dpp(0, __float_as_int(x), CTRL, 0xf, 0xf, true);
  return x + __int_as_float(y);
}
__device__ __forceinline__ float red16(float x) {
  x = dppadd<0xB1>(x);
  x = dppadd<0x4E>(x);
  x = dppadd<0x124>(x);
  x = dppadd<0x128>(x);
  return x;
}

// ------------------------------------------------ packing (transposed bf16 weights)

__global__ void k_pack1(const float* __restrict__ w0, const float* __restrict__ w1,
                        const float* __restrict__ w2, const float* __restrict__ w3,
                        const float* __restrict__ w4, const float* __restrict__ b1,
                        const float* __restrict__ b2, const float* __restrict__ b3,
                        const float* __restrict__ b4, u16* __restrict__ Wt,
                        float* __restrict__ bp) {
  int t = blockIdx.x * blockDim.x + threadIdx.x;
  if (t < 1280 * 128) {
    int j = t >> 7, k = t & 127;
    int seg = j >> 8, jj = j & 255;
    const float* s = (seg == 0) ? w0 : (seg == 1) ? w1 : (seg == 2) ? w2 : (seg == 3) ? w3 : w4;
    Wt[t] = f2b(s[k * 256 + jj]);
  }
  if (t < 1280) {
    int seg = t >> 8, jj = t & 255;
    bp[t] = (seg == 0) ? 0.0f : (seg == 1) ? b1[jj] : (seg == 2) ? b2[jj] : (seg == 3) ? b3[jj] : b4[jj];
  }
}

__global__ void k_pack2(const float* __restrict__ wq, const float* __restrict__ wk,
                        const float* __restrict__ wv, const float* __restrict__ ws,
                        const float* __restrict__ wg, const float* __restrict__ bq,
                        const float* __restrict__ bk, const float* __restrict__ bv,
                        const float* __restrict__ bs, u16* __restrict__ Wt,
                        float* __restrict__ bp) {
  int t = blockIdx.x * blockDim.x + threadIdx.x;
  if (t < 160 * 256) {
    int j = t >> 8, k = t & 255;
    int seg = j >> 5, jj = j & 31;
    const float* s = (seg == 0) ? wq : (seg == 1) ? wk : (seg == 2) ? wv : (seg == 3) ? ws : wg;
    Wt[t] = f2b(s[k * 32 + jj]);
  }
  if (t < 160) {
    int seg = t >> 5, jj = t & 31;
    bp[t] = (seg == 0) ? bq[jj] : (seg == 1) ? bk[jj] : (seg == 2) ? bv[jj] : (seg == 3) ? bs[jj] : 0.0f;
  }
}

__global__ void k_tobf16x2(const float* __restrict__ xo, const float* __restrict__ xa,
                           u16* __restrict__ bo, u16* __restrict__ ba) {
  int t = blockIdx.x * blockDim.x + threadIdx.x;
  if (t >= 2 * NN * 128) return;
  if (t < NN * 128) bo[t] = f2b(xo[t]);
  else ba[t - NN * 128] = f2b(xa[t - NN * 128]);
}

// ------------------------------------------------ CSR build

__global__ void k_hist(const int* __restrict__ dst, int* __restrict__ deg) {
  int t = blockIdx.x * blockDim.x + threadIdx.x;
  if (t < NE) atomicAdd(&deg[dst[t]], 1);
}

__global__ void k_scan20000(const int* __restrict__ deg, int* __restrict__ offs,
                            int* __restrict__ cur) {
  __shared__ int part[1024];
  int t = threadIdx.x;
  int loc[20];
  int s = 0;
#pragma unroll
  for (int i = 0; i < 20; ++i) {
    int idx = t * 20 + i;
    int v = (idx < NN) ? deg[idx] : 0;
    loc[i] = s;
    s += v;
  }
  part[t] = s;
  __syncthreads();
  for (int off = 1; off < 1024; off <<= 1) {
    int v = (t >= off) ? part[t - off] : 0;
    __syncthreads();
    part[t] += v;
    __syncthreads();
  }
  int base = (t > 0) ? part[t - 1] : 0;
#pragma unroll
  for (int i = 0; i < 20; ++i) {
    int idx = t * 20 + i;
    if (idx < NN) {
      offs[idx] = base + loc[i];
      cur[idx] = base + loc[i];
    }
  }
  if (t == 1023) offs[NN] = part[1023];
}

__global__ void k_scatter(const int* __restrict__ src, const int* __restrict__ dst,
                          int* __restrict__ cur, int* __restrict__ esrcs) {
  int t = blockIdx.x * blockDim.x + threadIdx.x;
  if (t >= NE) return;
  int d = dst[t];
  int pos = atomicAdd(&cur[d], 1);
  esrcs[pos] = src[t];
}

// ------------------------------------------------ MFMA GEMM, transposed epilogue (proven r7)

template <int LAYER>
__global__ void k_mfma_gemm_s(const u16* __restrict__ A0, const u16* __restrict__ A1,
                              int asel, const u16* __restrict__ Bt,
                              const float* __restrict__ bias, int M, int K, int Nc,
                              u8* __restrict__ G, u16* __restrict__ Cb) {
  const u16* A = (blockIdx.x >= (unsigned)asel) ? A1 : A0;
  int m0 = blockIdx.y * 128, n0 = blockIdx.x * 128;
  int wid = threadIdx.x >> 6, lane = threadIdx.x & 63;
  int mw = m0 + (wid & 1) * 64, nw = n0 + (wid >> 1) * 64;
  int arow = mw + (lane & 15);
  int bcol = nw + (lane & 15);
  int kblk = (lane >> 4) * 8;
  f32x4 acc[4][4] = {};
  const short8 zero8 = {0, 0, 0, 0, 0, 0, 0, 0};
  for (int k0 = 0; k0 < K; k0 += 32) {
    short8 af[4], bf[4];
#pragma unroll
    for (int mf = 0; mf < 4; ++mf) {
      int r = arow + mf * 16;
      if (r > M - 1) r = M - 1;
      af[mf] = *reinterpret_cast<const short8*>(&A[(size_t)r * K + k0 + kblk]);
    }
#pragma unroll
    for (int nf = 0; nf < 4; ++nf) {
      int c = bcol + nf * 16;
      bf[nf] = (c < Nc) ? *reinterpret_cast<const short8*>(&Bt[(size_t)c * K + k0 + kblk])
                        : zero8;
    }
#pragma unroll
    for (int mf = 0; mf < 4; ++mf)
#pragma unroll
      for (int nf = 0; nf < 4; ++nf)
        acc[mf][nf] = __builtin_amdgcn_mfma_f32_16x16x32_bf16(bf[nf], af[mf],
                                                              acc[mf][nf], 0, 0, 0);
  }
  const int CSTR = (LAYER == 1) ? 512 : 64;
  const int GSTR = (LAYER == 1) ? 768 : 96;
#pragma unroll
  for (int mf = 0; mf < 4; ++mf) {
    int row = mw + mf * 16 + (lane & 15);
    if (row >= M) continue;
#pragma unroll
    for (int nf = 0; nf < 4; ++nf) {
      int col0 = nw + nf * 16 + ((lane >> 4) << 2);
      if (col0 >= Nc) continue;
      float4 bs4 = *reinterpret_cast<const float4*>(&bias[col0]);
      float v0 = acc[mf][nf][0] + bs4.x;
      float v1 = acc[mf][nf][1] + bs4.y;
      float v2 = acc[mf][nf][2] + bs4.z;
      float v3 = acc[mf][nf][3] + bs4.w;
      int seg = (LAYER == 1) ? (col0 >> 8) : (col0 >> 5);
      bool tobf = (LAYER == 1) ? (seg == 1 || seg == 4) : (seg == 0 || seg == 3);
      if (tobf) {
        int ccol = (LAYER == 1) ? ((seg == 1) ? col0 - 256 : col0 - 768)
                                : ((seg == 0) ? col0 : col0 - 64);
        ushort4 w4;
        w4.x = f2b(v0); w4.y = f2b(v1); w4.z = f2b(v2); w4.w = f2b(v3);
        *reinterpret_cast<ushort4*>(&Cb[(size_t)row * CSTR + ccol]) = w4;
      } else {
        int gcol = (LAYER == 1) ? ((seg == 0) ? col0 : col0 - 256)
                                : ((seg == 4) ? col0 - 64 : col0 - 32);
        unsigned int p = (unsigned int)__builtin_amdgcn_cvt_pk_fp8_f32(
            v0 * FP8_SCALE, v1 * FP8_SCALE, 0, false);
        p = (unsigned int)__builtin_amdgcn_cvt_pk_fp8_f32(
            v2 * FP8_SCALE, v3 * FP8_SCALE, (int)p, true);
        *reinterpret_cast<unsigned int*>(&G[(size_t)row * GSTR + gcol]) = p;
      }
    }
  }
}

// ------------------------------------------------ attention pieces

__global__ void k_gat_al8(const u8* __restrict__ h, int stride, int coff,
                          const float* __restrict__ asrc, const float* __restrict__ adst,
                          float* __restrict__ als, float* __restrict__ ald, int total,
                          int heads, int c) {
  int i = blockIdx.x * blockDim.x + threadIdx.x;
  if (i >= total) return;
  int node = i / heads, hd = i - node * heads;
  const u8* hp = h + (size_t)node * stride + coff + hd * c;
  const float* as = asrc + hd * c;
  const float* ad = adst + hd * c;
  float s1 = 0.0f, s2 = 0.0f;
  for (int k = 0; k < c; k += 4) {
    float f[4];
    q4(*reinterpret_cast<const unsigned int*>(&hp[k]), f);
#pragma unroll
    for (int j = 0; j < 4; ++j) {
      s1 = fmaf(f[j], as[k + j], s1);
      s2 = fmaf(f[j], ad[k + j], s2);
    }
  }
  als[i] = s1 * (FP8_INV * LOG2E);
  ald[i] = s2 * (FP8_INV * LOG2E);
}

// Layer-1 FUSED aggregate: TWO waves per dst (edges at stride 2), LDS combine.
// Block = 256 thr = 4 waves = 2 dst. Grid = NN/2.
__global__ void k_agg256_fused(const int* __restrict__ offs, const int* __restrict__ esrcs,
                               const float* __restrict__ als, const float* __restrict__ ald,
                               const u8* __restrict__ G8, const u16* __restrict__ C1b,
                               const float* __restrict__ gbias,
                               const float* __restrict__ pg, const float* __restrict__ pt,
                               u16* __restrict__ outG, u16* __restrict__ outT) {
  __shared__ float part[2][64][10];
  int g = threadIdx.x >> 6;
  int dl = g >> 1, half = g & 1;
  int d = blockIdx.x * 2 + dl;
  int lane = threadIdx.x & 63;
  int head = lane >> 4, c4 = lane << 2;
  ushort4 q4v = *reinterpret_cast<const ushort4*>(&C1b[(size_t)d * 512 + c4]);
  float q0 = b2f(q4v.x), q1 = b2f(q4v.y), q2 = b2f(q4v.z), q3 = b2f(q4v.w);
  float aldd = ald[d * 4 + head];
  float ga0 = 0, ga1 = 0, ga2 = 0, ga3 = 0, gden = 0.0f;
  float ta0 = 0, ta1 = 0, ta2 = 0, ta3 = 0;
  float tden = half ? 0.0f : 1e-16f;
  int bs = offs[d] + half, be = offs[d + 1];
  const float GTC = 0.125f * FP8_INV * LOG2E;
  unsigned int f0 = 0, k0 = 0, v0 = 0, f1 = 0, k1 = 0, v1 = 0;
  float al0 = 0.0f, al1 = 0.0f;
  if (bs < be) {
    int s = esrcs[bs];
    const u8* row = &G8[(size_t)s * 768];
    f0 = *reinterpret_cast<const unsigned int*>(&row[c4]);
    k0 = *reinterpret_cast<const unsigned int*>(&row[256 + c4]);
    v0 = *reinterpret_cast<const unsigned int*>(&row[512 + c4]);
    al0 = als[s * 4 + head];
  }
  if (bs + 2 < be) {
    int s = esrcs[bs + 2];
    const u8* row = &G8[(size_t)s * 768];
    f1 = *reinterpret_cast<const unsigned int*>(&row[c4]);
    k1 = *reinterpret_cast<const unsigned int*>(&row[256 + c4]);
    v1 = *reinterpret_cast<const unsigned int*>(&row[512 + c4]);
    al1 = als[s * 4 + head];
  }
  for (int i = bs; i < be; i += 2) {
    unsigned int f2_ = 0, k2_ = 0, v2_ = 0;
    float al2_ = 0.0f;
    if (i + 4 < be) {
      int s = esrcs[i + 4];
      const u8* row = &G8[(size_t)s * 768];
      f2_ = *reinterpret_cast<const unsigned int*>(&row[c4]);
      k2_ = *reinterpret_cast<const unsigned int*>(&row[256 + c4]);
      v2_ = *reinterpret_cast<const unsigned int*>(&row[512 + c4]);
      al2_ = als[s * 4 + head];
    }
    float kf[4];
    q4(k0, kf);
    float pp = q0 * kf[0];
    pp = fmaf(q1, kf[1], pp);
    pp = fmaf(q2, kf[2], pp);
    pp = fmaf(q3, kf[3], pp);
    pp = red16(pp);
    float pet = exp2f(pp * GTC);
    float v = al0 + aldd;
    float peg = exp2f(v >= 0.0f ? v : 0.2f * v);
    float ff[4], vf[4];
    q4(f0, ff);
    q4(v0, vf);
    ga0 = fmaf(peg, ff[0], ga0);
    ga1 = fmaf(peg, ff[1], ga1);
    ga2 = fmaf(peg, ff[2], ga2);
    ga3 = fmaf(peg, ff[3], ga3);
    gden += peg;
    ta0 = fmaf(pet, vf[0], ta0);
    ta1 = fmaf(pet, vf[1], ta1);
    ta2 = fmaf(pet, vf[2], ta2);
    ta3 = fmaf(pet, vf[3], ta3);
    tden += pet;
    f0 = f1; k0 = k1; v0 = v1; al0 = al1;
    f1 = f2_; k1 = k2_; v1 = v2_; al1 = al2_;
  }
  if (half == 0) {  // self loop on wave 0
    float v = als[d * 4 + head] + aldd;
    float pe = exp2f(v >= 0.0f ? v : 0.2f * v);
    float ff[4];
    q4(*reinterpret_cast<const unsigned int*>(&G8[(size_t)d * 768 + c4]), ff);
    ga0 = fmaf(pe, ff[0], ga0);
    ga1 = fmaf(pe, ff[1], ga1);
    ga2 = fmaf(pe, ff[2], ga2);
    ga3 = fmaf(pe, ff[3], ga3);
    gden += pe;
  }
  if (half == 1) {
    float* p = part[dl][lane];
    p[0] = ga0; p[1] = ga1; p[2] = ga2; p[3] = ga3; p[4] = gden;
    p[5] = ta0; p[6] = ta1; p[7] = ta2; p[8] = ta3; p[9] = tden;
  }
  __syncthreads();
  if (half == 1) return;
  const float* p = part[dl][lane];
  ga0 += p[0]; ga1 += p[1]; ga2 += p[2]; ga3 += p[3]; gden += p[4];
  ta0 += p[5]; ta1 += p[6]; ta2 += p[7]; ta3 += p[8]; tden += p[9];
  float ig = FP8_INV / gden, it = FP8_INV / tden;
  float o0 = ga0 * ig + gbias[c4 + 0];
  float o1 = ga1 * ig + gbias[c4 + 1];
  float o2 = ga2 * ig + gbias[c4 + 2];
  float o3 = ga3 * ig + gbias[c4 + 3];
  o0 = o0 >= 0.0f ? o0 : pg[c4 + 0] * o0;
  o1 = o1 >= 0.0f ? o1 : pg[c4 + 1] * o1;
  o2 = o2 >= 0.0f ? o2 : pg[c4 + 2] * o2;
  o3 = o3 >= 0.0f ? o3 : pg[c4 + 3] * o3;
  ushort4 wg4;
  wg4.x = f2b(o0); wg4.y = f2b(o1); wg4.z = f2b(o2); wg4.w = f2b(o3);
  *reinterpret_cast<ushort4*>(&outG[(size_t)d * 256 + c4]) = wg4;
  ushort4 sk = *reinterpret_cast<const ushort4*>(&C1b[(size_t)d * 512 + 256 + c4]);
  float u0 = ta0 * it + b2f(sk.x);
  float u1 = ta1 * it + b2f(sk.y);
  float u2 = ta2 * it + b2f(sk.z);
  float u3 = ta3 * it + b2f(sk.w);
  u0 = u0 >= 0.0f ? u0 : pt[c4 + 0] * u0;
  u1 = u1 >= 0.0f ? u1 : pt[c4 + 1] * u1;
  u2 = u2 >= 0.0f ? u2 : pt[c4 + 2] * u2;
  u3 = u3 >= 0.0f ? u3 : pt[c4 + 3] * u3;
  ushort4 wt4;
  wt4.x = f2b(u0); wt4.y = f2b(u1); wt4.z = f2b(u2); wt4.w = f2b(u3);
  *reinterpret_cast<ushort4*>(&outT[(size_t)d * 256 + c4]) = wt4;
}

// Layer-2 FUSED aggregate + fuse_w matmul + column-sum accumulation (proven r9).
__global__ void k_agg32_fuse(const int* __restrict__ offs, const int* __restrict__ esrcs,
                             const float* __restrict__ als, const float* __restrict__ ald,
                             const u8* __restrict__ G28, const u16* __restrict__ C2b,
                             const float* __restrict__ gbias,
                             const float* __restrict__ pg, const float* __restrict__ pt,
                             const float* __restrict__ fw, const float* __restrict__ fb,
                             float* __restrict__ x2out, float* __restrict__ colsum) {
  __shared__ float xgv[8][32], xtv[8][32];
  int g = threadIdx.x >> 5, l = threadIdx.x & 31;
  int d = blockIdx.x * 8 + g;
  float qv = b2f(C2b[(size_t)d * 64 + l]);
  float aldd = ald[d];
  float ga = 0.0f, gden = 0.0f;
  float ta = 0.0f, tden = 1e-16f;
  int b0 = offs[d], b1 = offs[d + 1];
  const float GTC2 = 0.17677669529663687f * FP8_INV * LOG2E;
  u8 kc = 0, vc = 0, hc = 0;
  float alc = 0;
  if (b0 < b1) {
    int sc = esrcs[b0];
    const u8* row = &G28[(size_t)sc * 96];
    kc = row[l]; vc = row[32 + l]; hc = row[64 + l];
    alc = als[sc];
  }
  for (int i = b0; i < b1; ++i) {
    u8 kn = kc, vn = vc, hn = hc;
    float aln = alc;
    if (i + 1 < b1) {
      int sn = esrcs[i + 1];
      const u8* row = &G28[(size_t)sn * 96];
      kn = row[l]; vn = row[32 + l]; hn = row[64 + l];
      aln = als[sn];
    }
    float pp = qv * q2f(kc);
    pp = red16(pp);
    pp += __shfl_xor(pp, 16, 32);
    float pet = exp2f(pp * GTC2);
    float v = alc + aldd;
    float peg = exp2f(v >= 0.0f ? v : 0.2f * v);
    ga = fmaf(peg, q2f(hc), ga);
    gden += peg;
    ta = fmaf(pet, q2f(vc), ta);
    tden += pet;
    kc = kn; vc = vn; hc = hn; alc = aln;
  }
  {
    float v = als[d] + aldd;
    float pe = exp2f(v >= 0.0f ? v : 0.2f * v);
    ga = fmaf(pe, q2f(G28[(size_t)d * 96 + 64 + l]), ga);
    gden += pe;
  }
  float og = ga * FP8_INV / gden + gbias[l];
  og = og >= 0.0f ? og : pg[l] * og;
  float ot = ta * FP8_INV / tden + b2f(C2b[(size_t)d * 64 + 32 + l]);
  ot = ot >= 0.0f ? ot : pt[l] * ot;
  xgv[g][l] = og;
  xtv[g][l] = ot;
  __syncthreads();
  float acc = fb[l];
#pragma unroll
  for (int i = 0; i < 32; ++i) {
    acc = fmaf(xgv[g][i], fw[i * 32 + l], acc);
    acc = fmaf(xtv[g][i], fw[(32 + i) * 32 + l], acc);
  }
  x2out[(size_t)d * 32 + l] = acc;
  __syncthreads();
  xgv[g][l] = acc;
  __syncthreads();
  if (g == 0) {
    float s = acc;
#pragma unroll
    for (int i = 1; i < 8; ++i) s += xgv[i][l];
    atomicAdd(&colsum[(blockIdx.x & 7) * 32 + l], s);
  }
}

// ------------------------------------------------ epilogue

// sigmoid(colsum/NN) -> mlp -> disc_w -> bilinear rows + ADV logits (all fused)
__global__ void k_disc_all(const float* __restrict__ x2o, const float* __restrict__ x2a_,
                           const float* __restrict__ cso, const float* __restrict__ csa,
                           const float* __restrict__ mlp_w, const float* __restrict__ mlp_b,
                           const float* __restrict__ disc_w, const float* __restrict__ db,
                           const float* __restrict__ aw, const float* __restrict__ ab,
                           float* __restrict__ ret_os, float* __restrict__ ret_os_a,
                           float* __restrict__ logits) {
  __shared__ float sgv[64], h1s[32], h2s[32], m1[32], m2[32], sadv[33];
  int t = threadIdx.x;
  if (t < 64) {
    int j = t & 31;
    const float* cs = (t < 32) ? cso : csa;
    float m = 0.0f;
#pragma unroll
    for (int i = 0; i < 8; ++i) m += cs[i * 32 + j];
    sgv[t] = 1.0f / (1.0f + expf(-m / (float)NN));
  }
  if (t >= 64 && t < 96) {
    int j = t & 31;
    float s = 0.0f;
#pragma unroll
    for (int i = 0; i < 32; ++i) s += aw[j * 32 + i];
    sadv[j] = s;
  } else if (t == 96) {
    float s = 0.0f;
#pragma unroll
    for (int i = 0; i < 32; ++i) s += ab[i];
    sadv[32] = s;
  }
  __syncthreads();
  if (t < 64) {
    int j = t & 31;
    const float* sg = (t < 32) ? sgv : sgv + 32;
    float acc = mlp_b[j];
#pragma unroll
    for (int i = 0; i < 32; ++i) acc = fmaf(sg[i], mlp_w[i * 32 + j], acc);
    (t < 32 ? h1s : h2s)[j] = acc;
  }
  __syncthreads();
  if (t < 64) {
    int k = t & 31;
    const float* hv = (t < 32) ? h1s : h2s;
    float acc = 0.0f;
#pragma unroll
    for (int i = 0; i < 32; ++i) acc = fmaf(disc_w[k * 32 + i], hv[i], acc);
    (t < 32 ? m1 : m2)[k] = acc;
  }
  __syncthreads();
  int n = blockIdx.x * blockDim.x + t;
  if (n >= NN) return;
  const float* a = x2o + (size_t)n * 32;
  const float* b = x2a_ + (size_t)n * 32;
  float s_oo = 0, s_ao = 0, s_aa = 0, s_oa = 0;
  float lo = sadv[32], la = sadv[32];
#pragma unroll
  for (int i = 0; i < 32; ++i) {
    float v1 = m1[i], v2 = m2[i], av = sadv[i];
    float ai = a[i], bi = b[i];
    s_oo = fmaf(ai, v1, s_oo);
    s_ao = fmaf(bi, v1, s_ao);
    s_aa = fmaf(bi, v2, s_aa);
    s_oa = fmaf(ai, v2, s_oa);
    lo = fmaf(ai, av, lo);
    la = fmaf(bi, av, la);
  }
  float bb = db[0];
  ret_os[n * 2 + 0] = s_oo + bb;
  ret_os[n * 2 + 1] = s_ao + bb;
  ret_os_a[n * 2 + 0] = s_aa + bb;
  ret_os_a[n * 2 + 1] = s_oa + bb;
  logits[n] = lo;
  logits[NN + n] = la;
}

// dec1+dec2 fused: one block per batch element; hh row in LDS; 4 wave-dots.
__global__ void k_dec(const float* __restrict__ x2o, const int* __restrict__ idx0,
                      const int* __restrict__ idx1, const float* __restrict__ w1,
                      const float* __restrict__ b1, const float* __restrict__ w2,
                      const float* __restrict__ b2, const float* __restrict__ w3,
                      const float* __restrict__ b3, float* __restrict__ logo,
                      float* __restrict__ log1) {
  __shared__ float hhs[512];
  int bb = blockIdx.x;
  const float* r0 = x2o + (size_t)idx0[bb] * 32;
  const float* r1 = x2o + (size_t)idx1[bb] * 32;
  int t = threadIdx.x;
  for (int n = t; n < 512; n += 256) {
    float acc = b1[n];
#pragma unroll
    for (int i = 0; i < 32; ++i) {
      acc = fmaf(r0[i], w1[i * 512 + n], acc);
      acc = fmaf(r1[i], w1[(32 + i) * 512 + n], acc);
    }
    hhs[n] = fmaxf(acc, 0.0f);
  }
  __syncthreads();
  int g = t >> 6, lane = t & 63;
  const float* ws = (g < 2) ? w2 : w3;
  int jj = g & 1;
  float acc = 0.0f;
#pragma unroll
  for (int k = 0; k < 8; ++k) acc = fmaf(hhs[lane + k * 64], ws[(lane + k * 64) * 2 + jj], acc);
  acc += __shfl_xor(acc, 32);
  acc += __shfl_xor(acc, 16);
  acc += __shfl_xor(acc, 8);
  acc += __shfl_xor(acc, 4);
  acc += __shfl_xor(acc, 2);
  acc += __shfl_xor(acc, 1);
  if (lane == 0) {
    float b = (g < 2) ? b2[jj] : b3[jj];
    ((g < 2) ? logo : log1)[bb * 2 + jj] = acc + b;
  }
}

// ------------------------------------------------ host

extern "C" void kernel_launch(void* const* d_in, const int* in_sizes, int n_in,
                              void* d_out, int out_size, void* d_ws, size_t ws_size,
                              hipStream_t stream) {
  const float* x_o = (const float*)d_in[0];
  const float* x_a = (const float*)d_in[1];
  const float* gat1_w = (const float*)d_in[2];
  const float* gat1_asrc = (const float*)d_in[3];
  const float* gat1_adst = (const float*)d_in[4];
  const float* gat1_b = (const float*)d_in[5];
  const float* gat2_w = (const float*)d_in[6];
  const float* gat2_asrc = (const float*)d_in[7];
  const float* gat2_adst = (const float*)d_in[8];
  const float* gat2_b = (const float*)d_in[9];
  const float* pg1 = (const float*)d_in[10];
  const float* pg2 = (const float*)d_in[11];
  const float* gt1_wq = (const float*)d_in[12];
  const float* gt1_bq = (const float*)d_in[13];
  const float* gt1_wk = (const float*)d_in[14];
  const float* gt1_bk = (const float*)d_in[15];
  const float* gt1_wv = (const float*)d_in[16];
  const float* gt1_bv = (const float*)d_in[17];
  const float* gt1_ws = (const float*)d_in[18];
  const float* gt1_bs = (const float*)d_in[19];
  const float* gt2_wq = (const float*)d_in[20];
  const float* gt2_bq = (const float*)d_in[21];
  const float* gt2_wk = (const float*)d_in[22];
  const float* gt2_bk = (const float*)d_in[23];
  const float* gt2_wv = (const float*)d_in[24];
  const float* gt2_bv = (const float*)d_in[25];
  const float* gt2_ws = (const float*)d_in[26];
  const float* gt2_bs = (const float*)d_in[27];
  const float* pt1 = (const float*)d_in[28];
  const float* pt2 = (const float*)d_in[29];
  const float* fuse_w = (const float*)d_in[30];
  const float* fuse_b = (const float*)d_in[31];
  const float* mlp1_w = (const float*)d_in[32];
  const float* mlp1_b = (const float*)d_in[33];
  const float* disc_w = (const float*)d_in[34];
  const float* disc_b = (const float*)d_in[35];
  const float* fus_w1 = (const float*)d_in[36];
  const float* fus_b1 = (const float*)d_in[37];
  const float* fus_w2 = (const float*)d_in[38];
  const float* fus_b2 = (const float*)d_in[39];
  const float* fus_w3 = (const float*)d_in[40];
  const float* fus_b3 = (const float*)d_in[41];
  const float* adv_w = (const float*)d_in[42];
  const float* adv_b = (const float*)d_in[43];
  const int* ei = (const int*)d_in[44];
  const int* idxp = (const int*)d_in[45];
  const int* esrc = ei;
  const int* edst = ei + NE;
  const int* idx0 = idxp;
  const int* idx1 = idxp + NB;

  // ---- workspace carve (float units) ----
  float* w = (float*)d_ws;
  size_t o = 0;
  u8* G8 = (u8*)(w + o); o += 3840000;               // 20000*768 fp8
  u16* C1b = (u16*)(w + o); o += 5120000;            // 20000*512 bf16
  u8* G28 = (u8*)(w + o); o += 480000;               // 20000*96 fp8
  u16* C2b = (u16*)(w + o); o += 640000;             // 20000*64 bf16
  u16* bufB = (u16*)(w + o); o += 2560000;           // 20000*256 bf16
  u16* bufE = (u16*)(w + o); o += 2560000;           // 20000*256 bf16
  u16* xb_o = (u16*)(w + o); o += 1280000;           // 20000*128 bf16
  u16* xb_a = (u16*)(w + o); o += 1280000;
  u16* Wt1 = (u16*)(w + o); o += 81920;              // 1280*128 bf16
  u16* Wt2 = (u16*)(w + o); o += 20480;              // 160*256 bf16
  float* bp1 = w + o; o += 1280;
  float* bp2 = w + o; o += 160;
  float* als = w + o; o += NN * 4;
  float* ald = w + o; o += NN * 4;
  float* x2a = w + o; o += NN * 32;
  int* deg = (int*)(w + o); o += NN;
  int* offs = (int*)(w + o); o += NN + 8;
  int* cur = (int*)(w + o); o += NN;
  int* esrcs = (int*)(w + o); o += NE;
  float* colsum_o = w + o; o += 256;   // 8 shadows x 32
  float* colsum_a = w + o; o += 256;

  float* out = (float*)d_out;
  float* out_log = out;               // [B,2]
  float* out_ret = out + 8192;        // [N,2]
  float* out_reta = out + 48192;      // [N,2]
  float* out_x2o = out + 88192;       // [N,32]
  float* out_logit = out + 728192;    // [1,2N]
  float* out_log1 = out + 768192;     // [B,2]

  // ---- weight packing + input conversion ----
  k_pack1<<<(1280 * 128 + 255) / 256, 256, 0, stream>>>(gat1_w, gt1_wq, gt1_wk, gt1_wv,
                                                        gt1_ws, gt1_bq, gt1_bk, gt1_bv,
                                                        gt1_bs, Wt1, bp1);
  k_pack2<<<(160 * 256 + 255) / 256, 256, 0, stream>>>(gt2_wq, gt2_wk, gt2_wv, gt2_ws,
                                                       gat2_w, gt2_bq, gt2_bk, gt2_bv,
                                                       gt2_bs, Wt2, bp2);
  k_tobf16x2<<<(2 * NN * 128 + 255) / 256, 256, 0, stream>>>(x_o, x_a, xb_o, xb_a);
  // ---- CSR build + colsum zero ----
  hipMemsetAsync(deg, 0, NN * sizeof(int), stream);
  hipMemsetAsync(colsum_o, 0, 512 * sizeof(float), stream);
  k_hist<<<(NE + 255) / 256, 256, 0, stream>>>(edst, deg);
  k_scan20000<<<1, 1024, 0, stream>>>(deg, offs, cur);
  k_scatter<<<(NE + 255) / 256, 256, 0, stream>>>(esrc, edst, cur, esrcs);

  auto branch = [&](const u16* xb, float* x2out, float* colsum) {
    {
      dim3 g(10, (NN + 127) / 128);
      k_mfma_gemm_s<1><<<g, 256, 0, stream>>>(xb, xb, 999, Wt1, bp1, NN, 128, 1280,
                                              G8, C1b);
    }
    k_gat_al8<<<(NN * 4 + 255) / 256, 256, 0, stream>>>(G8, 768, 0, gat1_asrc, gat1_adst,
                                                        als, ald, NN * 4, 4, 64);
    k_agg256_fused<<<NN / 2, 256, 0, stream>>>(offs, esrcs, als, ald, G8, C1b,
                                               gat1_b, pg1, pt1, bufB, bufE);
    {
      dim3 g(2, (NN + 127) / 128);
      k_mfma_gemm_s<2><<<g, 256, 0, stream>>>(bufE, bufB, 1, Wt2, bp2, NN, 256, 160,
                                              G28, C2b);
    }
    k_gat_al8<<<(NN + 255) / 256, 256, 0, stream>>>(G28, 96, 64, gat2_asrc, gat2_adst,
                                                    als, ald, NN, 1, 32);
    k_agg32_fuse<<<NN / 8, 256, 0, stream>>>(offs, esrcs, als, ald, G28, C2b,
                                             gat2_b, pg2, pt2, fuse_w, fuse_b,
                                             x2out, colsum);
  };

  branch(xb_o, out_x2o, colsum_o);
  branch(xb_a, x2a, colsum_a);

  // ---- summary + discriminator + adversarial (fused) ----
  k_disc_all<<<(NN + 255) / 256, 256, 0, stream>>>(out_x2o, x2a, colsum_o, colsum_a,
                                                   mlp1_w, mlp1_b, disc_w, disc_b,
                                                   adv_w, adv_b, out_ret, out_reta,
                                                   out_logit);
  // ---- decoder (dec1+dec2 fused) ----
  k_dec<<<NB, 256, 0, stream>>>(out_x2o, idx0, idx1, fus_w1, fus_b1, fus_w2, fus_b2,
                                fus_w3, fus_b3, out_log, out_log1);
}